// Round 11
// baseline (265.130 us; speedup 1.0000x reference)
//
#include <hip/hip_runtime.h>
#include <hip/hip_bf16.h>

// NSA forward: B=2, N=1024, D=2048, H=16, HD=128, BS=64, SEL=8, WIN=64
#define HN   16
#define HDIM 128
#define NSEQ 1024
#define NBLK 16
#define BSZ  64
#define SCALE 0.08838834764831845f
#define QKV_STR 6400   // row stride of fused qkv+gate buffer (bf16), padded to 25*256
#define KOFS 2048
#define VOFS 4096
#define GOFS 6144

typedef __attribute__((ext_vector_type(8))) short bfrag;   // 8 bf16 (4 VGPRs)
typedef __attribute__((ext_vector_type(4))) float facc;    // MFMA accumulator

__device__ __forceinline__ float bf2f(short s) {
  union { unsigned u; float f; } cv;
  cv.u = ((unsigned)(unsigned short)s) << 16;
  return cv.f;
}
__device__ __forceinline__ short f2bf(float f) {
  unsigned u = __float_as_uint(f);
  u = (u + 0x7fff + ((u >> 16) & 1)) >> 16;  // RNE
  return (short)u;
}

#define ASYNC16(gp, lp)                                                    \
  __builtin_amdgcn_global_load_lds(                                        \
      (const __attribute__((address_space(1))) void*)(gp),                 \
      (__attribute__((address_space(3))) void*)(lp), 16, 0, 0)

#define MFMA16(a, b, c) __builtin_amdgcn_mfma_f32_16x16x32_bf16(a, b, c, 0, 0, 0)

// ------------------------------------------------------------------
// prep: z=0..2 -> Wq/Wk/Wv transpose-cast into w_t rows z*2048..
//       z=3   -> Wg transposed + zero-padded to rows 6144..6271
//       z=4   -> x cast to bf16
//       z=5   -> RoPE cos/sin table
// ------------------------------------------------------------------
__global__ __launch_bounds__(256) void prep(const float* __restrict__ Wq,
                                            const float* __restrict__ Wk,
                                            const float* __restrict__ Wv,
                                            const float* __restrict__ Wg,
                                            const float* __restrict__ x,
                                            short* __restrict__ w_t,
                                            short* __restrict__ x_bf,
                                            float2* __restrict__ tbl) {
  __shared__ float tile[32][33];
  const int z = blockIdx.z;
  const int bx = blockIdx.x * 32, by = blockIdx.y * 32;
  const int tx = threadIdx.x & 31, ty = threadIdx.x >> 5;
  if (z == 5) {
    if (blockIdx.y >= 4) return;
    int i = (blockIdx.y * 64 + blockIdx.x) * 256 + threadIdx.x;  // < 65536
    int d = i & 63, n = i >> 6;
    float inv = expf(-(float)d * (9.210340371976184f / 64.0f));
    float sn, cs;
    sincosf((float)n * inv, &sn, &cs);
    tbl[i] = make_float2(cs, sn);
    return;
  }
  if (z == 4) {
#pragma unroll
    for (int i = 0; i < 4; ++i) {
      const int row = by + ty + 8 * i;
      x_bf[(size_t)row * 2048 + bx + tx] = f2bf(x[(size_t)row * 2048 + bx + tx]);
    }
    return;
  }
  if (z == 3) {
    if (blockIdx.x >= 4) return;  // only 128 dst rows
#pragma unroll
    for (int i = 0; i < 4; ++i) {
      const int c = bx + tx;
      tile[ty + 8 * i][tx] = (c < 48) ? Wg[(size_t)(by + ty + 8 * i) * 48 + c] : 0.f;
    }
    __syncthreads();
#pragma unroll
    for (int i = 0; i < 4; ++i)
      w_t[(size_t)(GOFS + bx + ty + 8 * i) * 2048 + by + tx] = f2bf(tile[tx][ty + 8 * i]);
    return;
  }
  const float* src = (z == 0) ? Wq : (z == 1) ? Wk : Wv;
#pragma unroll
  for (int i = 0; i < 4; ++i)
    tile[ty + 8 * i][tx] = src[(size_t)(by + ty + 8 * i) * 2048 + bx + tx];
  __syncthreads();
#pragma unroll
  for (int i = 0; i < 4; ++i)
    w_t[(size_t)(z * 2048 + bx + ty + 8 * i) * 2048 + by + tx] = f2bf(tile[tx][ty + 8 * i]);
}

// ------------------------------------------------------------------
// Wo transpose (reuses w_t after qkv gemm)
// ------------------------------------------------------------------
__global__ __launch_bounds__(256) void transpose_cast(const float* __restrict__ src,
                                                      short* __restrict__ dst) {
  __shared__ float tile[32][33];
  const int bx = blockIdx.x * 32, by = blockIdx.y * 32;
  const int tx = threadIdx.x & 31, ty = threadIdx.x >> 5;
#pragma unroll
  for (int i = 0; i < 4; ++i)
    tile[ty + 8 * i][tx] = src[(size_t)(by + ty + 8 * i) * 2048 + bx + tx];
  __syncthreads();
#pragma unroll
  for (int i = 0; i < 4; ++i)
    dst[(size_t)(bx + ty + 8 * i) * 2048 + by + tx] = f2bf(tile[tx][ty + 8 * i]);
}

// ------------------------------------------------------------------
// 8-phase 256x256 bf16 GEMM (T2+T3+T4+T5): C[M][N] = A[M][K]*Bt[N][K]^T
// ------------------------------------------------------------------
__global__ __launch_bounds__(512, 1) void gemm256(const short* __restrict__ A,
                                                  const short* __restrict__ Bt,
                                                  short* __restrict__ C,
                                                  int M, int N, int K) {
  __shared__ short lds[2][2][16384];  // [buf][A/B][256*64]
  const int t = threadIdx.x;
  const int l = t & 63, w = t >> 6;
  const int wm = w >> 2, wn = w & 3;
  const int lm = l & 15, hi = l >> 4;
  const int lanexor = (lm & 7) << 3;            // shorts
  const int kk0 = (hi * 8) ^ lanexor;           // ks=0 column (shorts)
  const int L = blockIdx.x;
  const int row0 = (L & 7) * 256, col0 = (L >> 3) * 256;
  const int nt = K >> 6;

  const int srow = t >> 3;
  const int scol = 8 * ((t & 7) ^ (srow & 7));
  const short* Ab = A + (size_t)(row0 + srow) * K + scol;
  const short* Bb = Bt + (size_t)(col0 + srow) * K + scol;

#define STAGE(mat, srcbase, h, tau, buf)                                     \
  {                                                                          \
    const short* g_ = (srcbase) + (size_t)(h) * 128 * K + (size_t)(tau) * 64;\
    short* d_ = &lds[buf][mat][(h) * 8192 + t * 8];                          \
    ASYNC16(g_, d_);                                                         \
    ASYNC16(g_ + (size_t)64 * K, d_ + 4096);                                 \
  }

  facc acc[8][4] = {};
  bfrag af[8], bf0[4], bf1[4];

  STAGE(0, Ab, 0, 0, 0); STAGE(0, Ab, 1, 0, 0);
  STAGE(1, Bb, 0, 0, 0); STAGE(1, Bb, 1, 0, 0);
  STAGE(1, Bb, 0, 1, 1); STAGE(1, Bb, 1, 1, 1);
  asm volatile("s_waitcnt vmcnt(4)" ::: "memory");
  __builtin_amdgcn_s_barrier();

  for (int tau = 0; tau < nt; ++tau) {
    const int c = tau & 1;
    const int tA = (tau + 1 < nt) ? tau + 1 : nt - 1;
    const int tB = (tau + 2 < nt) ? tau + 2 : nt - 1;

#define DS_A(qm)                                                             \
  _Pragma("unroll") for (int ii = 0; ii < 4; ++ii) {                         \
    const int row_ = wm * 128 + (qm) * 64 + ii * 16 + lm;                    \
    af[ii * 2 + 0] = *(const bfrag*)&lds[c][0][row_ * 64 + kk0];             \
    af[ii * 2 + 1] = *(const bfrag*)&lds[c][0][row_ * 64 + (kk0 ^ 32)];      \
  }
#define DS_B(qn, arr)                                                        \
  _Pragma("unroll") for (int jj = 0; jj < 2; ++jj) {                         \
    const int row_ = wn * 64 + (qn) * 32 + jj * 16 + lm;                     \
    arr[jj * 2 + 0] = *(const bfrag*)&lds[c][1][row_ * 64 + kk0];            \
    arr[jj * 2 + 1] = *(const bfrag*)&lds[c][1][row_ * 64 + (kk0 ^ 32)];     \
  }
#define QUAD(qm, qn, arr)                                                    \
  _Pragma("unroll") for (int ii = 0; ii < 4; ++ii)                           \
  _Pragma("unroll") for (int jj = 0; jj < 2; ++jj) {                         \
    acc[(qm)*4+ii][(qn)*2+jj] = MFMA16(af[ii*2+0], arr[jj*2+0], acc[(qm)*4+ii][(qn)*2+jj]); \
    acc[(qm)*4+ii][(qn)*2+jj] = MFMA16(af[ii*2+1], arr[jj*2+1], acc[(qm)*4+ii][(qn)*2+jj]); \
  }

    DS_A(0); DS_B(0, bf0);
    STAGE(0, Ab, 0, tA, c ^ 1);
    __builtin_amdgcn_s_barrier();
    asm volatile("s_waitcnt lgkmcnt(0)" ::: "memory");
    __builtin_amdgcn_sched_barrier(0);
    __builtin_amdgcn_s_setprio(1);
    QUAD(0, 0, bf0);
    __builtin_amdgcn_s_setprio(0);
    __builtin_amdgcn_s_barrier();

    DS_B(1, bf1);
    STAGE(0, Ab, 1, tA, c ^ 1);
    __builtin_amdgcn_s_barrier();
    asm volatile("s_waitcnt lgkmcnt(0)" ::: "memory");
    __builtin_amdgcn_sched_barrier(0);
    __builtin_amdgcn_s_setprio(1);
    QUAD(0, 1, bf1);
    __builtin_amdgcn_s_setprio(0);
    __builtin_amdgcn_s_barrier();

    DS_A(1);
    STAGE(1, Bb, 0, tB, c);
    __builtin_amdgcn_s_barrier();
    asm volatile("s_waitcnt lgkmcnt(0)" ::: "memory");
    __builtin_amdgcn_sched_barrier(0);
    __builtin_amdgcn_s_setprio(1);
    QUAD(1, 1, bf1);
    __builtin_amdgcn_s_setprio(0);
    __builtin_amdgcn_s_barrier();

    STAGE(1, Bb, 1, tB, c);
    __builtin_amdgcn_s_setprio(1);
    QUAD(1, 0, bf0);
    __builtin_amdgcn_s_setprio(0);
    asm volatile("s_waitcnt vmcnt(4)" ::: "memory");
    __builtin_amdgcn_s_barrier();
  }

#pragma unroll
  for (int i = 0; i < 8; ++i)
#pragma unroll
    for (int j = 0; j < 4; ++j)
#pragma unroll
      for (int rr = 0; rr < 4; ++rr)
        C[(size_t)(row0 + wm * 128 + i * 16 + hi * 4 + rr) * N +
          col0 + wn * 64 + j * 16 + lm] = f2bf(acc[i][j][rr]);
#undef STAGE
#undef DS_A
#undef DS_B
#undef QUAD
}

// ------------------------------------------------------------------
// bf16 MFMA GEMM (m97 128^2): C[M][N] = A[M][K] * Bt[N][K]^T (out proj)
// ------------------------------------------------------------------
__device__ __forceinline__ void store_c(float* p, float v) { *p = v; }
__device__ __forceinline__ void store_c(short* p, float v) { *p = f2bf(v); }

template <typename OT>
__global__ __launch_bounds__(256) void gemm_bf16_bt(const short* __restrict__ A,
                                                    const short* __restrict__ Bt,
                                                    OT* __restrict__ C,
                                                    int M, int N, int K) {
  __shared__ short As[128 * 32];
  __shared__ short Bs[128 * 32];
  const int t = threadIdx.x;
  const int l = t & 63, w = t >> 6;
  const int wr = w >> 1, wc = w & 1;
  const int nwg = gridDim.x;
  const int L = blockIdx.x;
  const int wg = (L & 7) * (nwg >> 3) + (L >> 3);
  const int nrow = M >> 7;
  const int row0 = (wg % nrow) * 128, col0 = (wg / nrow) * 128;
  facc acc[4][4] = {};

  const int sr = t >> 2;
  const int sk = (t & 3) * 8;
  const short* Ag0 = A + (size_t)(row0 + sr) * K + sk;
  const short* Ag1 = Ag0 + (size_t)64 * K;
  const short* Bg0 = Bt + (size_t)(col0 + sr) * K + sk;
  const short* Bg1 = Bg0 + (size_t)64 * K;
  short* la = As + t * 8;
  short* lb = Bs + t * 8;

  const int lm = l & 15;
  const int lk = (l >> 4) * 8;

  for (int k0 = 0; k0 < K; k0 += 32) {
    ASYNC16(Ag0 + k0, la);
    ASYNC16(Ag1 + k0, la + 2048);
    ASYNC16(Bg0 + k0, lb);
    ASYNC16(Bg1 + k0, lb + 2048);
    __syncthreads();
    bfrag af[4], bf[4];
#pragma unroll
    for (int i = 0; i < 4; ++i)
      af[i] = *(const bfrag*)&As[(wr * 64 + i * 16 + lm) * 32 + lk];
#pragma unroll
    for (int j = 0; j < 4; ++j)
      bf[j] = *(const bfrag*)&Bs[(wc * 64 + j * 16 + lm) * 32 + lk];
#pragma unroll
    for (int i = 0; i < 4; ++i)
#pragma unroll
      for (int j = 0; j < 4; ++j)
        acc[i][j] = MFMA16(af[i], bf[j], acc[i][j]);
    __syncthreads();
  }

  const int orow = row0 + wr * 64 + (l >> 4) * 4;
  const int ocol = col0 + wc * 64 + lm;
#pragma unroll
  for (int i = 0; i < 4; ++i)
#pragma unroll
    for (int j = 0; j < 4; ++j)
#pragma unroll
      for (int rr = 0; rr < 4; ++rr)
        store_c(&C[(size_t)(orow + i * 16 + rr) * N + ocol + j * 16], acc[i][j][rr]);
}

// ------------------------------------------------------------------
// RoPE in place on q AND k slices, table-based, 8 dims/thread
// ------------------------------------------------------------------
__global__ __launch_bounds__(256) void rope_qk(short* __restrict__ qkv,
                                               const float2* __restrict__ tbl) {
  int i = blockIdx.x * 256 + threadIdx.x;  // 524288
  int c = i & 7;
  int h = (i >> 3) & 15;
  int qk = (i >> 7) & 1;
  int n = (i >> 8) & 1023;
  int b = i >> 18;
  short* base = qkv + (size_t)(b * NSEQ + n) * QKV_STR + qk * KOFS + h * HDIM + c * 8;
  const float2* tp = tbl + n * 64 + c * 8;
  bfrag t1 = *(const bfrag*)base, t2 = *(const bfrag*)(base + 64);
  bfrag o1, o2;
#pragma unroll
  for (int j = 0; j < 8; ++j) {
    float2 cssn = tp[j];
    float a = bf2f(t1[j]), bb = bf2f(t2[j]);
    o1[j] = f2bf(a * cssn.x - bb * cssn.y);
    o2[j] = f2bf(a * cssn.y + bb * cssn.x);
  }
  *(bfrag*)base = o1;
  *(bfrag*)(base + 64) = o2;
}

// ------------------------------------------------------------------
// Block mean (roped K) -> f32 kc [b][m][h][d]
// ------------------------------------------------------------------
__global__ __launch_bounds__(256) void block_mean(const short* __restrict__ src,
                                                  float* __restrict__ dst) {
  int i = blockIdx.x * 256 + threadIdx.x;  // 65536
  int d = i & 127;
  int h = (i >> 7) & 15;
  int m = (i >> 11) & 15;
  int b = i >> 15;
  const short* p = src + (size_t)(b * NSEQ + m * BSZ) * QKV_STR + h * HDIM + d;
  float acc = 0.f;
#pragma unroll 8
  for (int j = 0; j < 64; ++j) acc += bf2f(p[(size_t)j * QKV_STR]);
  dst[i] = acc * (1.0f / 64.0f);
}

// ------------------------------------------------------------------
// V transpose -> vt[b][h][d][n], fused V block-mean -> vct[b][h][d][m]
// ------------------------------------------------------------------
__global__ __launch_bounds__(256) void v_transpose(const short* __restrict__ qkv,
                                                   short* __restrict__ vt,
                                                   short* __restrict__ vct) {
  __shared__ short tile[64][136];
  const int n0 = blockIdx.x * 64;
  const int h = blockIdx.y, b = blockIdx.z;
  const int t = threadIdx.x;
#pragma unroll
  for (int it = 0; it < 4; ++it) {
    int idx = t + 256 * it;
    int row = idx >> 4, ch = idx & 15;
    *(bfrag*)&tile[row][ch * 8] =
        *(const bfrag*)&qkv[(size_t)(b * NSEQ + n0 + row) * QKV_STR + VOFS + h * HDIM + ch * 8];
  }
  __syncthreads();
#pragma unroll
  for (int it = 0; it < 4; ++it) {
    int idx = t + 256 * it;
    int d = idx >> 3, ch = idx & 7;
    bfrag tv;
    float s = 0.f;
#pragma unroll
    for (int j = 0; j < 8; ++j) {
      tv[j] = tile[ch * 8 + j][d];
      s += bf2f(tv[j]);
    }
    *(bfrag*)&vt[(((size_t)(b * HN + h) * 128) + d) * 1024 + n0 + ch * 8] = tv;
    s += __shfl_down(s, 4);
    s += __shfl_down(s, 2);
    s += __shfl_down(s, 1);
    if ((t & 7) == 0)
      vct[(((size_t)(b * HN + h) * 128) + d) * 16 + (n0 >> 6)] = f2bf(s * (1.0f / 64.0f));
  }
}

// ------------------------------------------------------------------
// Compressed probs (bf16 pc [b][h][n][16]) + top-8 selection bitmask.
// ------------------------------------------------------------------
__global__ __launch_bounds__(64) void cmp_sel(const short* __restrict__ qkv,
                                              const float* __restrict__ kc,
                                              short* __restrict__ pc,
                                              int* __restrict__ sel) {
  int i = blockIdx.x * 64 + threadIdx.x;  // B*H*N = 32768
  int n = i & 1023;
  int h = (i >> 10) & 15;
  int b = i >> 14;
  const short* qp = qkv + (size_t)(b * NSEQ + n) * QKV_STR + h * HDIM;
  const int nv = (n + 1) >> 6;
  float s[NBLK];
#pragma unroll
  for (int m = 0; m < NBLK; ++m) s[m] = 0.f;
  for (int d0 = 0; d0 < HDIM; d0 += 8) {
    bfrag qv = *(const bfrag*)&qp[d0];
    float qf[8];
#pragma unroll
    for (int dd = 0; dd < 8; ++dd) qf[dd] = bf2f(qv[dd]);
    for (int m = 0; m < nv; ++m) {
      const float4* kp = (const float4*)(kc + ((size_t)((b * NBLK + m) * HN + h) << 7) + d0);
      const float4 k0 = kp[0], k1 = kp[1];
      s[m] += qf[0] * k0.x + qf[1] * k0.y + qf[2] * k0.z + qf[3] * k0.w +
              qf[4] * k1.x + qf[5] * k1.y + qf[6] * k1.z + qf[7] * k1.w;
    }
  }
  float mx = -1e30f;
  for (int m = 0; m < nv; ++m) { s[m] *= SCALE; mx = fmaxf(mx, s[m]); }
  float den = 0.f;
  for (int m = 0; m < nv; ++m) { s[m] = __expf(s[m] - mx); den += s[m]; }
  const float rden = (nv > 0) ? 1.0f / den : 0.f;
  float p[NBLK];
#pragma unroll
  for (int m = 0; m < NBLK; ++m) p[m] = (m < nv) ? s[m] * rden : 0.f;
  bfrag o0, o1;
#pragma unroll
  for (int m = 0; m < 8; ++m) { o0[m] = f2bf(p[m]); o1[m] = f2bf(p[m + 8]); }
  bfrag* pout = (bfrag*)(pc + (size_t)i * 16);
  pout[0] = o0; pout[1] = o1;
  p[n >> 6] += 2.0f;
  int mask = 0;
#pragma unroll
  for (int ss = 0; ss < 8; ++ss) {
    int best = 0;
    float bv = -1e30f;
#pragma unroll
    for (int m = 0; m < NBLK; ++m)
      if (p[m] > bv) { bv = p[m]; best = m; }
    mask |= 1 << best;
    p[best] = -1e30f;
  }
  sel[i] = mask;
}

// ------------------------------------------------------------------
// MFMA attention, 1 wave per (b,h,16-row tile) [R6 structure], with
// the QK^T phase software-pipelined: per f-slot {issue K(f+1); exp of
// sacc[f-1]; MFMA(f)} so the exp VALU work (~200cy) covers the next
// K group's L2 latency instead of stalling after it. V(ks0) issued at
// f=3 under exp(2)+MFMA(3)+exp(3). launch_bounds (64,2): min-waves>=4
// forces the 64-VGPR tier and spills (R7/R8 lesson) -- keep at 2.
// ------------------------------------------------------------------
__global__ __launch_bounds__(64, 2) void attn_mfma(
    const short* __restrict__ qkv, const short* __restrict__ vt,
    const short* __restrict__ vct, const short* __restrict__ pc,
    const int* __restrict__ sel, short* __restrict__ o) {
  const int fid = blockIdx.x;            // 0..2047
  const int xcd = fid & 7;
  const int idx = fid >> 3;              // 0..255
  const int pair = (xcd << 2) | (idx & 3);
  const int rt = 63 - (idx >> 2);        // heavy tiles first
  const int h = pair & 15, b = pair >> 4;

  const int l = threadIdx.x;
  const int lm = l & 15, hi = l >> 4;
  const int nbase = rt * 16;

  __shared__ short p_slc[1024];
  __shared__ short p_swa[1024];

  // Q A-fragments
  const short* qrow = qkv + (size_t)(b * NSEQ + nbase + lm) * QKV_STR + h * HDIM;
  bfrag qf[4];
#pragma unroll
  for (int ks = 0; ks < 4; ++ks) qf[ks] = *(const bfrag*)&qrow[32 * ks + 8 * hi];

  // selection bits
  int selrow = sel[(size_t)(b * HN + h) * NSEQ + nbase + lm];
  int uni = selrow;
#pragma unroll
  for (int m = 1; m < 16; m <<= 1) uni |= __shfl_xor(uni, m);
  int sel4[4];
#pragma unroll
  for (int rg = 0; rg < 4; ++rg) sel4[rg] = __shfl(selrow, 4 * hi + rg);

  const int thi = nbase >> 6;
  const int tlo = (nbase >= 64) ? ((nbase - 64) >> 6) : 0;
  const int wmask = (int)((2u << thi) - (1u << tlo));
  const unsigned am = (unsigned)(uni | wmask) & (unsigned)((2u << thi) - 1);

  facc acc_slc[8] = {}, acc_swa[8] = {};
  float ps_s[4] = {0.f, 0.f, 0.f, 0.f}, ps_w[4] = {0.f, 0.f, 0.f, 0.f};

  const short* kbase0 = qkv + (size_t)(b * NSEQ) * QKV_STR + KOFS + h * HDIM + 8 * hi;
  const short* vtb0 = vt + ((size_t)(b * HN + h) * 128) * 1024 + 8 * hi;

#define LOADK4(d0, d1, d2, d3, colbase)                                     \
  {                                                                         \
    const short* kr_ = kbase0 + (size_t)((colbase) + lm) * QKV_STR;         \
    d0 = *(const bfrag*)(kr_);                                              \
    d1 = *(const bfrag*)(kr_ + 32);                                         \
    d2 = *(const bfrag*)(kr_ + 64);                                         \
    d3 = *(const bfrag*)(kr_ + 96);                                         \
  }

#define MFMA4(dst, s0, s1, s2, s3)                                          \
  dst = MFMA16(qf[0], s0, dst);                                             \
  dst = MFMA16(qf[1], s1, dst);                                             \
  dst = MFMA16(qf[2], s2, dst);                                             \
  dst = MFMA16(qf[3], s3, dst);

#define EXPF(f_)                                                            \
  _Pragma("unroll") for (int rg = 0; rg < 4; ++rg) {                        \
    const int col_ = ct * 64 + 16 * (f_) + lm;                              \
    const int row_ = nbase + 4 * hi + rg;                                   \
    float e_ = __expf(sacc[f_][rg] * SCALE);                                \
    e_ = (col_ <= row_) ? e_ : 0.f;                                         \
    float es_ = ((sel4[rg] >> ct) & 1) ? e_ : 0.f;                          \
    float ew_ = (row_ - col_ <= 64) ? e_ : 0.f;                             \
    ps_s[rg] += es_;                                                        \
    ps_w[rg] += ew_;                                                        \
    const int srow_ = 4 * hi + rg;                                          \
    const int sidx_ = (64 * srow_ + 16 * (f_) + lm) ^ ((srow_ & 7) << 3);   \
    if (do_s) p_slc[sidx_] = f2bf(es_);                                     \
    if (do_w) p_swa[sidx_] = f2bf(ew_);                                     \
  }

  int ct = __ffs((int)am) - 1;           // first active tile (am != 0 always)
  bfrag ka0, ka1, ka2, ka3;              // K(ct, f=0), preloaded
  LOADK4(ka0, ka1, ka2, ka3, ct * 64);

  while (ct >= 0) {
    const unsigned rem = am & ~((2u << ct) - 1);
    const int nct = rem ? (__ffs((int)rem) - 1) : -1;
    const bool do_s = (uni >> ct) & 1;
    const bool do_w = (wmask >> ct) & 1;

    facc sacc[4] = {};
    bfrag kb0, kb1, kb2, kb3, kc0, kc1, kc2, kc3, kd0, kd1, kd2, kd3;

    // f=0: issue K(ct,1); MFMA(0)
    LOADK4(kb0, kb1, kb2, kb3, ct * 64 + 16);
    MFMA4(sacc[0], ka0, ka1, ka2, ka3);

    // f=1: issue K(ct,2); exp(0); MFMA(1)
    LOADK4(kc0, kc1, kc2, kc3, ct * 64 + 32);
    EXPF(0);
    MFMA4(sacc[1], kb0, kb1, kb2, kb3);

    // f=2: issue K(ct,3); exp(1); MFMA(2)
    LOADK4(kd0, kd1, kd2, kd3, ct * 64 + 48);
    EXPF(1);
    MFMA4(sacc[2], kc0, kc1, kc2, kc3);

    // f=3: issue K(next tile, 0) + V(ks0); exp(2); MFMA(3)
    LOADK4(ka0, ka1, ka2, ka3, (nct >= 0 ? nct : ct) * 64);
    const short* vtb = vtb0 + ct * 64;
    bfrag vb0[8];
#pragma unroll
    for (int df = 0; df < 8; ++df)
      vb0[df] = *(const bfrag*)&vtb[(size_t)(16 * df + lm) * 1024];
    EXPF(2);
    MFMA4(sacc[3], kd0, kd1, kd2, kd3);
    EXPF(3);

    // ---- PV (within-wave LDS write->read ordering; no barrier needed)
    {
      const int ridx0 = (64 * lm + 8 * hi) ^ ((lm & 7) << 3);
      bfrag pas = {}, paw = {};
      if (do_s) pas = *(const bfrag*)&p_slc[ridx0];
      if (do_w) paw = *(const bfrag*)&p_swa[ridx0];
      bfrag vb1[8];
#pragma unroll
      for (int df = 0; df < 8; ++df)
        vb1[df] = *(const bfrag*)&vtb[(size_t)(16 * df + lm) * 1024 + 32];
#pragma unroll
      for (int df = 0; df < 8; ++df) {
        if (do_s) acc_slc[df] = MFMA16(pas, vb0[df], acc_slc[df]);
        if (do_w) acc_swa[df] = MFMA16(paw, vb0[df], acc_swa[df]);
      }
      const int ridx1 = (64 * lm + 8 * hi + 32) ^ ((lm & 7) << 3);
      bfrag pas1 = {}, paw1 = {};
      if (do_s) pas1 = *(const bfrag*)&p_slc[ridx1];
      if (do_w) paw1 = *(const bfrag*)&p_swa[ridx1];
#pragma unroll
      for (int df = 0; df < 8; ++df) {
        if (do_s) acc_slc[df] = MFMA16(pas1, vb1[df], acc_slc[df]);
        if (do_w) acc_swa[df] = MFMA16(paw1, vb1[df], acc_swa[df]);
      }
    }
    ct = nct;
  }
#undef LOADK4
#undef MFMA4
#undef EXPF

  // ---- compressed branch: O_cmp = Pc[16x16] * Vc[16x128], K padded to 32
  facc acc_cmp[8] = {};
  {
    bfrag pa = {};
    if (hi < 2)
      pa = *(const bfrag*)&pc[((size_t)(b * HN + h) * NSEQ + nbase + lm) * 16 + 8 * hi];
#pragma unroll
    for (int df = 0; df < 8; ++df) {
      bfrag vb = {};
      if (hi < 2)
        vb = *(const bfrag*)&vct[(((size_t)(b * HN + h) * 128) + 16 * df + lm) * 16 + 8 * hi];
      acc_cmp[df] = MFMA16(pa, vb, acc_cmp[df]);
    }
  }

  // ---- denominators: reduce across the 16 col-lanes
#pragma unroll
  for (int m = 1; m < 16; m <<= 1) {
#pragma unroll
    for (int rg = 0; rg < 4; ++rg) {
      ps_s[rg] += __shfl_xor(ps_s[rg], m);
      ps_w[rg] += __shfl_xor(ps_w[rg], m);
    }
  }

  float inv_s[4], inv_w[4], gcv[4], gsv[4], gwv[4];
#pragma unroll
  for (int rg = 0; rg < 4; ++rg) {
    inv_s[rg] = 1.0f / ps_s[rg];
    inv_w[rg] = 1.0f / ps_w[rg];
    const short* gp = qkv + (size_t)(b * NSEQ + nbase + 4 * hi + rg) * QKV_STR + GOFS;
    gcv[rg] = 1.0f / (1.0f + __expf(-bf2f(gp[h])));
    gsv[rg] = 1.0f / (1.0f + __expf(-bf2f(gp[16 + h])));
    gwv[rg] = 1.0f / (1.0f + __expf(-bf2f(gp[32 + h])));
  }

  short* obase = o + (size_t)(b * NSEQ + nbase) * 2048 + h * HDIM;
#pragma unroll
  for (int df = 0; df < 8; ++df)
#pragma unroll
    for (int rg = 0; rg < 4; ++rg) {
      float val = gcv[rg] * acc_cmp[df][rg] +
                  gsv[rg] * acc_slc[df][rg] * inv_s[rg] +
                  gwv[rg] * acc_swa[df][rg] * inv_w[rg];
      obase[(size_t)(4 * hi + rg) * 2048 + 16 * df + lm] = f2bf(val);
    }
}

// ------------------------------------------------------------------
extern "C" void kernel_launch(void* const* d_in, const int* in_sizes, int n_in,
                              void* d_out, int out_size, void* d_ws, size_t ws_size,
                              hipStream_t stream) {
  const float* x  = (const float*)d_in[0];
  const float* Wq = (const float*)d_in[1];
  const float* Wk = (const float*)d_in[2];
  const float* Wv = (const float*)d_in[3];
  const float* Wg = (const float*)d_in[4];
  const float* Wo = (const float*)d_in[5];
  float* out = (float*)d_out;

  char* w = (char*)d_ws;
  short* x_bf = (short*)w;            // 8.4 MB (reused as o_bf)
  short* o_bf = x_bf;
  w += (size_t)2048 * 2048 * 2;
  short* w_t  = (short*)w;            // 26.2 MB (rows 6272..6399 unused pad)
  w += (size_t)6400 * 2048 * 2;
  short* qkv  = (short*)w;            // 26.2 MB (stride 6400; gate at 6144)
  w += (size_t)2048 * 6400 * 2;
  float* kc   = (float*)w; w += (size_t)65536 * 4;
  short* vct  = (short*)w; w += (size_t)65536 * 2;
  short* pcb  = (short*)w; w += (size_t)524288 * 2;
  int*   sel  = (int*)w;   w += (size_t)32768 * 4;
  short* vt   = (short*)w; w += (size_t)4194304 * 2;  // 8.4 MB
  float2* tbl = (float2*)w; w += (size_t)65536 * 8;   // 0.5 MB

  const dim3 blk(256);
  prep<<<dim3(64, 64, 6), blk, 0, stream>>>(Wq, Wk, Wv, Wg, x, w_t, x_bf, tbl);
  gemm256<<<200, dim3(512), 0, stream>>>(x_bf, w_t, qkv, 2048, 6400, 2048);
  rope_qk<<<2048, blk, 0, stream>>>(qkv, tbl);
  block_mean<<<256, blk, 0, stream>>>(qkv + KOFS, kc);
  v_transpose<<<dim3(16, 16, 2), blk, 0, stream>>>(qkv, vt, vct);
  cmp_sel<<<512, dim3(64), 0, stream>>>(qkv, kc, pcb, sel);
  transpose_cast<<<dim3(64, 64), blk, 0, stream>>>(Wo, w_t);
  attn_mfma<<<2048, dim3(64), 0, stream>>>(qkv, vt, vct, pcb, sel, o_bf);
  gemm_bf16_bt<float><<<256, blk, 0, stream>>>(o_bf, w_t, out, 2048, 2048, 2048);
}

// Round 12
// 264.860 us; speedup vs baseline: 1.0010x; 1.0010x over previous
//
#include <hip/hip_runtime.h>
#include <hip/hip_bf16.h>

// NSA forward: B=2, N=1024, D=2048, H=16, HD=128, BS=64, SEL=8, WIN=64
#define HN   16
#define HDIM 128
#define NSEQ 1024
#define NBLK 16
#define BSZ  64
#define SCALE 0.08838834764831845f
#define QKV_STR 6400   // row stride of fused qkv+gate buffer (bf16), padded to 25*256
#define KOFS 2048
#define VOFS 4096
#define GOFS 6144

typedef __attribute__((ext_vector_type(8))) short bfrag;   // 8 bf16 (4 VGPRs)
typedef __attribute__((ext_vector_type(4))) float facc;    // MFMA accumulator

__device__ __forceinline__ float bf2f(short s) {
  union { unsigned u; float f; } cv;
  cv.u = ((unsigned)(unsigned short)s) << 16;
  return cv.f;
}
__device__ __forceinline__ short f2bf(float f) {
  unsigned u = __float_as_uint(f);
  u = (u + 0x7fff + ((u >> 16) & 1)) >> 16;  // RNE
  return (short)u;
}

#define ASYNC16(gp, lp)                                                    \
  __builtin_amdgcn_global_load_lds(                                        \
      (const __attribute__((address_space(1))) void*)(gp),                 \
      (__attribute__((address_space(3))) void*)(lp), 16, 0, 0)

#define MFMA16(a, b, c) __builtin_amdgcn_mfma_f32_16x16x32_bf16(a, b, c, 0, 0, 0)

// ------------------------------------------------------------------
// prep: z=0..2 -> Wq/Wk/Wv transpose-cast into w_t rows z*2048..
//       z=3   -> Wg transposed + zero-padded to rows 6144..6271
//       z=4   -> x cast to bf16
//       z=5   -> RoPE cos/sin table
// ------------------------------------------------------------------
__global__ __launch_bounds__(256) void prep(const float* __restrict__ Wq,
                                            const float* __restrict__ Wk,
                                            const float* __restrict__ Wv,
                                            const float* __restrict__ Wg,
                                            const float* __restrict__ x,
                                            short* __restrict__ w_t,
                                            short* __restrict__ x_bf,
                                            float2* __restrict__ tbl) {
  __shared__ float tile[32][33];
  const int z = blockIdx.z;
  const int bx = blockIdx.x * 32, by = blockIdx.y * 32;
  const int tx = threadIdx.x & 31, ty = threadIdx.x >> 5;
  if (z == 5) {
    if (blockIdx.y >= 4) return;
    int i = (blockIdx.y * 64 + blockIdx.x) * 256 + threadIdx.x;  // < 65536
    int d = i & 63, n = i >> 6;
    float inv = expf(-(float)d * (9.210340371976184f / 64.0f));
    float sn, cs;
    sincosf((float)n * inv, &sn, &cs);
    tbl[i] = make_float2(cs, sn);
    return;
  }
  if (z == 4) {
#pragma unroll
    for (int i = 0; i < 4; ++i) {
      const int row = by + ty + 8 * i;
      x_bf[(size_t)row * 2048 + bx + tx] = f2bf(x[(size_t)row * 2048 + bx + tx]);
    }
    return;
  }
  if (z == 3) {
    if (blockIdx.x >= 4) return;  // only 128 dst rows
#pragma unroll
    for (int i = 0; i < 4; ++i) {
      const int c = bx + tx;
      tile[ty + 8 * i][tx] = (c < 48) ? Wg[(size_t)(by + ty + 8 * i) * 48 + c] : 0.f;
    }
    __syncthreads();
#pragma unroll
    for (int i = 0; i < 4; ++i)
      w_t[(size_t)(GOFS + bx + ty + 8 * i) * 2048 + by + tx] = f2bf(tile[tx][ty + 8 * i]);
    return;
  }
  const float* src = (z == 0) ? Wq : (z == 1) ? Wk : Wv;
#pragma unroll
  for (int i = 0; i < 4; ++i)
    tile[ty + 8 * i][tx] = src[(size_t)(by + ty + 8 * i) * 2048 + bx + tx];
  __syncthreads();
#pragma unroll
  for (int i = 0; i < 4; ++i)
    w_t[(size_t)(z * 2048 + bx + ty + 8 * i) * 2048 + by + tx] = f2bf(tile[tx][ty + 8 * i]);
}

// ------------------------------------------------------------------
// Wo transpose (reuses w_t after qkv gemm)
// ------------------------------------------------------------------
__global__ __launch_bounds__(256) void transpose_cast(const float* __restrict__ src,
                                                      short* __restrict__ dst) {
  __shared__ float tile[32][33];
  const int bx = blockIdx.x * 32, by = blockIdx.y * 32;
  const int tx = threadIdx.x & 31, ty = threadIdx.x >> 5;
#pragma unroll
  for (int i = 0; i < 4; ++i)
    tile[ty + 8 * i][tx] = src[(size_t)(by + ty + 8 * i) * 2048 + bx + tx];
  __syncthreads();
#pragma unroll
  for (int i = 0; i < 4; ++i)
    dst[(size_t)(bx + ty + 8 * i) * 2048 + by + tx] = f2bf(tile[tx][ty + 8 * i]);
}

// ------------------------------------------------------------------
// 8-phase 256x256 bf16 GEMM (T2+T3+T4+T5): C[M][N] = A[M][K]*Bt[N][K]^T
// XCD col-chunk swizzle: each XCD owns ~nwg/8 consecutive items in
// (row-fast, col-slow) order -> ~4 B col-panels (4MB, L2-resident)
// shared by 8 row-blocks, instead of streaming all 25 panels.
// ------------------------------------------------------------------
__global__ __launch_bounds__(512, 1) void gemm256(const short* __restrict__ A,
                                                  const short* __restrict__ Bt,
                                                  short* __restrict__ C,
                                                  int M, int N, int K) {
  __shared__ short lds[2][2][16384];  // [buf][A/B][256*64]
  const int t = threadIdx.x;
  const int l = t & 63, w = t >> 6;
  const int wm = w >> 2, wn = w & 3;
  const int lm = l & 15, hi = l >> 4;
  const int lanexor = (lm & 7) << 3;            // shorts
  const int kk0 = (hi * 8) ^ lanexor;           // ks=0 column (shorts)
  const int L = blockIdx.x;
  const int item = (L & 7) * (gridDim.x >> 3) + (L >> 3);  // bijective (nwg%8==0)
  const int nrow = M >> 8;
  const int row0 = (item % nrow) * 256, col0 = (item / nrow) * 256;
  const int nt = K >> 6;

  const int srow = t >> 3;
  const int scol = 8 * ((t & 7) ^ (srow & 7));
  const short* Ab = A + (size_t)(row0 + srow) * K + scol;
  const short* Bb = Bt + (size_t)(col0 + srow) * K + scol;

#define STAGE(mat, srcbase, h, tau, buf)                                     \
  {                                                                          \
    const short* g_ = (srcbase) + (size_t)(h) * 128 * K + (size_t)(tau) * 64;\
    short* d_ = &lds[buf][mat][(h) * 8192 + t * 8];                          \
    ASYNC16(g_, d_);                                                         \
    ASYNC16(g_ + (size_t)64 * K, d_ + 4096);                                 \
  }

  facc acc[8][4] = {};
  bfrag af[8], bf0[4], bf1[4];

  STAGE(0, Ab, 0, 0, 0); STAGE(0, Ab, 1, 0, 0);
  STAGE(1, Bb, 0, 0, 0); STAGE(1, Bb, 1, 0, 0);
  STAGE(1, Bb, 0, 1, 1); STAGE(1, Bb, 1, 1, 1);
  asm volatile("s_waitcnt vmcnt(4)" ::: "memory");
  __builtin_amdgcn_s_barrier();

  for (int tau = 0; tau < nt; ++tau) {
    const int c = tau & 1;
    const int tA = (tau + 1 < nt) ? tau + 1 : nt - 1;
    const int tB = (tau + 2 < nt) ? tau + 2 : nt - 1;

#define DS_A(qm)                                                             \
  _Pragma("unroll") for (int ii = 0; ii < 4; ++ii) {                         \
    const int row_ = wm * 128 + (qm) * 64 + ii * 16 + lm;                    \
    af[ii * 2 + 0] = *(const bfrag*)&lds[c][0][row_ * 64 + kk0];             \
    af[ii * 2 + 1] = *(const bfrag*)&lds[c][0][row_ * 64 + (kk0 ^ 32)];      \
  }
#define DS_B(qn, arr)                                                        \
  _Pragma("unroll") for (int jj = 0; jj < 2; ++jj) {                         \
    const int row_ = wn * 64 + (qn) * 32 + jj * 16 + lm;                     \
    arr[jj * 2 + 0] = *(const bfrag*)&lds[c][1][row_ * 64 + kk0];            \
    arr[jj * 2 + 1] = *(const bfrag*)&lds[c][1][row_ * 64 + (kk0 ^ 32)];     \
  }
#define QUAD(qm, qn, arr)                                                    \
  _Pragma("unroll") for (int ii = 0; ii < 4; ++ii)                           \
  _Pragma("unroll") for (int jj = 0; jj < 2; ++jj) {                         \
    acc[(qm)*4+ii][(qn)*2+jj] = MFMA16(af[ii*2+0], arr[jj*2+0], acc[(qm)*4+ii][(qn)*2+jj]); \
    acc[(qm)*4+ii][(qn)*2+jj] = MFMA16(af[ii*2+1], arr[jj*2+1], acc[(qm)*4+ii][(qn)*2+jj]); \
  }

    DS_A(0); DS_B(0, bf0);
    STAGE(0, Ab, 0, tA, c ^ 1);
    __builtin_amdgcn_s_barrier();
    asm volatile("s_waitcnt lgkmcnt(0)" ::: "memory");
    __builtin_amdgcn_sched_barrier(0);
    __builtin_amdgcn_s_setprio(1);
    QUAD(0, 0, bf0);
    __builtin_amdgcn_s_setprio(0);
    __builtin_amdgcn_s_barrier();

    DS_B(1, bf1);
    STAGE(0, Ab, 1, tA, c ^ 1);
    __builtin_amdgcn_s_barrier();
    asm volatile("s_waitcnt lgkmcnt(0)" ::: "memory");
    __builtin_amdgcn_sched_barrier(0);
    __builtin_amdgcn_s_setprio(1);
    QUAD(0, 1, bf1);
    __builtin_amdgcn_s_setprio(0);
    __builtin_amdgcn_s_barrier();

    DS_A(1);
    STAGE(1, Bb, 0, tB, c);
    __builtin_amdgcn_s_barrier();
    asm volatile("s_waitcnt lgkmcnt(0)" ::: "memory");
    __builtin_amdgcn_sched_barrier(0);
    __builtin_amdgcn_s_setprio(1);
    QUAD(1, 1, bf1);
    __builtin_amdgcn_s_setprio(0);
    __builtin_amdgcn_s_barrier();

    STAGE(1, Bb, 1, tB, c);
    __builtin_amdgcn_s_setprio(1);
    QUAD(1, 0, bf0);
    __builtin_amdgcn_s_setprio(0);
    asm volatile("s_waitcnt vmcnt(4)" ::: "memory");
    __builtin_amdgcn_s_barrier();
  }

#pragma unroll
  for (int i = 0; i < 8; ++i)
#pragma unroll
    for (int j = 0; j < 4; ++j)
#pragma unroll
      for (int rr = 0; rr < 4; ++rr)
        C[(size_t)(row0 + wm * 128 + i * 16 + hi * 4 + rr) * N +
          col0 + wn * 64 + j * 16 + lm] = f2bf(acc[i][j][rr]);
#undef STAGE
#undef DS_A
#undef DS_B
#undef QUAD
}

// ------------------------------------------------------------------
// bf16 MFMA GEMM (m97 128^2): C[M][N] = A[M][K] * Bt[N][K]^T (out proj)
// ------------------------------------------------------------------
__device__ __forceinline__ void store_c(float* p, float v) { *p = v; }
__device__ __forceinline__ void store_c(short* p, float v) { *p = f2bf(v); }

template <typename OT>
__global__ __launch_bounds__(256) void gemm_bf16_bt(const short* __restrict__ A,
                                                    const short* __restrict__ Bt,
                                                    OT* __restrict__ C,
                                                    int M, int N, int K) {
  __shared__ short As[128 * 32];
  __shared__ short Bs[128 * 32];
  const int t = threadIdx.x;
  const int l = t & 63, w = t >> 6;
  const int wr = w >> 1, wc = w & 1;
  const int nwg = gridDim.x;
  const int L = blockIdx.x;
  const int wg = (L & 7) * (nwg >> 3) + (L >> 3);
  const int nrow = M >> 7;
  const int row0 = (wg % nrow) * 128, col0 = (wg / nrow) * 128;
  facc acc[4][4] = {};

  const int sr = t >> 2;
  const int sk = (t & 3) * 8;
  const short* Ag0 = A + (size_t)(row0 + sr) * K + sk;
  const short* Ag1 = Ag0 + (size_t)64 * K;
  const short* Bg0 = Bt + (size_t)(col0 + sr) * K + sk;
  const short* Bg1 = Bg0 + (size_t)64 * K;
  short* la = As + t * 8;
  short* lb = Bs + t * 8;

  const int lm = l & 15;
  const int lk = (l >> 4) * 8;

  for (int k0 = 0; k0 < K; k0 += 32) {
    ASYNC16(Ag0 + k0, la);
    ASYNC16(Ag1 + k0, la + 2048);
    ASYNC16(Bg0 + k0, lb);
    ASYNC16(Bg1 + k0, lb + 2048);
    __syncthreads();
    bfrag af[4], bf[4];
#pragma unroll
    for (int i = 0; i < 4; ++i)
      af[i] = *(const bfrag*)&As[(wr * 64 + i * 16 + lm) * 32 + lk];
#pragma unroll
    for (int j = 0; j < 4; ++j)
      bf[j] = *(const bfrag*)&Bs[(wc * 64 + j * 16 + lm) * 32 + lk];
#pragma unroll
    for (int i = 0; i < 4; ++i)
#pragma unroll
      for (int j = 0; j < 4; ++j)
        acc[i][j] = MFMA16(af[i], bf[j], acc[i][j]);
    __syncthreads();
  }

  const int orow = row0 + wr * 64 + (l >> 4) * 4;
  const int ocol = col0 + wc * 64 + lm;
#pragma unroll
  for (int i = 0; i < 4; ++i)
#pragma unroll
    for (int j = 0; j < 4; ++j)
#pragma unroll
      for (int rr = 0; rr < 4; ++rr)
        store_c(&C[(size_t)(orow + i * 16 + rr) * N + ocol + j * 16], acc[i][j][rr]);
}

// ------------------------------------------------------------------
// RoPE in place on q AND k slices, table-based, 8 dims/thread
// ------------------------------------------------------------------
__global__ __launch_bounds__(256) void rope_qk(short* __restrict__ qkv,
                                               const float2* __restrict__ tbl) {
  int i = blockIdx.x * 256 + threadIdx.x;  // 524288
  int c = i & 7;
  int h = (i >> 3) & 15;
  int qk = (i >> 7) & 1;
  int n = (i >> 8) & 1023;
  int b = i >> 18;
  short* base = qkv + (size_t)(b * NSEQ + n) * QKV_STR + qk * KOFS + h * HDIM + c * 8;
  const float2* tp = tbl + n * 64 + c * 8;
  bfrag t1 = *(const bfrag*)base, t2 = *(const bfrag*)(base + 64);
  bfrag o1, o2;
#pragma unroll
  for (int j = 0; j < 8; ++j) {
    float2 cssn = tp[j];
    float a = bf2f(t1[j]), bb = bf2f(t2[j]);
    o1[j] = f2bf(a * cssn.x - bb * cssn.y);
    o2[j] = f2bf(a * cssn.y + bb * cssn.x);
  }
  *(bfrag*)base = o1;
  *(bfrag*)(base + 64) = o2;
}

// ------------------------------------------------------------------
// Block mean (roped K) -> f32 kc [b][m][h][d]
// ------------------------------------------------------------------
__global__ __launch_bounds__(256) void block_mean(const short* __restrict__ src,
                                                  float* __restrict__ dst) {
  int i = blockIdx.x * 256 + threadIdx.x;  // 65536
  int d = i & 127;
  int h = (i >> 7) & 15;
  int m = (i >> 11) & 15;
  int b = i >> 15;
  const short* p = src + (size_t)(b * NSEQ + m * BSZ) * QKV_STR + h * HDIM + d;
  float acc = 0.f;
#pragma unroll 8
  for (int j = 0; j < 64; ++j) acc += bf2f(p[(size_t)j * QKV_STR]);
  dst[i] = acc * (1.0f / 64.0f);
}

// ------------------------------------------------------------------
// V transpose -> vt[b][h][d][n], fused V block-mean -> vct[b][h][d][m]
// ------------------------------------------------------------------
__global__ __launch_bounds__(256) void v_transpose(const short* __restrict__ qkv,
                                                   short* __restrict__ vt,
                                                   short* __restrict__ vct) {
  __shared__ short tile[64][136];
  const int n0 = blockIdx.x * 64;
  const int h = blockIdx.y, b = blockIdx.z;
  const int t = threadIdx.x;
#pragma unroll
  for (int it = 0; it < 4; ++it) {
    int idx = t + 256 * it;
    int row = idx >> 4, ch = idx & 15;
    *(bfrag*)&tile[row][ch * 8] =
        *(const bfrag*)&qkv[(size_t)(b * NSEQ + n0 + row) * QKV_STR + VOFS + h * HDIM + ch * 8];
  }
  __syncthreads();
#pragma unroll
  for (int it = 0; it < 4; ++it) {
    int idx = t + 256 * it;
    int d = idx >> 3, ch = idx & 7;
    bfrag tv;
    float s = 0.f;
#pragma unroll
    for (int j = 0; j < 8; ++j) {
      tv[j] = tile[ch * 8 + j][d];
      s += bf2f(tv[j]);
    }
    *(bfrag*)&vt[(((size_t)(b * HN + h) * 128) + d) * 1024 + n0 + ch * 8] = tv;
    s += __shfl_down(s, 4);
    s += __shfl_down(s, 2);
    s += __shfl_down(s, 1);
    if ((t & 7) == 0)
      vct[(((size_t)(b * HN + h) * 128) + d) * 16 + (n0 >> 6)] = f2bf(s * (1.0f / 64.0f));
  }
}

// ------------------------------------------------------------------
// Compressed probs (bf16 pc [b][h][n][16]) + top-8 selection bitmask.
// ------------------------------------------------------------------
__global__ __launch_bounds__(64) void cmp_sel(const short* __restrict__ qkv,
                                              const float* __restrict__ kc,
                                              short* __restrict__ pc,
                                              int* __restrict__ sel) {
  int i = blockIdx.x * 64 + threadIdx.x;  // B*H*N = 32768
  int n = i & 1023;
  int h = (i >> 10) & 15;
  int b = i >> 14;
  const short* qp = qkv + (size_t)(b * NSEQ + n) * QKV_STR + h * HDIM;
  const int nv = (n + 1) >> 6;
  float s[NBLK];
#pragma unroll
  for (int m = 0; m < NBLK; ++m) s[m] = 0.f;
  for (int d0 = 0; d0 < HDIM; d0 += 8) {
    bfrag qv = *(const bfrag*)&qp[d0];
    float qf[8];
#pragma unroll
    for (int dd = 0; dd < 8; ++dd) qf[dd] = bf2f(qv[dd]);
    for (int m = 0; m < nv; ++m) {
      const float4* kp = (const float4*)(kc + ((size_t)((b * NBLK + m) * HN + h) << 7) + d0);
      const float4 k0 = kp[0], k1 = kp[1];
      s[m] += qf[0] * k0.x + qf[1] * k0.y + qf[2] * k0.z + qf[3] * k0.w +
              qf[4] * k1.x + qf[5] * k1.y + qf[6] * k1.z + qf[7] * k1.w;
    }
  }
  float mx = -1e30f;
  for (int m = 0; m < nv; ++m) { s[m] *= SCALE; mx = fmaxf(mx, s[m]); }
  float den = 0.f;
  for (int m = 0; m < nv; ++m) { s[m] = __expf(s[m] - mx); den += s[m]; }
  const float rden = (nv > 0) ? 1.0f / den : 0.f;
  float p[NBLK];
#pragma unroll
  for (int m = 0; m < NBLK; ++m) p[m] = (m < nv) ? s[m] * rden : 0.f;
  bfrag o0, o1;
#pragma unroll
  for (int m = 0; m < 8; ++m) { o0[m] = f2bf(p[m]); o1[m] = f2bf(p[m + 8]); }
  bfrag* pout = (bfrag*)(pc + (size_t)i * 16);
  pout[0] = o0; pout[1] = o1;
  p[n >> 6] += 2.0f;
  int mask = 0;
#pragma unroll
  for (int ss = 0; ss < 8; ++ss) {
    int best = 0;
    float bv = -1e30f;
#pragma unroll
    for (int m = 0; m < NBLK; ++m)
      if (p[m] > bv) { bv = p[m]; best = m; }
    mask |= 1 << best;
    p[best] = -1e30f;
  }
  sel[i] = mask;
}

// ------------------------------------------------------------------
// MFMA attention, 1 wave per (b,h,16-row tile), software-pipelined:
// per f-slot {issue K(f+1); exp(f-1); MFMA(f)}; V loads hoisted to
// f=1/f=2 so PV finds them resident (all V latency hidden under
// exp+MFMA). launch_bounds (64,2): min-waves>=4 forces the 64-VGPR
// tier and spills (R7/R8 lesson) -- keep at 2 (256-VGPR cap).
// ------------------------------------------------------------------
__global__ __launch_bounds__(64, 2) void attn_mfma(
    const short* __restrict__ qkv, const short* __restrict__ vt,
    const short* __restrict__ vct, const short* __restrict__ pc,
    const int* __restrict__ sel, short* __restrict__ o) {
  const int fid = blockIdx.x;            // 0..2047
  const int xcd = fid & 7;
  const int idx = fid >> 3;              // 0..255
  const int pair = (xcd << 2) | (idx & 3);
  const int rt = 63 - (idx >> 2);        // heavy tiles first
  const int h = pair & 15, b = pair >> 4;

  const int l = threadIdx.x;
  const int lm = l & 15, hi = l >> 4;
  const int nbase = rt * 16;

  __shared__ short p_slc[1024];
  __shared__ short p_swa[1024];

  // Q A-fragments
  const short* qrow = qkv + (size_t)(b * NSEQ + nbase + lm) * QKV_STR + h * HDIM;
  bfrag qf[4];
#pragma unroll
  for (int ks = 0; ks < 4; ++ks) qf[ks] = *(const bfrag*)&qrow[32 * ks + 8 * hi];

  // selection bits
  int selrow = sel[(size_t)(b * HN + h) * NSEQ + nbase + lm];
  int uni = selrow;
#pragma unroll
  for (int m = 1; m < 16; m <<= 1) uni |= __shfl_xor(uni, m);
  int sel4[4];
#pragma unroll
  for (int rg = 0; rg < 4; ++rg) sel4[rg] = __shfl(selrow, 4 * hi + rg);

  const int thi = nbase >> 6;
  const int tlo = (nbase >= 64) ? ((nbase - 64) >> 6) : 0;
  const int wmask = (int)((2u << thi) - (1u << tlo));
  const unsigned am = (unsigned)(uni | wmask) & (unsigned)((2u << thi) - 1);

  facc acc_slc[8] = {}, acc_swa[8] = {};
  float ps_s[4] = {0.f, 0.f, 0.f, 0.f}, ps_w[4] = {0.f, 0.f, 0.f, 0.f};

  const short* kbase0 = qkv + (size_t)(b * NSEQ) * QKV_STR + KOFS + h * HDIM + 8 * hi;
  const short* vtb0 = vt + ((size_t)(b * HN + h) * 128) * 1024 + 8 * hi;

#define LOADK4(d0, d1, d2, d3, colbase)                                     \
  {                                                                         \
    const short* kr_ = kbase0 + (size_t)((colbase) + lm) * QKV_STR;         \
    d0 = *(const bfrag*)(kr_);                                              \
    d1 = *(const bfrag*)(kr_ + 32);                                         \
    d2 = *(const bfrag*)(kr_ + 64);                                         \
    d3 = *(const bfrag*)(kr_ + 96);                                         \
  }

#define MFMA4(dst, s0, s1, s2, s3)                                          \
  dst = MFMA16(qf[0], s0, dst);                                             \
  dst = MFMA16(qf[1], s1, dst);                                             \
  dst = MFMA16(qf[2], s2, dst);                                             \
  dst = MFMA16(qf[3], s3, dst);

#define EXPF(f_)                                                            \
  _Pragma("unroll") for (int rg = 0; rg < 4; ++rg) {                        \
    const int col_ = ct * 64 + 16 * (f_) + lm;                              \
    const int row_ = nbase + 4 * hi + rg;                                   \
    float e_ = __expf(sacc[f_][rg] * SCALE);                                \
    e_ = (col_ <= row_) ? e_ : 0.f;                                         \
    float es_ = ((sel4[rg] >> ct) & 1) ? e_ : 0.f;                          \
    float ew_ = (row_ - col_ <= 64) ? e_ : 0.f;                             \
    ps_s[rg] += es_;                                                        \
    ps_w[rg] += ew_;                                                        \
    const int srow_ = 4 * hi + rg;                                          \
    const int sidx_ = (64 * srow_ + 16 * (f_) + lm) ^ ((srow_ & 7) << 3);   \
    if (do_s) p_slc[sidx_] = f2bf(es_);                                     \
    if (do_w) p_swa[sidx_] = f2bf(ew_);                                     \
  }

  int ct = __ffs((int)am) - 1;           // first active tile (am != 0 always)
  bfrag ka0, ka1, ka2, ka3;              // K(ct, f=0), preloaded
  LOADK4(ka0, ka1, ka2, ka3, ct * 64);

  while (ct >= 0) {
    const unsigned rem = am & ~((2u << ct) - 1);
    const int nct = rem ? (__ffs((int)rem) - 1) : -1;
    const bool do_s = (uni >> ct) & 1;
    const bool do_w = (wmask >> ct) & 1;
    const short* vtb = vtb0 + ct * 64;

    facc sacc[4] = {};
    bfrag kb0, kb1, kb2, kb3, kc0, kc1, kc2, kc3, kd0, kd1, kd2, kd3;
    bfrag vb0[8], vb1[8];

    // f=0: issue K(ct,1); MFMA(0)
    LOADK4(kb0, kb1, kb2, kb3, ct * 64 + 16);
    MFMA4(sacc[0], ka0, ka1, ka2, ka3);

    // f=1: issue K(ct,2) + V(ks0); exp(0); MFMA(1)
    LOADK4(kc0, kc1, kc2, kc3, ct * 64 + 32);
#pragma unroll
    for (int df = 0; df < 8; ++df)
      vb0[df] = *(const bfrag*)&vtb[(size_t)(16 * df + lm) * 1024];
    EXPF(0);
    MFMA4(sacc[1], kb0, kb1, kb2, kb3);

    // f=2: issue K(ct,3) + V(ks1); exp(1); MFMA(2)
    LOADK4(kd0, kd1, kd2, kd3, ct * 64 + 48);
#pragma unroll
    for (int df = 0; df < 8; ++df)
      vb1[df] = *(const bfrag*)&vtb[(size_t)(16 * df + lm) * 1024 + 32];
    EXPF(1);
    MFMA4(sacc[2], kc0, kc1, kc2, kc3);

    // f=3: issue K(next tile, 0); exp(2); MFMA(3); exp(3)
    LOADK4(ka0, ka1, ka2, ka3, (nct >= 0 ? nct : ct) * 64);
    EXPF(2);
    MFMA4(sacc[3], kd0, kd1, kd2, kd3);
    EXPF(3);

    // ---- PV (within-wave LDS write->read ordering; no barrier needed)
    {
      const int ridx0 = (64 * lm + 8 * hi) ^ ((lm & 7) << 3);
      bfrag pas = {}, paw = {};
      if (do_s) pas = *(const bfrag*)&p_slc[ridx0];
      if (do_w) paw = *(const bfrag*)&p_swa[ridx0];
#pragma unroll
      for (int df = 0; df < 8; ++df) {
        if (do_s) acc_slc[df] = MFMA16(pas, vb0[df], acc_slc[df]);
        if (do_w) acc_swa[df] = MFMA16(paw, vb0[df], acc_swa[df]);
      }
      const int ridx1 = (64 * lm + 8 * hi + 32) ^ ((lm & 7) << 3);
      bfrag pas1 = {}, paw1 = {};
      if (do_s) pas1 = *(const bfrag*)&p_slc[ridx1];
      if (do_w) paw1 = *(const bfrag*)&p_swa[ridx1];
#pragma unroll
      for (int df = 0; df < 8; ++df) {
        if (do_s) acc_slc[df] = MFMA16(pas1, vb1[df], acc_slc[df]);
        if (do_w) acc_swa[df] = MFMA16(paw1, vb1[df], acc_swa[df]);
      }
    }
    ct = nct;
  }
#undef LOADK4
#undef MFMA4
#undef EXPF

  // ---- compressed branch: O_cmp = Pc[16x16] * Vc[16x128], K padded to 32
  facc acc_cmp[8] = {};
  {
    bfrag pa = {};
    if (hi < 2)
      pa = *(const bfrag*)&pc[((size_t)(b * HN + h) * NSEQ + nbase + lm) * 16 + 8 * hi];
#pragma unroll
    for (int df = 0; df < 8; ++df) {
      bfrag vb = {};
      if (hi < 2)
        vb = *(const bfrag*)&vct[(((size_t)(b * HN + h) * 128) + 16 * df + lm) * 16 + 8 * hi];
      acc_cmp[df] = MFMA16(pa, vb, acc_cmp[df]);
    }
  }

  // ---- denominators: reduce across the 16 col-lanes
#pragma unroll
  for (int m = 1; m < 16; m <<= 1) {
#pragma unroll
    for (int rg = 0; rg < 4; ++rg) {
      ps_s[rg] += __shfl_xor(ps_s[rg], m);
      ps_w[rg] += __shfl_xor(ps_w[rg], m);
    }
  }

  float inv_s[4], inv_w[4], gcv[4], gsv[4], gwv[4];
#pragma unroll
  for (int rg = 0; rg < 4; ++rg) {
    inv_s[rg] = 1.0f / ps_s[rg];
    inv_w[rg] = 1.0f / ps_w[rg];
    const short* gp = qkv + (size_t)(b * NSEQ + nbase + 4 * hi + rg) * QKV_STR + GOFS;
    gcv[rg] = 1.0f / (1.0f + __expf(-bf2f(gp[h])));
    gsv[rg] = 1.0f / (1.0f + __expf(-bf2f(gp[16 + h])));
    gwv[rg] = 1.0f / (1.0f + __expf(-bf2f(gp[32 + h])));
  }

  short* obase = o + (size_t)(b * NSEQ + nbase) * 2048 + h * HDIM;
#pragma unroll
  for (int df = 0; df < 8; ++df)
#pragma unroll
    for (int rg = 0; rg < 4; ++rg) {
      float val = gcv[rg] * acc_cmp[df][rg] +
                  gsv[rg] * acc_slc[df][rg] * inv_s[rg] +
                  gwv[rg] * acc_swa[df][rg] * inv_w[rg];
      obase[(size_t)(4 * hi + rg) * 2048 + 16 * df + lm] = f2bf(val);
    }
}

// ------------------------------------------------------------------
extern "C" void kernel_launch(void* const* d_in, const int* in_sizes, int n_in,
                              void* d_out, int out_size, void* d_ws, size_t ws_size,
                              hipStream_t stream) {
  const float* x  = (const float*)d_in[0];
  const float* Wq = (const float*)d_in[1];
  const float* Wk = (const float*)d_in[2];
  const float* Wv = (const float*)d_in[3];
  const float* Wg = (const float*)d_in[4];
  const float* Wo = (const float*)d_in[5];
  float* out = (float*)d_out;

  char* w = (char*)d_ws;
  short* x_bf = (short*)w;            // 8.4 MB (reused as o_bf)
  short* o_bf = x_bf;
  w += (size_t)2048 * 2048 * 2;
  short* w_t  = (short*)w;            // 26.2 MB (rows 6272..6399 unused pad)
  w += (size_t)6400 * 2048 * 2;
  short* qkv  = (short*)w;            // 26.2 MB (stride 6400; gate at 6144)
  w += (size_t)2048 * 6400 * 2;
  float* kc   = (float*)w; w += (size_t)65536 * 4;
  short* vct  = (short*)w; w += (size_t)65536 * 2;
  short* pcb  = (short*)w; w += (size_t)524288 * 2;
  int*   sel  = (int*)w;   w += (size_t)32768 * 4;
  short* vt   = (short*)w; w += (size_t)4194304 * 2;  // 8.4 MB
  float2* tbl = (float2*)w; w += (size_t)65536 * 8;   // 0.5 MB

  const dim3 blk(256);
  prep<<<dim3(64, 64, 6), blk, 0, stream>>>(Wq, Wk, Wv, Wg, x, w_t, x_bf, tbl);
  gemm256<<<200, dim3(512), 0, stream>>>(x_bf, w_t, qkv, 2048, 6400, 2048);
  rope_qk<<<2048, blk, 0, stream>>>(qkv, tbl);
  block_mean<<<256, blk, 0, stream>>>(qkv + KOFS, kc);
  v_transpose<<<dim3(16, 16, 2), blk, 0, stream>>>(qkv, vt, vct);
  cmp_sel<<<512, dim3(64), 0, stream>>>(qkv, kc, pcb, sel);
  transpose_cast<<<dim3(64, 64), blk, 0, stream>>>(Wo, w_t);
  attn_mfma<<<2048, dim3(64), 0, stream>>>(qkv, vt, vct, pcb, sel, o_bf);
  gemm_bf16_bt<float><<<256, blk, 0, stream>>>(o_bf, w_t, out, 2048, 2048, 2048);
}

// Round 13
// 260.891 us; speedup vs baseline: 1.0163x; 1.0152x over previous
//
#include <hip/hip_runtime.h>
#include <hip/hip_bf16.h>

// NSA forward: B=2, N=1024, D=2048, H=16, HD=128, BS=64, SEL=8, WIN=64
#define HN   16
#define HDIM 128
#define NSEQ 1024
#define NBLK 16
#define BSZ  64
#define SCALE 0.08838834764831845f
#define QKV_STR 6400   // row stride of fused qkv+gate buffer (bf16), padded to 25*256
#define KOFS 2048
#define VOFS 4096
#define GOFS 6144

typedef __attribute__((ext_vector_type(8))) short bfrag;   // 8 bf16 (4 VGPRs)
typedef __attribute__((ext_vector_type(4))) float facc;    // MFMA accumulator

__device__ __forceinline__ float bf2f(short s) {
  union { unsigned u; float f; } cv;
  cv.u = ((unsigned)(unsigned short)s) << 16;
  return cv.f;
}
__device__ __forceinline__ short f2bf(float f) {
  unsigned u = __float_as_uint(f);
  u = (u + 0x7fff + ((u >> 16) & 1)) >> 16;  // RNE
  return (short)u;
}

#define ASYNC16(gp, lp)                                                    \
  __builtin_amdgcn_global_load_lds(                                        \
      (const __attribute__((address_space(1))) void*)(gp),                 \
      (__attribute__((address_space(3))) void*)(lp), 16, 0, 0)

#define MFMA16(a, b, c) __builtin_amdgcn_mfma_f32_16x16x32_bf16(a, b, c, 0, 0, 0)

// ------------------------------------------------------------------
// prep: z=0..2 -> Wq/Wk/Wv transpose-cast into w_t rows z*2048..
//       z=3   -> Wg transposed + zero-padded to rows 6144..6271
//       z=4   -> x cast to bf16
//       z=5   -> RoPE cos/sin table
// ------------------------------------------------------------------
__global__ __launch_bounds__(256) void prep(const float* __restrict__ Wq,
                                            const float* __restrict__ Wk,
                                            const float* __restrict__ Wv,
                                            const float* __restrict__ Wg,
                                            const float* __restrict__ x,
                                            short* __restrict__ w_t,
                                            short* __restrict__ x_bf,
                                            float2* __restrict__ tbl) {
  __shared__ float tile[32][33];
  const int z = blockIdx.z;
  const int bx = blockIdx.x * 32, by = blockIdx.y * 32;
  const int tx = threadIdx.x & 31, ty = threadIdx.x >> 5;
  if (z == 5) {
    if (blockIdx.y >= 4) return;
    int i = (blockIdx.y * 64 + blockIdx.x) * 256 + threadIdx.x;  // < 65536
    int d = i & 63, n = i >> 6;
    float inv = expf(-(float)d * (9.210340371976184f / 64.0f));
    float sn, cs;
    sincosf((float)n * inv, &sn, &cs);
    tbl[i] = make_float2(cs, sn);
    return;
  }
  if (z == 4) {
#pragma unroll
    for (int i = 0; i < 4; ++i) {
      const int row = by + ty + 8 * i;
      x_bf[(size_t)row * 2048 + bx + tx] = f2bf(x[(size_t)row * 2048 + bx + tx]);
    }
    return;
  }
  if (z == 3) {
    if (blockIdx.x >= 4) return;  // only 128 dst rows
#pragma unroll
    for (int i = 0; i < 4; ++i) {
      const int c = bx + tx;
      tile[ty + 8 * i][tx] = (c < 48) ? Wg[(size_t)(by + ty + 8 * i) * 48 + c] : 0.f;
    }
    __syncthreads();
#pragma unroll
    for (int i = 0; i < 4; ++i)
      w_t[(size_t)(GOFS + bx + ty + 8 * i) * 2048 + by + tx] = f2bf(tile[tx][ty + 8 * i]);
    return;
  }
  const float* src = (z == 0) ? Wq : (z == 1) ? Wk : Wv;
#pragma unroll
  for (int i = 0; i < 4; ++i)
    tile[ty + 8 * i][tx] = src[(size_t)(by + ty + 8 * i) * 2048 + bx + tx];
  __syncthreads();
#pragma unroll
  for (int i = 0; i < 4; ++i)
    w_t[(size_t)(z * 2048 + bx + ty + 8 * i) * 2048 + by + tx] = f2bf(tile[tx][ty + 8 * i]);
}

// ------------------------------------------------------------------
// Wo transpose (reuses w_t after qkv gemm)
// ------------------------------------------------------------------
__global__ __launch_bounds__(256) void transpose_cast(const float* __restrict__ src,
                                                      short* __restrict__ dst) {
  __shared__ float tile[32][33];
  const int bx = blockIdx.x * 32, by = blockIdx.y * 32;
  const int tx = threadIdx.x & 31, ty = threadIdx.x >> 5;
#pragma unroll
  for (int i = 0; i < 4; ++i)
    tile[ty + 8 * i][tx] = src[(size_t)(by + ty + 8 * i) * 2048 + bx + tx];
  __syncthreads();
#pragma unroll
  for (int i = 0; i < 4; ++i)
    dst[(size_t)(bx + ty + 8 * i) * 2048 + by + tx] = f2bf(tile[tx][ty + 8 * i]);
}

// ------------------------------------------------------------------
// 8-phase 256x256 bf16 GEMM (T2+T3+T4+T5): C[M][N] = A[M][K]*Bt[N][K]^T
// ------------------------------------------------------------------
__global__ __launch_bounds__(512, 1) void gemm256(const short* __restrict__ A,
                                                  const short* __restrict__ Bt,
                                                  short* __restrict__ C,
                                                  int M, int N, int K) {
  __shared__ short lds[2][2][16384];  // [buf][A/B][256*64]
  const int t = threadIdx.x;
  const int l = t & 63, w = t >> 6;
  const int wm = w >> 2, wn = w & 3;
  const int lm = l & 15, hi = l >> 4;
  const int lanexor = (lm & 7) << 3;            // shorts
  const int kk0 = (hi * 8) ^ lanexor;           // ks=0 column (shorts)
  const int L = blockIdx.x;
  const int item = (L & 7) * (gridDim.x >> 3) + (L >> 3);  // bijective (nwg%8==0)
  const int nrow = M >> 8;
  const int row0 = (item % nrow) * 256, col0 = (item / nrow) * 256;
  const int nt = K >> 6;

  const int srow = t >> 3;
  const int scol = 8 * ((t & 7) ^ (srow & 7));
  const short* Ab = A + (size_t)(row0 + srow) * K + scol;
  const short* Bb = Bt + (size_t)(col0 + srow) * K + scol;

#define STAGE(mat, srcbase, h, tau, buf)                                     \
  {                                                                          \
    const short* g_ = (srcbase) + (size_t)(h) * 128 * K + (size_t)(tau) * 64;\
    short* d_ = &lds[buf][mat][(h) * 8192 + t * 8];                          \
    ASYNC16(g_, d_);                                                         \
    ASYNC16(g_ + (size_t)64 * K, d_ + 4096);                                 \
  }

  facc acc[8][4] = {};
  bfrag af[8], bf0[4], bf1[4];

  STAGE(0, Ab, 0, 0, 0); STAGE(0, Ab, 1, 0, 0);
  STAGE(1, Bb, 0, 0, 0); STAGE(1, Bb, 1, 0, 0);
  STAGE(1, Bb, 0, 1, 1); STAGE(1, Bb, 1, 1, 1);
  asm volatile("s_waitcnt vmcnt(4)" ::: "memory");
  __builtin_amdgcn_s_barrier();

  for (int tau = 0; tau < nt; ++tau) {
    const int c = tau & 1;
    const int tA = (tau + 1 < nt) ? tau + 1 : nt - 1;
    const int tB = (tau + 2 < nt) ? tau + 2 : nt - 1;

#define DS_A(qm)                                                             \
  _Pragma("unroll") for (int ii = 0; ii < 4; ++ii) {                         \
    const int row_ = wm * 128 + (qm) * 64 + ii * 16 + lm;                    \
    af[ii * 2 + 0] = *(const bfrag*)&lds[c][0][row_ * 64 + kk0];             \
    af[ii * 2 + 1] = *(const bfrag*)&lds[c][0][row_ * 64 + (kk0 ^ 32)];      \
  }
#define DS_B(qn, arr)                                                        \
  _Pragma("unroll") for (int jj = 0; jj < 2; ++jj) {                         \
    const int row_ = wn * 64 + (qn) * 32 + jj * 16 + lm;                     \
    arr[jj * 2 + 0] = *(const bfrag*)&lds[c][1][row_ * 64 + kk0];            \
    arr[jj * 2 + 1] = *(const bfrag*)&lds[c][1][row_ * 64 + (kk0 ^ 32)];     \
  }
#define QUAD(qm, qn, arr)                                                    \
  _Pragma("unroll") for (int ii = 0; ii < 4; ++ii)                           \
  _Pragma("unroll") for (int jj = 0; jj < 2; ++jj) {                         \
    acc[(qm)*4+ii][(qn)*2+jj] = MFMA16(af[ii*2+0], arr[jj*2+0], acc[(qm)*4+ii][(qn)*2+jj]); \
    acc[(qm)*4+ii][(qn)*2+jj] = MFMA16(af[ii*2+1], arr[jj*2+1], acc[(qm)*4+ii][(qn)*2+jj]); \
  }

    DS_A(0); DS_B(0, bf0);
    STAGE(0, Ab, 0, tA, c ^ 1);
    __builtin_amdgcn_s_barrier();
    asm volatile("s_waitcnt lgkmcnt(0)" ::: "memory");
    __builtin_amdgcn_sched_barrier(0);
    __builtin_amdgcn_s_setprio(1);
    QUAD(0, 0, bf0);
    __builtin_amdgcn_s_setprio(0);
    __builtin_amdgcn_s_barrier();

    DS_B(1, bf1);
    STAGE(0, Ab, 1, tA, c ^ 1);
    __builtin_amdgcn_s_barrier();
    asm volatile("s_waitcnt lgkmcnt(0)" ::: "memory");
    __builtin_amdgcn_sched_barrier(0);
    __builtin_amdgcn_s_setprio(1);
    QUAD(0, 1, bf1);
    __builtin_amdgcn_s_setprio(0);
    __builtin_amdgcn_s_barrier();

    DS_A(1);
    STAGE(1, Bb, 0, tB, c);
    __builtin_amdgcn_s_barrier();
    asm volatile("s_waitcnt lgkmcnt(0)" ::: "memory");
    __builtin_amdgcn_sched_barrier(0);
    __builtin_amdgcn_s_setprio(1);
    QUAD(1, 1, bf1);
    __builtin_amdgcn_s_setprio(0);
    __builtin_amdgcn_s_barrier();

    STAGE(1, Bb, 1, tB, c);
    __builtin_amdgcn_s_setprio(1);
    QUAD(1, 0, bf0);
    __builtin_amdgcn_s_setprio(0);
    asm volatile("s_waitcnt vmcnt(4)" ::: "memory");
    __builtin_amdgcn_s_barrier();
  }

#pragma unroll
  for (int i = 0; i < 8; ++i)
#pragma unroll
    for (int j = 0; j < 4; ++j)
#pragma unroll
      for (int rr = 0; rr < 4; ++rr)
        C[(size_t)(row0 + wm * 128 + i * 16 + hi * 4 + rr) * N +
          col0 + wn * 64 + j * 16 + lm] = f2bf(acc[i][j][rr]);
#undef STAGE
#undef DS_A
#undef DS_B
#undef QUAD
}

// ------------------------------------------------------------------
// bf16 MFMA GEMM (m97 128^2): C[M][N] = A[M][K] * Bt[N][K]^T (out proj)
// ------------------------------------------------------------------
__device__ __forceinline__ void store_c(float* p, float v) { *p = v; }
__device__ __forceinline__ void store_c(short* p, float v) { *p = f2bf(v); }

template <typename OT>
__global__ __launch_bounds__(256) void gemm_bf16_bt(const short* __restrict__ A,
                                                    const short* __restrict__ Bt,
                                                    OT* __restrict__ C,
                                                    int M, int N, int K) {
  __shared__ short As[128 * 32];
  __shared__ short Bs[128 * 32];
  const int t = threadIdx.x;
  const int l = t & 63, w = t >> 6;
  const int wr = w >> 1, wc = w & 1;
  const int nwg = gridDim.x;
  const int L = blockIdx.x;
  const int wg = (L & 7) * (nwg >> 3) + (L >> 3);
  const int nrow = M >> 7;
  const int row0 = (wg % nrow) * 128, col0 = (wg / nrow) * 128;
  facc acc[4][4] = {};

  const int sr = t >> 2;
  const int sk = (t & 3) * 8;
  const short* Ag0 = A + (size_t)(row0 + sr) * K + sk;
  const short* Ag1 = Ag0 + (size_t)64 * K;
  const short* Bg0 = Bt + (size_t)(col0 + sr) * K + sk;
  const short* Bg1 = Bg0 + (size_t)64 * K;
  short* la = As + t * 8;
  short* lb = Bs + t * 8;

  const int lm = l & 15;
  const int lk = (l >> 4) * 8;

  for (int k0 = 0; k0 < K; k0 += 32) {
    ASYNC16(Ag0 + k0, la);
    ASYNC16(Ag1 + k0, la + 2048);
    ASYNC16(Bg0 + k0, lb);
    ASYNC16(Bg1 + k0, lb + 2048);
    __syncthreads();
    bfrag af[4], bf[4];
#pragma unroll
    for (int i = 0; i < 4; ++i)
      af[i] = *(const bfrag*)&As[(wr * 64 + i * 16 + lm) * 32 + lk];
#pragma unroll
    for (int j = 0; j < 4; ++j)
      bf[j] = *(const bfrag*)&Bs[(wc * 64 + j * 16 + lm) * 32 + lk];
#pragma unroll
    for (int i = 0; i < 4; ++i)
#pragma unroll
      for (int j = 0; j < 4; ++j)
        acc[i][j] = MFMA16(af[i], bf[j], acc[i][j]);
    __syncthreads();
  }

  const int orow = row0 + wr * 64 + (l >> 4) * 4;
  const int ocol = col0 + wc * 64 + lm;
#pragma unroll
  for (int i = 0; i < 4; ++i)
#pragma unroll
    for (int j = 0; j < 4; ++j)
#pragma unroll
      for (int rr = 0; rr < 4; ++rr)
        store_c(&C[(size_t)(orow + i * 16 + rr) * N + ocol + j * 16], acc[i][j][rr]);
}

// ------------------------------------------------------------------
// RoPE in place on q AND k slices, table-based, 8 dims/thread
// ------------------------------------------------------------------
__global__ __launch_bounds__(256) void rope_qk(short* __restrict__ qkv,
                                               const float2* __restrict__ tbl) {
  int i = blockIdx.x * 256 + threadIdx.x;  // 524288
  int c = i & 7;
  int h = (i >> 3) & 15;
  int qk = (i >> 7) & 1;
  int n = (i >> 8) & 1023;
  int b = i >> 18;
  short* base = qkv + (size_t)(b * NSEQ + n) * QKV_STR + qk * KOFS + h * HDIM + c * 8;
  const float2* tp = tbl + n * 64 + c * 8;
  bfrag t1 = *(const bfrag*)base, t2 = *(const bfrag*)(base + 64);
  bfrag o1, o2;
#pragma unroll
  for (int j = 0; j < 8; ++j) {
    float2 cssn = tp[j];
    float a = bf2f(t1[j]), bb = bf2f(t2[j]);
    o1[j] = f2bf(a * cssn.x - bb * cssn.y);
    o2[j] = f2bf(a * cssn.y + bb * cssn.x);
  }
  *(bfrag*)base = o1;
  *(bfrag*)(base + 64) = o2;
}

// ------------------------------------------------------------------
// Block mean (roped K) -> f32 kc [b][m][h][d]
// ------------------------------------------------------------------
__global__ __launch_bounds__(256) void block_mean(const short* __restrict__ src,
                                                  float* __restrict__ dst) {
  int i = blockIdx.x * 256 + threadIdx.x;  // 65536
  int d = i & 127;
  int h = (i >> 7) & 15;
  int m = (i >> 11) & 15;
  int b = i >> 15;
  const short* p = src + (size_t)(b * NSEQ + m * BSZ) * QKV_STR + h * HDIM + d;
  float acc = 0.f;
#pragma unroll 8
  for (int j = 0; j < 64; ++j) acc += bf2f(p[(size_t)j * QKV_STR]);
  dst[i] = acc * (1.0f / 64.0f);
}

// ------------------------------------------------------------------
// V transpose -> vt[b][h][d][n], fused V block-mean -> vct[b][h][d][m]
// ------------------------------------------------------------------
__global__ __launch_bounds__(256) void v_transpose(const short* __restrict__ qkv,
                                                   short* __restrict__ vt,
                                                   short* __restrict__ vct) {
  __shared__ short tile[64][136];
  const int n0 = blockIdx.x * 64;
  const int h = blockIdx.y, b = blockIdx.z;
  const int t = threadIdx.x;
#pragma unroll
  for (int it = 0; it < 4; ++it) {
    int idx = t + 256 * it;
    int row = idx >> 4, ch = idx & 15;
    *(bfrag*)&tile[row][ch * 8] =
        *(const bfrag*)&qkv[(size_t)(b * NSEQ + n0 + row) * QKV_STR + VOFS + h * HDIM + ch * 8];
  }
  __syncthreads();
#pragma unroll
  for (int it = 0; it < 4; ++it) {
    int idx = t + 256 * it;
    int d = idx >> 3, ch = idx & 7;
    bfrag tv;
    float s = 0.f;
#pragma unroll
    for (int j = 0; j < 8; ++j) {
      tv[j] = tile[ch * 8 + j][d];
      s += bf2f(tv[j]);
    }
    *(bfrag*)&vt[(((size_t)(b * HN + h) * 128) + d) * 1024 + n0 + ch * 8] = tv;
    s += __shfl_down(s, 4);
    s += __shfl_down(s, 2);
    s += __shfl_down(s, 1);
    if ((t & 7) == 0)
      vct[(((size_t)(b * HN + h) * 128) + d) * 16 + (n0 >> 6)] = f2bf(s * (1.0f / 64.0f));
  }
}

// ------------------------------------------------------------------
// Compressed probs (bf16 pc [b][h][n][16]) + top-8 selection bitmask.
// ------------------------------------------------------------------
__global__ __launch_bounds__(64) void cmp_sel(const short* __restrict__ qkv,
                                              const float* __restrict__ kc,
                                              short* __restrict__ pc,
                                              int* __restrict__ sel) {
  int i = blockIdx.x * 64 + threadIdx.x;  // B*H*N = 32768
  int n = i & 1023;
  int h = (i >> 10) & 15;
  int b = i >> 14;
  const short* qp = qkv + (size_t)(b * NSEQ + n) * QKV_STR + h * HDIM;
  const int nv = (n + 1) >> 6;
  float s[NBLK];
#pragma unroll
  for (int m = 0; m < NBLK; ++m) s[m] = 0.f;
  for (int d0 = 0; d0 < HDIM; d0 += 8) {
    bfrag qv = *(const bfrag*)&qp[d0];
    float qf[8];
#pragma unroll
    for (int dd = 0; dd < 8; ++dd) qf[dd] = bf2f(qv[dd]);
    for (int m = 0; m < nv; ++m) {
      const float4* kp = (const float4*)(kc + ((size_t)((b * NBLK + m) * HN + h) << 7) + d0);
      const float4 k0 = kp[0], k1 = kp[1];
      s[m] += qf[0] * k0.x + qf[1] * k0.y + qf[2] * k0.z + qf[3] * k0.w +
              qf[4] * k1.x + qf[5] * k1.y + qf[6] * k1.z + qf[7] * k1.w;
    }
  }
  float mx = -1e30f;
  for (int m = 0; m < nv; ++m) { s[m] *= SCALE; mx = fmaxf(mx, s[m]); }
  float den = 0.f;
  for (int m = 0; m < nv; ++m) { s[m] = __expf(s[m] - mx); den += s[m]; }
  const float rden = (nv > 0) ? 1.0f / den : 0.f;
  float p[NBLK];
#pragma unroll
  for (int m = 0; m < NBLK; ++m) p[m] = (m < nv) ? s[m] * rden : 0.f;
  bfrag o0, o1;
#pragma unroll
  for (int m = 0; m < 8; ++m) { o0[m] = f2bf(p[m]); o1[m] = f2bf(p[m + 8]); }
  bfrag* pout = (bfrag*)(pc + (size_t)i * 16);
  pout[0] = o0; pout[1] = o1;
  p[n >> 6] += 2.0f;
  int mask = 0;
#pragma unroll
  for (int ss = 0; ss < 8; ++ss) {
    int best = 0;
    float bv = -1e30f;
#pragma unroll
    for (int m = 0; m < NBLK; ++m)
      if (p[m] > bv) { bv = p[m]; best = m; }
    mask |= 1 << best;
    p[best] = -1e30f;
  }
  sel[i] = mask;
}

// ------------------------------------------------------------------
// MFMA attention, load-balanced: 2 INDEPENDENT waves per block,
// wave0 handles rt = 63-rank (heavy), wave1 handles rt = rank (light)
// -> each block does ~constant total tile-iterations, no straggler CU.
// No barriers, no cross-wave combine; per-wave LDS P-buffer half.
// Per-wave pipeline: f-slot {issue K(f+1); exp(f-1); MFMA(f)}, V
// hoisted to f=1/f=2. launch_bounds (128,2): min-waves>=4 forces the
// 64-VGPR tier and spills (R7/R8 lesson) -- keep at 2.
// ------------------------------------------------------------------
__global__ __launch_bounds__(128, 2) void attn_mfma(
    const short* __restrict__ qkv, const short* __restrict__ vt,
    const short* __restrict__ vct, const short* __restrict__ pc,
    const int* __restrict__ sel, short* __restrict__ o) {
  const int fid = blockIdx.x;            // 0..1023
  const int xcd = fid & 7;
  const int idx = fid >> 3;              // 0..127
  const int pair = (xcd << 2) | (idx & 3);
  const int rank = idx >> 2;             // 0..31
  const int h = pair & 15, b = pair >> 4;

  const int tid = threadIdx.x;
  const int wid = tid >> 6;
  const int rt = wid ? rank : 63 - rank; // heavy+light paired per block
  const int l = tid & 63;
  const int lm = l & 15, hi = l >> 4;
  const int nbase = rt * 16;

  __shared__ short pbuf[2][2][1024];     // [wid][slc/swa][...] (8 KB)
  short* p_slc = &pbuf[wid][0][0];
  short* p_swa = &pbuf[wid][1][0];

  // Q A-fragments
  const short* qrow = qkv + (size_t)(b * NSEQ + nbase + lm) * QKV_STR + h * HDIM;
  bfrag qf[4];
#pragma unroll
  for (int ks = 0; ks < 4; ++ks) qf[ks] = *(const bfrag*)&qrow[32 * ks + 8 * hi];

  // selection bits
  int selrow = sel[(size_t)(b * HN + h) * NSEQ + nbase + lm];
  int uni = selrow;
#pragma unroll
  for (int m = 1; m < 16; m <<= 1) uni |= __shfl_xor(uni, m);
  int sel4[4];
#pragma unroll
  for (int rg = 0; rg < 4; ++rg) sel4[rg] = __shfl(selrow, 4 * hi + rg);

  const int thi = nbase >> 6;
  const int tlo = (nbase >= 64) ? ((nbase - 64) >> 6) : 0;
  const int wmask = (int)((2u << thi) - (1u << tlo));
  const unsigned am = (unsigned)(uni | wmask) & (unsigned)((2u << thi) - 1);

  facc acc_slc[8] = {}, acc_swa[8] = {};
  float ps_s[4] = {0.f, 0.f, 0.f, 0.f}, ps_w[4] = {0.f, 0.f, 0.f, 0.f};

  const short* kbase0 = qkv + (size_t)(b * NSEQ) * QKV_STR + KOFS + h * HDIM + 8 * hi;
  const short* vtb0 = vt + ((size_t)(b * HN + h) * 128) * 1024 + 8 * hi;

#define LOADK4(d0, d1, d2, d3, colbase)                                     \
  {                                                                         \
    const short* kr_ = kbase0 + (size_t)((colbase) + lm) * QKV_STR;         \
    d0 = *(const bfrag*)(kr_);                                              \
    d1 = *(const bfrag*)(kr_ + 32);                                         \
    d2 = *(const bfrag*)(kr_ + 64);                                         \
    d3 = *(const bfrag*)(kr_ + 96);                                         \
  }

#define MFMA4(dst, s0, s1, s2, s3)                                          \
  dst = MFMA16(qf[0], s0, dst);                                             \
  dst = MFMA16(qf[1], s1, dst);                                             \
  dst = MFMA16(qf[2], s2, dst);                                             \
  dst = MFMA16(qf[3], s3, dst);

#define EXPF(f_)                                                            \
  _Pragma("unroll") for (int rg = 0; rg < 4; ++rg) {                        \
    const int col_ = ct * 64 + 16 * (f_) + lm;                              \
    const int row_ = nbase + 4 * hi + rg;                                   \
    float e_ = __expf(sacc[f_][rg] * SCALE);                                \
    e_ = (col_ <= row_) ? e_ : 0.f;                                         \
    float es_ = ((sel4[rg] >> ct) & 1) ? e_ : 0.f;                          \
    float ew_ = (row_ - col_ <= 64) ? e_ : 0.f;                             \
    ps_s[rg] += es_;                                                        \
    ps_w[rg] += ew_;                                                        \
    const int srow_ = 4 * hi + rg;                                          \
    const int sidx_ = (64 * srow_ + 16 * (f_) + lm) ^ ((srow_ & 7) << 3);   \
    if (do_s) p_slc[sidx_] = f2bf(es_);                                     \
    if (do_w) p_swa[sidx_] = f2bf(ew_);                                     \
  }

  int ct = __ffs((int)am) - 1;           // first active tile (am != 0 always)
  bfrag ka0, ka1, ka2, ka3;              // K(ct, f=0), preloaded
  LOADK4(ka0, ka1, ka2, ka3, ct * 64);

  while (ct >= 0) {
    const unsigned rem = am & ~((2u << ct) - 1);
    const int nct = rem ? (__ffs((int)rem) - 1) : -1;
    const bool do_s = (uni >> ct) & 1;
    const bool do_w = (wmask >> ct) & 1;
    const short* vtb = vtb0 + ct * 64;

    facc sacc[4] = {};
    bfrag kb0, kb1, kb2, kb3, kc0, kc1, kc2, kc3, kd0, kd1, kd2, kd3;
    bfrag vb0[8], vb1[8];

    // f=0: issue K(ct,1); MFMA(0)
    LOADK4(kb0, kb1, kb2, kb3, ct * 64 + 16);
    MFMA4(sacc[0], ka0, ka1, ka2, ka3);

    // f=1: issue K(ct,2) + V(ks0); exp(0); MFMA(1)
    LOADK4(kc0, kc1, kc2, kc3, ct * 64 + 32);
#pragma unroll
    for (int df = 0; df < 8; ++df)
      vb0[df] = *(const bfrag*)&vtb[(size_t)(16 * df + lm) * 1024];
    EXPF(0);
    MFMA4(sacc[1], kb0, kb1, kb2, kb3);

    // f=2: issue K(ct,3) + V(ks1); exp(1); MFMA(2)
    LOADK4(kd0, kd1, kd2, kd3, ct * 64 + 48);
#pragma unroll
    for (int df = 0; df < 8; ++df)
      vb1[df] = *(const bfrag*)&vtb[(size_t)(16 * df + lm) * 1024 + 32];
    EXPF(1);
    MFMA4(sacc[2], kc0, kc1, kc2, kc3);

    // f=3: issue K(next tile, 0); exp(2); MFMA(3); exp(3)
    LOADK4(ka0, ka1, ka2, ka3, (nct >= 0 ? nct : ct) * 64);
    EXPF(2);
    MFMA4(sacc[3], kd0, kd1, kd2, kd3);
    EXPF(3);

    // ---- PV (within-wave LDS write->read ordering; no barrier needed)
    {
      const int ridx0 = (64 * lm + 8 * hi) ^ ((lm & 7) << 3);
      bfrag pas = {}, paw = {};
      if (do_s) pas = *(const bfrag*)&p_slc[ridx0];
      if (do_w) paw = *(const bfrag*)&p_swa[ridx0];
#pragma unroll
      for (int df = 0; df < 8; ++df) {
        if (do_s) acc_slc[df] = MFMA16(pas, vb0[df], acc_slc[df]);
        if (do_w) acc_swa[df] = MFMA16(paw, vb0[df], acc_swa[df]);
      }
      const int ridx1 = (64 * lm + 8 * hi + 32) ^ ((lm & 7) << 3);
      bfrag pas1 = {}, paw1 = {};
      if (do_s) pas1 = *(const bfrag*)&p_slc[ridx1];
      if (do_w) paw1 = *(const bfrag*)&p_swa[ridx1];
#pragma unroll
      for (int df = 0; df < 8; ++df) {
        if (do_s) acc_slc[df] = MFMA16(pas1, vb1[df], acc_slc[df]);
        if (do_w) acc_swa[df] = MFMA16(paw1, vb1[df], acc_swa[df]);
      }
    }
    ct = nct;
  }
#undef LOADK4
#undef MFMA4
#undef EXPF

  // ---- compressed branch: O_cmp = Pc[16x16] * Vc[16x128], K padded to 32
  facc acc_cmp[8] = {};
  {
    bfrag pa = {};
    if (hi < 2)
      pa = *(const bfrag*)&pc[((size_t)(b * HN + h) * NSEQ + nbase + lm) * 16 + 8 * hi];
#pragma unroll
    for (int df = 0; df < 8; ++df) {
      bfrag vb = {};
      if (hi < 2)
        vb = *(const bfrag*)&vct[(((size_t)(b * HN + h) * 128) + 16 * df + lm) * 16 + 8 * hi];
      acc_cmp[df] = MFMA16(pa, vb, acc_cmp[df]);
    }
  }

  // ---- denominators: reduce across the 16 col-lanes
#pragma unroll
  for (int m = 1; m < 16; m <<= 1) {
#pragma unroll
    for (int rg = 0; rg < 4; ++rg) {
      ps_s[rg] += __shfl_xor(ps_s[rg], m);
      ps_w[rg] += __shfl_xor(ps_w[rg], m);
    }
  }

  float inv_s[4], inv_w[4], gcv[4], gsv[4], gwv[4];
#pragma unroll
  for (int rg = 0; rg < 4; ++rg) {
    inv_s[rg] = 1.0f / ps_s[rg];
    inv_w[rg] = 1.0f / ps_w[rg];
    const short* gp = qkv + (size_t)(b * NSEQ + nbase + 4 * hi + rg) * QKV_STR + GOFS;
    gcv[rg] = 1.0f / (1.0f + __expf(-bf2f(gp[h])));
    gsv[rg] = 1.0f / (1.0f + __expf(-bf2f(gp[16 + h])));
    gwv[rg] = 1.0f / (1.0f + __expf(-bf2f(gp[32 + h])));
  }

  short* obase = o + (size_t)(b * NSEQ + nbase) * 2048 + h * HDIM;
#pragma unroll
  for (int df = 0; df < 8; ++df)
#pragma unroll
    for (int rg = 0; rg < 4; ++rg) {
      float val = gcv[rg] * acc_cmp[df][rg] +
                  gsv[rg] * acc_slc[df][rg] * inv_s[rg] +
                  gwv[rg] * acc_swa[df][rg] * inv_w[rg];
      obase[(size_t)(4 * hi + rg) * 2048 + 16 * df + lm] = f2bf(val);
    }
}

// ------------------------------------------------------------------
extern "C" void kernel_launch(void* const* d_in, const int* in_sizes, int n_in,
                              void* d_out, int out_size, void* d_ws, size_t ws_size,
                              hipStream_t stream) {
  const float* x  = (const float*)d_in[0];
  const float* Wq = (const float*)d_in[1];
  const float* Wk = (const float*)d_in[2];
  const float* Wv = (const float*)d_in[3];
  const float* Wg = (const float*)d_in[4];
  const float* Wo = (const float*)d_in[5];
  float* out = (float*)d_out;

  char* w = (char*)d_ws;
  short* x_bf = (short*)w;            // 8.4 MB (reused as o_bf)
  short* o_bf = x_bf;
  w += (size_t)2048 * 2048 * 2;
  short* w_t  = (short*)w;            // 26.2 MB (rows 6272..6399 unused pad)
  w += (size_t)6400 * 2048 * 2;
  short* qkv  = (short*)w;            // 26.2 MB (stride 6400; gate at 6144)
  w += (size_t)2048 * 6400 * 2;
  float* kc   = (float*)w; w += (size_t)65536 * 4;
  short* vct  = (short*)w; w += (size_t)65536 * 2;
  short* pcb  = (short*)w; w += (size_t)524288 * 2;
  int*   sel  = (int*)w;   w += (size_t)32768 * 4;
  short* vt   = (short*)w; w += (size_t)4194304 * 2;  // 8.4 MB
  float2* tbl = (float2*)w; w += (size_t)65536 * 8;   // 0.5 MB

  const dim3 blk(256);
  prep<<<dim3(64, 64, 6), blk, 0, stream>>>(Wq, Wk, Wv, Wg, x, w_t, x_bf, tbl);
  gemm256<<<200, dim3(512), 0, stream>>>(x_bf, w_t, qkv, 2048, 6400, 2048);
  rope_qk<<<2048, blk, 0, stream>>>(qkv, tbl);
  block_mean<<<256, blk, 0, stream>>>(qkv + KOFS, kc);
  v_transpose<<<dim3(16, 16, 2), blk, 0, stream>>>(qkv, vt, vct);
  cmp_sel<<<512, dim3(64), 0, stream>>>(qkv, kc, pcb, sel);
  transpose_cast<<<dim3(64, 64), blk, 0, stream>>>(Wo, w_t);
  attn_mfma<<<1024, dim3(128), 0, stream>>>(qkv, vt, vct, pcb, sel, o_bf);
  gemm_bf16_bt<float><<<256, blk, 0, stream>>>(o_bf, w_t, out, 2048, 2048, 2048);
}

// Round 14
// 242.096 us; speedup vs baseline: 1.0951x; 1.0776x over previous
//
#include <hip/hip_runtime.h>
#include <hip/hip_bf16.h>

// NSA forward: B=2, N=1024, D=2048, H=16, HD=128, BS=64, SEL=8, WIN=64
#define HN   16
#define HDIM 128
#define NSEQ 1024
#define NBLK 16
#define BSZ  64
#define SCALE 0.08838834764831845f
#define QKV_STR 6400   // row stride of fused qkv+gate buffer (bf16), padded to 25*256
#define KOFS 2048
#define VOFS 4096
#define GOFS 6144

typedef __attribute__((ext_vector_type(8))) short bfrag;   // 8 bf16 (4 VGPRs)
typedef __attribute__((ext_vector_type(4))) float facc;    // MFMA accumulator

__device__ __forceinline__ float bf2f(short s) {
  union { unsigned u; float f; } cv;
  cv.u = ((unsigned)(unsigned short)s) << 16;
  return cv.f;
}
__device__ __forceinline__ short f2bf(float f) {
  unsigned u = __float_as_uint(f);
  u = (u + 0x7fff + ((u >> 16) & 1)) >> 16;  // RNE
  return (short)u;
}

#define ASYNC16(gp, lp)                                                    \
  __builtin_amdgcn_global_load_lds(                                        \
      (const __attribute__((address_space(1))) void*)(gp),                 \
      (__attribute__((address_space(3))) void*)(lp), 16, 0, 0)

#define MFMA16(a, b, c) __builtin_amdgcn_mfma_f32_16x16x32_bf16(a, b, c, 0, 0, 0)

// ------------------------------------------------------------------
// prep: z=0..2 -> Wq/Wk/Wv transpose-cast into w_t rows z*2048..
//       z=3   -> Wg transposed + zero-padded to rows 6144..6271
//       z=4   -> x cast to bf16
//       z=5   -> RoPE cos/sin table
// ------------------------------------------------------------------
__global__ __launch_bounds__(256) void prep(const float* __restrict__ Wq,
                                            const float* __restrict__ Wk,
                                            const float* __restrict__ Wv,
                                            const float* __restrict__ Wg,
                                            const float* __restrict__ x,
                                            short* __restrict__ w_t,
                                            short* __restrict__ x_bf,
                                            float2* __restrict__ tbl) {
  __shared__ float tile[32][33];
  const int z = blockIdx.z;
  const int bx = blockIdx.x * 32, by = blockIdx.y * 32;
  const int tx = threadIdx.x & 31, ty = threadIdx.x >> 5;
  if (z == 5) {
    if (blockIdx.y >= 4) return;
    int i = (blockIdx.y * 64 + blockIdx.x) * 256 + threadIdx.x;  // < 65536
    int d = i & 63, n = i >> 6;
    float inv = expf(-(float)d * (9.210340371976184f / 64.0f));
    float sn, cs;
    sincosf((float)n * inv, &sn, &cs);
    tbl[i] = make_float2(cs, sn);
    return;
  }
  if (z == 4) {
#pragma unroll
    for (int i = 0; i < 4; ++i) {
      const int row = by + ty + 8 * i;
      x_bf[(size_t)row * 2048 + bx + tx] = f2bf(x[(size_t)row * 2048 + bx + tx]);
    }
    return;
  }
  if (z == 3) {
    if (blockIdx.x >= 4) return;  // only 128 dst rows
#pragma unroll
    for (int i = 0; i < 4; ++i) {
      const int c = bx + tx;
      tile[ty + 8 * i][tx] = (c < 48) ? Wg[(size_t)(by + ty + 8 * i) * 48 + c] : 0.f;
    }
    __syncthreads();
#pragma unroll
    for (int i = 0; i < 4; ++i)
      w_t[(size_t)(GOFS + bx + ty + 8 * i) * 2048 + by + tx] = f2bf(tile[tx][ty + 8 * i]);
    return;
  }
  const float* src = (z == 0) ? Wq : (z == 1) ? Wk : Wv;
#pragma unroll
  for (int i = 0; i < 4; ++i)
    tile[ty + 8 * i][tx] = src[(size_t)(by + ty + 8 * i) * 2048 + bx + tx];
  __syncthreads();
#pragma unroll
  for (int i = 0; i < 4; ++i)
    w_t[(size_t)(z * 2048 + bx + ty + 8 * i) * 2048 + by + tx] = f2bf(tile[tx][ty + 8 * i]);
}

// ------------------------------------------------------------------
// Wo transpose (reuses w_t after qkv gemm)
// ------------------------------------------------------------------
__global__ __launch_bounds__(256) void transpose_cast(const float* __restrict__ src,
                                                      short* __restrict__ dst) {
  __shared__ float tile[32][33];
  const int bx = blockIdx.x * 32, by = blockIdx.y * 32;
  const int tx = threadIdx.x & 31, ty = threadIdx.x >> 5;
#pragma unroll
  for (int i = 0; i < 4; ++i)
    tile[ty + 8 * i][tx] = src[(size_t)(by + ty + 8 * i) * 2048 + bx + tx];
  __syncthreads();
#pragma unroll
  for (int i = 0; i < 4; ++i)
    dst[(size_t)(bx + ty + 8 * i) * 2048 + by + tx] = f2bf(tile[tx][ty + 8 * i]);
}

// ------------------------------------------------------------------
// 8-phase 256x256 bf16 GEMM (T2+T3+T4+T5): C[M][N] = A[M][K]*Bt[N][K]^T
// ------------------------------------------------------------------
__global__ __launch_bounds__(512, 1) void gemm256(const short* __restrict__ A,
                                                  const short* __restrict__ Bt,
                                                  short* __restrict__ C,
                                                  int M, int N, int K) {
  __shared__ short lds[2][2][16384];  // [buf][A/B][256*64]
  const int t = threadIdx.x;
  const int l = t & 63, w = t >> 6;
  const int wm = w >> 2, wn = w & 3;
  const int lm = l & 15, hi = l >> 4;
  const int lanexor = (lm & 7) << 3;            // shorts
  const int kk0 = (hi * 8) ^ lanexor;           // ks=0 column (shorts)
  const int L = blockIdx.x;
  const int item = (L & 7) * (gridDim.x >> 3) + (L >> 3);  // bijective (nwg%8==0)
  const int nrow = M >> 8;
  const int row0 = (item % nrow) * 256, col0 = (item / nrow) * 256;
  const int nt = K >> 6;

  const int srow = t >> 3;
  const int scol = 8 * ((t & 7) ^ (srow & 7));
  const short* Ab = A + (size_t)(row0 + srow) * K + scol;
  const short* Bb = Bt + (size_t)(col0 + srow) * K + scol;

#define STAGE(mat, srcbase, h, tau, buf)                                     \
  {                                                                          \
    const short* g_ = (srcbase) + (size_t)(h) * 128 * K + (size_t)(tau) * 64;\
    short* d_ = &lds[buf][mat][(h) * 8192 + t * 8];                          \
    ASYNC16(g_, d_);                                                         \
    ASYNC16(g_ + (size_t)64 * K, d_ + 4096);                                 \
  }

  facc acc[8][4] = {};
  bfrag af[8], bf0[4], bf1[4];

  STAGE(0, Ab, 0, 0, 0); STAGE(0, Ab, 1, 0, 0);
  STAGE(1, Bb, 0, 0, 0); STAGE(1, Bb, 1, 0, 0);
  STAGE(1, Bb, 0, 1, 1); STAGE(1, Bb, 1, 1, 1);
  asm volatile("s_waitcnt vmcnt(4)" ::: "memory");
  __builtin_amdgcn_s_barrier();

  for (int tau = 0; tau < nt; ++tau) {
    const int c = tau & 1;
    const int tA = (tau + 1 < nt) ? tau + 1 : nt - 1;
    const int tB = (tau + 2 < nt) ? tau + 2 : nt - 1;

#define DS_A(qm)                                                             \
  _Pragma("unroll") for (int ii = 0; ii < 4; ++ii) {                         \
    const int row_ = wm * 128 + (qm) * 64 + ii * 16 + lm;                    \
    af[ii * 2 + 0] = *(const bfrag*)&lds[c][0][row_ * 64 + kk0];             \
    af[ii * 2 + 1] = *(const bfrag*)&lds[c][0][row_ * 64 + (kk0 ^ 32)];      \
  }
#define DS_B(qn, arr)                                                        \
  _Pragma("unroll") for (int jj = 0; jj < 2; ++jj) {                         \
    const int row_ = wn * 64 + (qn) * 32 + jj * 16 + lm;                     \
    arr[jj * 2 + 0] = *(const bfrag*)&lds[c][1][row_ * 64 + kk0];            \
    arr[jj * 2 + 1] = *(const bfrag*)&lds[c][1][row_ * 64 + (kk0 ^ 32)];     \
  }
#define QUAD(qm, qn, arr)                                                    \
  _Pragma("unroll") for (int ii = 0; ii < 4; ++ii)                           \
  _Pragma("unroll") for (int jj = 0; jj < 2; ++jj) {                         \
    acc[(qm)*4+ii][(qn)*2+jj] = MFMA16(af[ii*2+0], arr[jj*2+0], acc[(qm)*4+ii][(qn)*2+jj]); \
    acc[(qm)*4+ii][(qn)*2+jj] = MFMA16(af[ii*2+1], arr[jj*2+1], acc[(qm)*4+ii][(qn)*2+jj]); \
  }

    DS_A(0); DS_B(0, bf0);
    STAGE(0, Ab, 0, tA, c ^ 1);
    __builtin_amdgcn_s_barrier();
    asm volatile("s_waitcnt lgkmcnt(0)" ::: "memory");
    __builtin_amdgcn_sched_barrier(0);
    __builtin_amdgcn_s_setprio(1);
    QUAD(0, 0, bf0);
    __builtin_amdgcn_s_setprio(0);
    __builtin_amdgcn_s_barrier();

    DS_B(1, bf1);
    STAGE(0, Ab, 1, tA, c ^ 1);
    __builtin_amdgcn_s_barrier();
    asm volatile("s_waitcnt lgkmcnt(0)" ::: "memory");
    __builtin_amdgcn_sched_barrier(0);
    __builtin_amdgcn_s_setprio(1);
    QUAD(0, 1, bf1);
    __builtin_amdgcn_s_setprio(0);
    __builtin_amdgcn_s_barrier();

    DS_A(1);
    STAGE(1, Bb, 0, tB, c);
    __builtin_amdgcn_s_barrier();
    asm volatile("s_waitcnt lgkmcnt(0)" ::: "memory");
    __builtin_amdgcn_sched_barrier(0);
    __builtin_amdgcn_s_setprio(1);
    QUAD(1, 1, bf1);
    __builtin_amdgcn_s_setprio(0);
    __builtin_amdgcn_s_barrier();

    STAGE(1, Bb, 1, tB, c);
    __builtin_amdgcn_s_setprio(1);
    QUAD(1, 0, bf0);
    __builtin_amdgcn_s_setprio(0);
    asm volatile("s_waitcnt vmcnt(4)" ::: "memory");
    __builtin_amdgcn_s_barrier();
  }

#pragma unroll
  for (int i = 0; i < 8; ++i)
#pragma unroll
    for (int j = 0; j < 4; ++j)
#pragma unroll
      for (int rr = 0; rr < 4; ++rr)
        C[(size_t)(row0 + wm * 128 + i * 16 + hi * 4 + rr) * N +
          col0 + wn * 64 + j * 16 + lm] = f2bf(acc[i][j][rr]);
#undef STAGE
#undef DS_A
#undef DS_B
#undef QUAD
}

// ------------------------------------------------------------------
// bf16 MFMA GEMM (m97 128^2): C[M][N] = A[M][K] * Bt[N][K]^T (out proj)
// ------------------------------------------------------------------
__device__ __forceinline__ void store_c(float* p, float v) { *p = v; }
__device__ __forceinline__ void store_c(short* p, float v) { *p = f2bf(v); }

template <typename OT>
__global__ __launch_bounds__(256) void gemm_bf16_bt(const short* __restrict__ A,
                                                    const short* __restrict__ Bt,
                                                    OT* __restrict__ C,
                                                    int M, int N, int K) {
  __shared__ short As[128 * 32];
  __shared__ short Bs[128 * 32];
  const int t = threadIdx.x;
  const int l = t & 63, w = t >> 6;
  const int wr = w >> 1, wc = w & 1;
  const int nwg = gridDim.x;
  const int L = blockIdx.x;
  const int wg = (L & 7) * (nwg >> 3) + (L >> 3);
  const int nrow = M >> 7;
  const int row0 = (wg % nrow) * 128, col0 = (wg / nrow) * 128;
  facc acc[4][4] = {};

  const int sr = t >> 2;
  const int sk = (t & 3) * 8;
  const short* Ag0 = A + (size_t)(row0 + sr) * K + sk;
  const short* Ag1 = Ag0 + (size_t)64 * K;
  const short* Bg0 = Bt + (size_t)(col0 + sr) * K + sk;
  const short* Bg1 = Bg0 + (size_t)64 * K;
  short* la = As + t * 8;
  short* lb = Bs + t * 8;

  const int lm = l & 15;
  const int lk = (l >> 4) * 8;

  for (int k0 = 0; k0 < K; k0 += 32) {
    ASYNC16(Ag0 + k0, la);
    ASYNC16(Ag1 + k0, la + 2048);
    ASYNC16(Bg0 + k0, lb);
    ASYNC16(Bg1 + k0, lb + 2048);
    __syncthreads();
    bfrag af[4], bf[4];
#pragma unroll
    for (int i = 0; i < 4; ++i)
      af[i] = *(const bfrag*)&As[(wr * 64 + i * 16 + lm) * 32 + lk];
#pragma unroll
    for (int j = 0; j < 4; ++j)
      bf[j] = *(const bfrag*)&Bs[(wc * 64 + j * 16 + lm) * 32 + lk];
#pragma unroll
    for (int i = 0; i < 4; ++i)
#pragma unroll
      for (int j = 0; j < 4; ++j)
        acc[i][j] = MFMA16(af[i], bf[j], acc[i][j]);
    __syncthreads();
  }

  const int orow = row0 + wr * 64 + (l >> 4) * 4;
  const int ocol = col0 + wc * 64 + lm;
#pragma unroll
  for (int i = 0; i < 4; ++i)
#pragma unroll
    for (int j = 0; j < 4; ++j)
#pragma unroll
      for (int rr = 0; rr < 4; ++rr)
        store_c(&C[(size_t)(orow + i * 16 + rr) * N + ocol + j * 16], acc[i][j][rr]);
}

// ------------------------------------------------------------------
// RoPE in place on q AND k slices, table-based, 8 dims/thread
// ------------------------------------------------------------------
__global__ __launch_bounds__(256) void rope_qk(short* __restrict__ qkv,
                                               const float2* __restrict__ tbl) {
  int i = blockIdx.x * 256 + threadIdx.x;  // 524288
  int c = i & 7;
  int h = (i >> 3) & 15;
  int qk = (i >> 7) & 1;
  int n = (i >> 8) & 1023;
  int b = i >> 18;
  short* base = qkv + (size_t)(b * NSEQ + n) * QKV_STR + qk * KOFS + h * HDIM + c * 8;
  const float2* tp = tbl + n * 64 + c * 8;
  bfrag t1 = *(const bfrag*)base, t2 = *(const bfrag*)(base + 64);
  bfrag o1, o2;
#pragma unroll
  for (int j = 0; j < 8; ++j) {
    float2 cssn = tp[j];
    float a = bf2f(t1[j]), bb = bf2f(t2[j]);
    o1[j] = f2bf(a * cssn.x - bb * cssn.y);
    o2[j] = f2bf(a * cssn.y + bb * cssn.x);
  }
  *(bfrag*)base = o1;
  *(bfrag*)(base + 64) = o2;
}

// ------------------------------------------------------------------
// Block mean (roped K) -> f32 kc [b][m][h][d]
// ------------------------------------------------------------------
__global__ __launch_bounds__(256) void block_mean(const short* __restrict__ src,
                                                  float* __restrict__ dst) {
  int i = blockIdx.x * 256 + threadIdx.x;  // 65536
  int d = i & 127;
  int h = (i >> 7) & 15;
  int m = (i >> 11) & 15;
  int b = i >> 15;
  const short* p = src + (size_t)(b * NSEQ + m * BSZ) * QKV_STR + h * HDIM + d;
  float acc = 0.f;
#pragma unroll 8
  for (int j = 0; j < 64; ++j) acc += bf2f(p[(size_t)j * QKV_STR]);
  dst[i] = acc * (1.0f / 64.0f);
}

// ------------------------------------------------------------------
// V transpose -> vt[b][h][d][n], fused V block-mean -> vct[b][h][d][m]
// ------------------------------------------------------------------
__global__ __launch_bounds__(256) void v_transpose(const short* __restrict__ qkv,
                                                   short* __restrict__ vt,
                                                   short* __restrict__ vct) {
  __shared__ short tile[64][136];
  const int n0 = blockIdx.x * 64;
  const int h = blockIdx.y, b = blockIdx.z;
  const int t = threadIdx.x;
#pragma unroll
  for (int it = 0; it < 4; ++it) {
    int idx = t + 256 * it;
    int row = idx >> 4, ch = idx & 15;
    *(bfrag*)&tile[row][ch * 8] =
        *(const bfrag*)&qkv[(size_t)(b * NSEQ + n0 + row) * QKV_STR + VOFS + h * HDIM + ch * 8];
  }
  __syncthreads();
#pragma unroll
  for (int it = 0; it < 4; ++it) {
    int idx = t + 256 * it;
    int d = idx >> 3, ch = idx & 7;
    bfrag tv;
    float s = 0.f;
#pragma unroll
    for (int j = 0; j < 8; ++j) {
      tv[j] = tile[ch * 8 + j][d];
      s += bf2f(tv[j]);
    }
    *(bfrag*)&vt[(((size_t)(b * HN + h) * 128) + d) * 1024 + n0 + ch * 8] = tv;
    s += __shfl_down(s, 4);
    s += __shfl_down(s, 2);
    s += __shfl_down(s, 1);
    if ((t & 7) == 0)
      vct[(((size_t)(b * HN + h) * 128) + d) * 16 + (n0 >> 6)] = f2bf(s * (1.0f / 64.0f));
  }
}

// ------------------------------------------------------------------
// Compressed probs (bf16 pc [b][h][n][16]) + top-8 selection bitmask.
// ------------------------------------------------------------------
__global__ __launch_bounds__(64) void cmp_sel(const short* __restrict__ qkv,
                                              const float* __restrict__ kc,
                                              short* __restrict__ pc,
                                              int* __restrict__ sel) {
  int i = blockIdx.x * 64 + threadIdx.x;  // B*H*N = 32768
  int n = i & 1023;
  int h = (i >> 10) & 15;
  int b = i >> 14;
  const short* qp = qkv + (size_t)(b * NSEQ + n) * QKV_STR + h * HDIM;
  const int nv = (n + 1) >> 6;
  float s[NBLK];
#pragma unroll
  for (int m = 0; m < NBLK; ++m) s[m] = 0.f;
  for (int d0 = 0; d0 < HDIM; d0 += 8) {
    bfrag qv = *(const bfrag*)&qp[d0];
    float qf[8];
#pragma unroll
    for (int dd = 0; dd < 8; ++dd) qf[dd] = bf2f(qv[dd]);
    for (int m = 0; m < nv; ++m) {
      const float4* kp = (const float4*)(kc + ((size_t)((b * NBLK + m) * HN + h) << 7) + d0);
      const float4 k0 = kp[0], k1 = kp[1];
      s[m] += qf[0] * k0.x + qf[1] * k0.y + qf[2] * k0.z + qf[3] * k0.w +
              qf[4] * k1.x + qf[5] * k1.y + qf[6] * k1.z + qf[7] * k1.w;
    }
  }
  float mx = -1e30f;
  for (int m = 0; m < nv; ++m) { s[m] *= SCALE; mx = fmaxf(mx, s[m]); }
  float den = 0.f;
  for (int m = 0; m < nv; ++m) { s[m] = __expf(s[m] - mx); den += s[m]; }
  const float rden = (nv > 0) ? 1.0f / den : 0.f;
  float p[NBLK];
#pragma unroll
  for (int m = 0; m < NBLK; ++m) p[m] = (m < nv) ? s[m] * rden : 0.f;
  bfrag o0, o1;
#pragma unroll
  for (int m = 0; m < 8; ++m) { o0[m] = f2bf(p[m]); o1[m] = f2bf(p[m + 8]); }
  bfrag* pout = (bfrag*)(pc + (size_t)i * 16);
  pout[0] = o0; pout[1] = o1;
  p[n >> 6] += 2.0f;
  int mask = 0;
#pragma unroll
  for (int ss = 0; ss < 8; ++ss) {
    int best = 0;
    float bv = -1e30f;
#pragma unroll
    for (int m = 0; m < NBLK; ++m)
      if (p[m] > bv) { bv = p[m]; best = m; }
    mask |= 1 << best;
    p[best] = -1e30f;
  }
  sel[i] = mask;
}

// ------------------------------------------------------------------
// MFMA attention, LDS-staged: one block = 8 waves per (b,h), wave wid
// owns row-tile rt = wid*8 + rblk (striped -> uniform CTMAX per block).
// Per ct: stage K/V tile (ct+1) into XOR-swizzled double-buffered LDS
// (inverse-swz global source + swz ds_read, same pattern as gemm256),
// vmcnt(0)+barrier; waves compute their row-tile when active
// (predicated, no barriers inside compute). K/V now read once per
// block from L2 and 8x from LDS -- kills the per-wave L2-latency
// chains that capped R6-R13 at ~80us.
// ------------------------------------------------------------------
__global__ __launch_bounds__(512, 1) void attn_mfma(
    const short* __restrict__ qkv, const short* __restrict__ vt,
    const short* __restrict__ vct, const short* __restrict__ pc,
    const int* __restrict__ sel, short* __restrict__ o) {
  const int fid = blockIdx.x;            // 0..255
  const int xcd = fid & 7;
  const int idx = fid >> 3;              // 0..31
  const int pair = (xcd << 2) | (idx & 3);
  const int rblk = idx >> 2;             // 0..7
  const int h = pair & 15, b = pair >> 4;

  const int tid = threadIdx.x;
  const int wid = tid >> 6;              // 0..7
  const int l = tid & 63;
  const int lm = l & 15, hi = l >> 4;
  const int rt = wid * 8 + rblk;         // striped row-tile ownership
  const int nbase = rt * 16;
  const int CTMAX = ((56 + rblk) * 16) >> 6;  // thi of the largest rt in block

  __shared__ short kbuf[2][8192];        // [buf][64 n][128 d] swizzled
  __shared__ short vbuf[2][8192];        // [buf][128 d][64 n] swizzled
  __shared__ short pbuf[8][2][1024];     // per-wave P (slc/swa)
  short* p_slc = &pbuf[wid][0][0];
  short* p_swa = &pbuf[wid][1][0];

  // Q A-fragments
  const short* qrow = qkv + (size_t)(b * NSEQ + nbase + lm) * QKV_STR + h * HDIM;
  bfrag qf[4];
#pragma unroll
  for (int ks = 0; ks < 4; ++ks) qf[ks] = *(const bfrag*)&qrow[32 * ks + 8 * hi];

  // selection bits
  int selrow = sel[(size_t)(b * HN + h) * NSEQ + nbase + lm];
  int uni = selrow;
#pragma unroll
  for (int m = 1; m < 16; m <<= 1) uni |= __shfl_xor(uni, m);
  int sel4[4];
#pragma unroll
  for (int rg = 0; rg < 4; ++rg) sel4[rg] = __shfl(selrow, 4 * hi + rg);

  const int thi = nbase >> 6;
  const int tlo = (nbase >= 64) ? ((nbase - 64) >> 6) : 0;
  const int wmask = (int)((2u << thi) - (1u << tlo));
  const unsigned am = (unsigned)(uni | wmask) & (unsigned)((2u << thi) - 1);

  facc acc_slc[8] = {}, acc_swa[8] = {};
  float ps_s[4] = {0.f, 0.f, 0.f, 0.f}, ps_w[4] = {0.f, 0.f, 0.f, 0.f};

  // staging: K tile = qkv K rows [ct*64..+63] x 128 dims;
  //          V tile = vt rows [0..127 d] x n [ct*64..+63].
  // dest linear (thread idx2 -> 16B), source column pre-XOR-swizzled.
#define STAGEKV(ct_, buf_)                                                   \
  {                                                                          \
    _Pragma("unroll") for (int rr = 0; rr < 2; ++rr) {                       \
      const int i2 = tid + 512 * rr;                                         \
      const int rw = i2 >> 4, cc = i2 & 15;                                  \
      const short* g_ = qkv + (size_t)(b * NSEQ + (ct_) * 64 + rw) * QKV_STR \
                        + KOFS + h * HDIM + 8 * (cc ^ (rw & 7));             \
      ASYNC16(g_, &kbuf[buf_][i2 * 8]);                                      \
    }                                                                        \
    _Pragma("unroll") for (int rr = 0; rr < 2; ++rr) {                       \
      const int i2 = tid + 512 * rr;                                         \
      const int dd = i2 >> 3, cc = i2 & 7;                                   \
      const short* g_ = vt + ((size_t)(b * HN + h) * 128 + dd) * 1024        \
                        + (ct_) * 64 + 8 * (cc ^ (dd & 7));                  \
      ASYNC16(g_, &vbuf[buf_][i2 * 8]);                                      \
    }                                                                        \
  }

#define EXPF(f_)                                                            \
  _Pragma("unroll") for (int rg = 0; rg < 4; ++rg) {                        \
    const int col_ = ct * 64 + 16 * (f_) + lm;                              \
    const int row_ = nbase + 4 * hi + rg;                                   \
    float e_ = __expf(sacc[f_][rg] * SCALE);                                \
    e_ = (col_ <= row_) ? e_ : 0.f;                                         \
    float es_ = ((sel4[rg] >> ct) & 1) ? e_ : 0.f;                          \
    float ew_ = (row_ - col_ <= 64) ? e_ : 0.f;                             \
    ps_s[rg] += es_;                                                        \
    ps_w[rg] += ew_;                                                        \
    const int srow_ = 4 * hi + rg;                                          \
    const int sidx_ = (64 * srow_ + 16 * (f_) + lm) ^ ((srow_ & 7) << 3);   \
    if (do_s) p_slc[sidx_] = f2bf(es_);                                     \
    if (do_w) p_swa[sidx_] = f2bf(ew_);                                     \
  }

  // prologue: stage tile 0 into buf 0
  STAGEKV(0, 0);
  asm volatile("s_waitcnt vmcnt(0)" ::: "memory");
  __syncthreads();

  for (int ct = 0; ct <= CTMAX; ++ct) {
    const int cur = ct & 1;
    if (ct < CTMAX) STAGEKV(ct + 1, cur ^ 1);

    if ((am >> ct) & 1) {
      const bool do_s = (uni >> ct) & 1;
      const bool do_w = (wmask >> ct) & 1;

      // QK^T from LDS K tile
      facc sacc[4] = {};
#pragma unroll
      for (int f = 0; f < 4; ++f) {
        const int row_ = 16 * f + lm;
        const int rx = row_ & 7;
        bfrag k0 = *(const bfrag*)&kbuf[cur][row_ * 128 + 8 * ((0 + hi) ^ rx)];
        bfrag k1 = *(const bfrag*)&kbuf[cur][row_ * 128 + 8 * ((4 + hi) ^ rx)];
        bfrag k2 = *(const bfrag*)&kbuf[cur][row_ * 128 + 8 * ((8 + hi) ^ rx)];
        bfrag k3 = *(const bfrag*)&kbuf[cur][row_ * 128 + 8 * ((12 + hi) ^ rx)];
        sacc[f] = MFMA16(qf[0], k0, sacc[f]);
        sacc[f] = MFMA16(qf[1], k1, sacc[f]);
        sacc[f] = MFMA16(qf[2], k2, sacc[f]);
        sacc[f] = MFMA16(qf[3], k3, sacc[f]);
      }

      EXPF(0); EXPF(1); EXPF(2); EXPF(3);

      // PV from LDS V tile (per-wave P buffers; within-wave ordering)
#pragma unroll
      for (int ks = 0; ks < 2; ++ks) {
        const int ridx = (64 * lm + 8 * hi + 32 * ks) ^ ((lm & 7) << 3);
        bfrag pas = {}, paw = {};
        if (do_s) pas = *(const bfrag*)&p_slc[ridx];
        if (do_w) paw = *(const bfrag*)&p_swa[ridx];
#pragma unroll
        for (int df = 0; df < 8; ++df) {
          const int d_ = 16 * df + lm;
          bfrag vb = *(const bfrag*)&vbuf[cur][d_ * 64 + 8 * ((4 * ks + hi) ^ (d_ & 7))];
          if (do_s) acc_slc[df] = MFMA16(pas, vb, acc_slc[df]);
          if (do_w) acc_swa[df] = MFMA16(paw, vb, acc_swa[df]);
        }
      }
    }

    asm volatile("s_waitcnt vmcnt(0)" ::: "memory");
    __syncthreads();
  }
#undef STAGEKV
#undef EXPF

  // ---- compressed branch: O_cmp = Pc[16x16] * Vc[16x128], K padded to 32
  facc acc_cmp[8] = {};
  {
    bfrag pa = {};
    if (hi < 2)
      pa = *(const bfrag*)&pc[((size_t)(b * HN + h) * NSEQ + nbase + lm) * 16 + 8 * hi];
#pragma unroll
    for (int df = 0; df < 8; ++df) {
      bfrag vb = {};
      if (hi < 2)
        vb = *(const bfrag*)&vct[(((size_t)(b * HN + h) * 128) + 16 * df + lm) * 16 + 8 * hi];
      acc_cmp[df] = MFMA16(pa, vb, acc_cmp[df]);
    }
  }

  // ---- denominators: reduce across the 16 col-lanes
#pragma unroll
  for (int m = 1; m < 16; m <<= 1) {
#pragma unroll
    for (int rg = 0; rg < 4; ++rg) {
      ps_s[rg] += __shfl_xor(ps_s[rg], m);
      ps_w[rg] += __shfl_xor(ps_w[rg], m);
    }
  }

  float inv_s[4], inv_w[4], gcv[4], gsv[4], gwv[4];
#pragma unroll
  for (int rg = 0; rg < 4; ++rg) {
    inv_s[rg] = 1.0f / ps_s[rg];
    inv_w[rg] = 1.0f / ps_w[rg];
    const short* gp = qkv + (size_t)(b * NSEQ + nbase + 4 * hi + rg) * QKV_STR + GOFS;
    gcv[rg] = 1.0f / (1.0f + __expf(-bf2f(gp[h])));
    gsv[rg] = 1.0f / (1.0f + __expf(-bf2f(gp[16 + h])));
    gwv[rg] = 1.0f / (1.0f + __expf(-bf2f(gp[32 + h])));
  }

  short* obase = o + (size_t)(b * NSEQ + nbase) * 2048 + h * HDIM;
#pragma unroll
  for (int df = 0; df < 8; ++df)
#pragma unroll
    for (int rg = 0; rg < 4; ++rg) {
      float val = gcv[rg] * acc_cmp[df][rg] +
                  gsv[rg] * acc_slc[df][rg] * inv_s[rg] +
                  gwv[rg] * acc_swa[df][rg] * inv_w[rg];
      obase[(size_t)(4 * hi + rg) * 2048 + 16 * df + lm] = f2bf(val);
    }
}

// ------------------------------------------------------------------
extern "C" void kernel_launch(void* const* d_in, const int* in_sizes, int n_in,
                              void* d_out, int out_size, void* d_ws, size_t ws_size,
                              hipStream_t stream) {
  const float* x  = (const float*)d_in[0];
  const float* Wq = (const float*)d_in[1];
  const float* Wk = (const float*)d_in[2];
  const float* Wv = (const float*)d_in[3];
  const float* Wg = (const float*)d_in[4];
  const float* Wo = (const float*)d_in[5];
  float* out = (float*)d_out;

  char* w = (char*)d_ws;
  short* x_bf = (short*)w;            // 8.4 MB (reused as o_bf)
  short* o_bf = x_bf;
  w += (size_t)2048 * 2048 * 2;
  short* w_t  = (short*)w;            // 26.2 MB (rows 6272..6399 unused pad)
  w += (size_t)6400 * 2048 * 2;
  short* qkv  = (short*)w;            // 26.2 MB (stride 6400; gate at 6144)
  w += (size_t)2048 * 6400 * 2;
  float* kc   = (float*)w; w += (size_t)65536 * 4;
  short* vct  = (short*)w; w += (size_t)65536 * 2;
  short* pcb  = (short*)w; w += (size_t)524288 * 2;
  int*   sel  = (int*)w;   w += (size_t)32768 * 4;
  short* vt   = (short*)w; w += (size_t)4194304 * 2;  // 8.4 MB
  float2* tbl = (float2*)w; w += (size_t)65536 * 8;   // 0.5 MB

  const dim3 blk(256);
  prep<<<dim3(64, 64, 6), blk, 0, stream>>>(Wq, Wk, Wv, Wg, x, w_t, x_bf, tbl);
  gemm256<<<200, dim3(512), 0, stream>>>(x_bf, w_t, qkv, 2048, 6400, 2048);
  rope_qk<<<2048, blk, 0, stream>>>(qkv, tbl);
  block_mean<<<256, blk, 0, stream>>>(qkv + KOFS, kc);
  v_transpose<<<dim3(16, 16, 2), blk, 0, stream>>>(qkv, vt, vct);
  cmp_sel<<<512, dim3(64), 0, stream>>>(qkv, kc, pcb, sel);
  transpose_cast<<<dim3(64, 64), blk, 0, stream>>>(Wo, w_t);
  attn_mfma<<<256, dim3(512), 0, stream>>>(qkv, vt, vct, pcb, sel, o_bf);
  gemm_bf16_bt<float><<<256, blk, 0, stream>>>(o_bf, w_t, out, 2048, 2048, 2048);
}

// Round 15
// 237.747 us; speedup vs baseline: 1.1152x; 1.0183x over previous
//
#include <hip/hip_runtime.h>
#include <hip/hip_bf16.h>

// NSA forward: B=2, N=1024, D=2048, H=16, HD=128, BS=64, SEL=8, WIN=64
#define HN   16
#define HDIM 128
#define NSEQ 1024
#define NBLK 16
#define BSZ  64
#define SCALE 0.08838834764831845f
#define QKV_STR 6400   // row stride of fused qkv+gate buffer (bf16), padded to 25*256
#define KOFS 2048
#define VOFS 4096
#define GOFS 6144

typedef __attribute__((ext_vector_type(8))) short bfrag;   // 8 bf16 (4 VGPRs)
typedef __attribute__((ext_vector_type(4))) float facc;    // MFMA accumulator

__device__ __forceinline__ float bf2f(short s) {
  union { unsigned u; float f; } cv;
  cv.u = ((unsigned)(unsigned short)s) << 16;
  return cv.f;
}
__device__ __forceinline__ short f2bf(float f) {
  unsigned u = __float_as_uint(f);
  u = (u + 0x7fff + ((u >> 16) & 1)) >> 16;  // RNE
  return (short)u;
}

#define ASYNC16(gp, lp)                                                    \
  __builtin_amdgcn_global_load_lds(                                        \
      (const __attribute__((address_space(1))) void*)(gp),                 \
      (__attribute__((address_space(3))) void*)(lp), 16, 0, 0)

#define MFMA16(a, b, c) __builtin_amdgcn_mfma_f32_16x16x32_bf16(a, b, c, 0, 0, 0)

// ------------------------------------------------------------------
// prep: z=0..2 -> Wq/Wk/Wv transpose-cast into w_t rows z*2048..
//       z=3   -> Wg transposed + zero-padded to rows 6144..6271
//       z=4   -> x cast to bf16
//       z=5   -> RoPE cos/sin table
//       z=6   -> Wo transpose-cast into wo_t
// ------------------------------------------------------------------
__global__ __launch_bounds__(256) void prep(const float* __restrict__ Wq,
                                            const float* __restrict__ Wk,
                                            const float* __restrict__ Wv,
                                            const float* __restrict__ Wg,
                                            const float* __restrict__ Wo,
                                            const float* __restrict__ x,
                                            short* __restrict__ w_t,
                                            short* __restrict__ wo_t,
                                            short* __restrict__ x_bf,
                                            float2* __restrict__ tbl) {
  __shared__ float tile[32][33];
  const int z = blockIdx.z;
  const int bx = blockIdx.x * 32, by = blockIdx.y * 32;
  const int tx = threadIdx.x & 31, ty = threadIdx.x >> 5;
  if (z == 5) {
    if (blockIdx.y >= 4) return;
    int i = (blockIdx.y * 64 + blockIdx.x) * 256 + threadIdx.x;  // < 65536
    int d = i & 63, n = i >> 6;
    float inv = expf(-(float)d * (9.210340371976184f / 64.0f));
    float sn, cs;
    sincosf((float)n * inv, &sn, &cs);
    tbl[i] = make_float2(cs, sn);
    return;
  }
  if (z == 4) {
#pragma unroll
    for (int i = 0; i < 4; ++i) {
      const int row = by + ty + 8 * i;
      x_bf[(size_t)row * 2048 + bx + tx] = f2bf(x[(size_t)row * 2048 + bx + tx]);
    }
    return;
  }
  if (z == 3) {
    if (blockIdx.x >= 4) return;  // only 128 dst rows
#pragma unroll
    for (int i = 0; i < 4; ++i) {
      const int c = bx + tx;
      tile[ty + 8 * i][tx] = (c < 48) ? Wg[(size_t)(by + ty + 8 * i) * 48 + c] : 0.f;
    }
    __syncthreads();
#pragma unroll
    for (int i = 0; i < 4; ++i)
      w_t[(size_t)(GOFS + bx + ty + 8 * i) * 2048 + by + tx] = f2bf(tile[tx][ty + 8 * i]);
    return;
  }
  if (z == 6) {
#pragma unroll
    for (int i = 0; i < 4; ++i)
      tile[ty + 8 * i][tx] = Wo[(size_t)(by + ty + 8 * i) * 2048 + bx + tx];
    __syncthreads();
#pragma unroll
    for (int i = 0; i < 4; ++i)
      wo_t[(size_t)(bx + ty + 8 * i) * 2048 + by + tx] = f2bf(tile[tx][ty + 8 * i]);
    return;
  }
  const float* src = (z == 0) ? Wq : (z == 1) ? Wk : Wv;
#pragma unroll
  for (int i = 0; i < 4; ++i)
    tile[ty + 8 * i][tx] = src[(size_t)(by + ty + 8 * i) * 2048 + bx + tx];
  __syncthreads();
#pragma unroll
  for (int i = 0; i < 4; ++i)
    w_t[(size_t)(z * 2048 + bx + ty + 8 * i) * 2048 + by + tx] = f2bf(tile[tx][ty + 8 * i]);
}

// ------------------------------------------------------------------
// 8-phase 256x256 bf16 GEMM (T2+T3+T4+T5): C[M][N] = A[M][K]*Bt[N][K]^T
// True m201 schedule: 2 K-tiles/iter, one half-tile staged per phase,
// uniform ~2-K-tile prefetch distance, vmcnt(4) only at phases 4 & 8.
// Safety: per K-tile, A-halves last read in P2, B-halves in P1; every
// stage targets a region whose last read is >= 1 barrier earlier, and
// every consumer is covered by the preceding counted vmcnt.
// Requires K % 128 == 0.
// ------------------------------------------------------------------
__global__ __launch_bounds__(512, 1) void gemm256(const short* __restrict__ A,
                                                  const short* __restrict__ Bt,
                                                  short* __restrict__ C,
                                                  int M, int N, int K) {
  __shared__ short lds[2][2][16384];  // [buf][A/B][256*64]
  const int t = threadIdx.x;
  const int l = t & 63, w = t >> 6;
  const int wm = w >> 2, wn = w & 3;
  const int lm = l & 15, hi = l >> 4;
  const int lanexor = (lm & 7) << 3;            // shorts
  const int kk0 = (hi * 8) ^ lanexor;           // ks=0 column (shorts)
  const int L = blockIdx.x;
  const int item = (L & 7) * (gridDim.x >> 3) + (L >> 3);  // bijective (nwg%8==0)
  const int nrow = M >> 8;
  const int row0 = (item % nrow) * 256, col0 = (item / nrow) * 256;
  const int nt = K >> 6;
  const int ni = nt >> 1;

  const int srow = t >> 3;
  const int scol = 8 * ((t & 7) ^ (srow & 7));
  const short* Ab = A + (size_t)(row0 + srow) * K + scol;
  const short* Bb = Bt + (size_t)(col0 + srow) * K + scol;

#define STAGE(mat, srcbase, h, tau, buf)                                     \
  {                                                                          \
    const short* g_ = (srcbase) + (size_t)(h) * 128 * K + (size_t)(tau) * 64;\
    short* d_ = &lds[buf][mat][(h) * 8192 + t * 8];                          \
    ASYNC16(g_, d_);                                                         \
    ASYNC16(g_ + (size_t)64 * K, d_ + 4096);                                 \
  }

#define DS_A(qm, cb)                                                         \
  _Pragma("unroll") for (int ii = 0; ii < 4; ++ii) {                         \
    const int row_ = wm * 128 + (qm) * 64 + ii * 16 + lm;                    \
    af[ii * 2 + 0] = *(const bfrag*)&lds[cb][0][row_ * 64 + kk0];            \
    af[ii * 2 + 1] = *(const bfrag*)&lds[cb][0][row_ * 64 + (kk0 ^ 32)];     \
  }
#define DS_B(qn, arr, cb)                                                    \
  _Pragma("unroll") for (int jj = 0; jj < 2; ++jj) {                         \
    const int row_ = wn * 64 + (qn) * 32 + jj * 16 + lm;                     \
    arr[jj * 2 + 0] = *(const bfrag*)&lds[cb][1][row_ * 64 + kk0];           \
    arr[jj * 2 + 1] = *(const bfrag*)&lds[cb][1][row_ * 64 + (kk0 ^ 32)];    \
  }
#define QUAD(qm, qn, arr)                                                    \
  _Pragma("unroll") for (int ii = 0; ii < 4; ++ii)                           \
  _Pragma("unroll") for (int jj = 0; jj < 2; ++jj) {                         \
    acc[(qm)*4+ii][(qn)*2+jj] = MFMA16(af[ii*2+0], arr[jj*2+0], acc[(qm)*4+ii][(qn)*2+jj]); \
    acc[(qm)*4+ii][(qn)*2+jj] = MFMA16(af[ii*2+1], arr[jj*2+1], acc[(qm)*4+ii][(qn)*2+jj]); \
  }
#define BARLG                                                                \
  __builtin_amdgcn_s_barrier();                                              \
  asm volatile("s_waitcnt lgkmcnt(0)" ::: "memory");                         \
  __builtin_amdgcn_sched_barrier(0)
#define PRIO1 __builtin_amdgcn_s_setprio(1)
#define PRIO0 __builtin_amdgcn_s_setprio(0)
#define BAR __builtin_amdgcn_s_barrier()

  facc acc[8][4] = {};
  bfrag af[8], bf0[4], bf1[4];

  // prologue: full tile 0 -> buf0, B halves of tile 1 -> buf1
  STAGE(0, Ab, 0, 0, 0); STAGE(0, Ab, 1, 0, 0);
  STAGE(1, Bb, 0, 0, 0); STAGE(1, Bb, 1, 0, 0);
  STAGE(1, Bb, 0, 1, 1); STAGE(1, Bb, 1, 1, 1);
  asm volatile("s_waitcnt vmcnt(4)" ::: "memory");
  BAR;

  for (int i = 0; i < ni; ++i) {
    const int t1 = 2 * i + 1;
    const int g2 = (2 * i + 2 < nt) ? 2 * i + 2 : 2 * i;
    const int g3 = (2 * i + 3 < nt) ? 2 * i + 3 : t1;

    // ======== K-tile tau0 = 2i (buf0) ========
    // ph1
    DS_A(0, 0); DS_B(0, bf0, 0);
    STAGE(0, Ab, 0, t1, 1);
    BARLG; PRIO1; QUAD(0, 0, bf0); PRIO0; BAR;
    // ph2
    DS_B(1, bf1, 0);
    STAGE(0, Ab, 1, t1, 1);
    BARLG; PRIO1; QUAD(0, 1, bf1); PRIO0; BAR;
    // ph3
    DS_A(1, 0);
    STAGE(1, Bb, 0, g2, 0);
    BARLG; PRIO1; QUAD(1, 1, bf1); PRIO0; BAR;
    // ph4
    STAGE(1, Bb, 1, g2, 0);
    PRIO1; QUAD(1, 0, bf0); PRIO0;
    asm volatile("s_waitcnt vmcnt(4)" ::: "memory");
    BAR;

    // ======== K-tile tau1 = 2i+1 (buf1) ========
    // ph5
    DS_A(0, 1); DS_B(0, bf0, 1);
    STAGE(0, Ab, 0, g2, 0);
    BARLG; PRIO1; QUAD(0, 0, bf0); PRIO0; BAR;
    // ph6
    DS_B(1, bf1, 1);
    STAGE(0, Ab, 1, g2, 0);
    BARLG; PRIO1; QUAD(0, 1, bf1); PRIO0; BAR;
    // ph7
    DS_A(1, 1);
    STAGE(1, Bb, 0, g3, 1);
    BARLG; PRIO1; QUAD(1, 1, bf1); PRIO0; BAR;
    // ph8
    STAGE(1, Bb, 1, g3, 1);
    PRIO1; QUAD(1, 0, bf0); PRIO0;
    asm volatile("s_waitcnt vmcnt(4)" ::: "memory");
    BAR;
  }

#pragma unroll
  for (int i = 0; i < 8; ++i)
#pragma unroll
    for (int j = 0; j < 4; ++j)
#pragma unroll
      for (int rr = 0; rr < 4; ++rr)
        C[(size_t)(row0 + wm * 128 + i * 16 + hi * 4 + rr) * N +
          col0 + wn * 64 + j * 16 + lm] = f2bf(acc[i][j][rr]);
#undef STAGE
#undef DS_A
#undef DS_B
#undef QUAD
#undef BARLG
#undef PRIO1
#undef PRIO0
#undef BAR
}

// ------------------------------------------------------------------
// bf16 MFMA GEMM (m97 128^2): C[M][N] = A[M][K] * Bt[N][K]^T (out proj)
// ------------------------------------------------------------------
__device__ __forceinline__ void store_c(float* p, float v) { *p = v; }
__device__ __forceinline__ void store_c(short* p, float v) { *p = f2bf(v); }

template <typename OT>
__global__ __launch_bounds__(256) void gemm_bf16_bt(const short* __restrict__ A,
                                                    const short* __restrict__ Bt,
                                                    OT* __restrict__ C,
                                                    int M, int N, int K) {
  __shared__ short As[128 * 32];
  __shared__ short Bs[128 * 32];
  const int t = threadIdx.x;
  const int l = t & 63, w = t >> 6;
  const int wr = w >> 1, wc = w & 1;
  const int nwg = gridDim.x;
  const int L = blockIdx.x;
  const int wg = (L & 7) * (nwg >> 3) + (L >> 3);
  const int nrow = M >> 7;
  const int row0 = (wg % nrow) * 128, col0 = (wg / nrow) * 128;
  facc acc[4][4] = {};

  const int sr = t >> 2;
  const int sk = (t & 3) * 8;
  const short* Ag0 = A + (size_t)(row0 + sr) * K + sk;
  const short* Ag1 = Ag0 + (size_t)64 * K;
  const short* Bg0 = Bt + (size_t)(col0 + sr) * K + sk;
  const short* Bg1 = Bg0 + (size_t)64 * K;
  short* la = As + t * 8;
  short* lb = Bs + t * 8;

  const int lm = l & 15;
  const int lk = (l >> 4) * 8;

  for (int k0 = 0; k0 < K; k0 += 32) {
    ASYNC16(Ag0 + k0, la);
    ASYNC16(Ag1 + k0, la + 2048);
    ASYNC16(Bg0 + k0, lb);
    ASYNC16(Bg1 + k0, lb + 2048);
    __syncthreads();
    bfrag af[4], bf[4];
#pragma unroll
    for (int i = 0; i < 4; ++i)
      af[i] = *(const bfrag*)&As[(wr * 64 + i * 16 + lm) * 32 + lk];
#pragma unroll
    for (int j = 0; j < 4; ++j)
      bf[j] = *(const bfrag*)&Bs[(wc * 64 + j * 16 + lm) * 32 + lk];
#pragma unroll
    for (int i = 0; i < 4; ++i)
#pragma unroll
      for (int j = 0; j < 4; ++j)
        acc[i][j] = MFMA16(af[i], bf[j], acc[i][j]);
    __syncthreads();
  }

  const int orow = row0 + wr * 64 + (l >> 4) * 4;
  const int ocol = col0 + wc * 64 + lm;
#pragma unroll
  for (int i = 0; i < 4; ++i)
#pragma unroll
    for (int j = 0; j < 4; ++j)
#pragma unroll
      for (int rr = 0; rr < 4; ++rr)
        store_c(&C[(size_t)(orow + i * 16 + rr) * N + ocol + j * 16], acc[i][j][rr]);
}

// ------------------------------------------------------------------
// RoPE in place on q AND k slices, table-based, 8 dims/thread
// ------------------------------------------------------------------
__global__ __launch_bounds__(256) void rope_qk(short* __restrict__ qkv,
                                               const float2* __restrict__ tbl) {
  int i = blockIdx.x * 256 + threadIdx.x;  // 524288
  int c = i & 7;
  int h = (i >> 3) & 15;
  int qk = (i >> 7) & 1;
  int n = (i >> 8) & 1023;
  int b = i >> 18;
  short* base = qkv + (size_t)(b * NSEQ + n) * QKV_STR + qk * KOFS + h * HDIM + c * 8;
  const float2* tp = tbl + n * 64 + c * 8;
  bfrag t1 = *(const bfrag*)base, t2 = *(const bfrag*)(base + 64);
  bfrag o1, o2;
#pragma unroll
  for (int j = 0; j < 8; ++j) {
    float2 cssn = tp[j];
    float a = bf2f(t1[j]), bb = bf2f(t2[j]);
    o1[j] = f2bf(a * cssn.x - bb * cssn.y);
    o2[j] = f2bf(a * cssn.y + bb * cssn.x);
  }
  *(bfrag*)base = o1;
  *(bfrag*)(base + 64) = o2;
}

// ------------------------------------------------------------------
// Block mean (roped K) -> f32 kc [b][m][h][d]
// ------------------------------------------------------------------
__global__ __launch_bounds__(256) void block_mean(const short* __restrict__ src,
                                                  float* __restrict__ dst) {
  int i = blockIdx.x * 256 + threadIdx.x;  // 65536
  int d = i & 127;
  int h = (i >> 7) & 15;
  int m = (i >> 11) & 15;
  int b = i >> 15;
  const short* p = src + (size_t)(b * NSEQ + m * BSZ) * QKV_STR + h * HDIM + d;
  float acc = 0.f;
#pragma unroll 8
  for (int j = 0; j < 64; ++j) acc += bf2f(p[(size_t)j * QKV_STR]);
  dst[i] = acc * (1.0f / 64.0f);
}

// ------------------------------------------------------------------
// V transpose -> vt[b][h][d][n], fused V block-mean -> vct[b][h][d][m]
// ------------------------------------------------------------------
__global__ __launch_bounds__(256) void v_transpose(const short* __restrict__ qkv,
                                                   short* __restrict__ vt,
                                                   short* __restrict__ vct) {
  __shared__ short tile[64][136];
  const int n0 = blockIdx.x * 64;
  const int h = blockIdx.y, b = blockIdx.z;
  const int t = threadIdx.x;
#pragma unroll
  for (int it = 0; it < 4; ++it) {
    int idx = t + 256 * it;
    int row = idx >> 4, ch = idx & 15;
    *(bfrag*)&tile[row][ch * 8] =
        *(const bfrag*)&qkv[(size_t)(b * NSEQ + n0 + row) * QKV_STR + VOFS + h * HDIM + ch * 8];
  }
  __syncthreads();
#pragma unroll
  for (int it = 0; it < 4; ++it) {
    int idx = t + 256 * it;
    int d = idx >> 3, ch = idx & 7;
    bfrag tv;
    float s = 0.f;
#pragma unroll
    for (int j = 0; j < 8; ++j) {
      tv[j] = tile[ch * 8 + j][d];
      s += bf2f(tv[j]);
    }
    *(bfrag*)&vt[(((size_t)(b * HN + h) * 128) + d) * 1024 + n0 + ch * 8] = tv;
    s += __shfl_down(s, 4);
    s += __shfl_down(s, 2);
    s += __shfl_down(s, 1);
    if ((t & 7) == 0)
      vct[(((size_t)(b * HN + h) * 128) + d) * 16 + (n0 >> 6)] = f2bf(s * (1.0f / 64.0f));
  }
}

// ------------------------------------------------------------------
// Compressed probs (bf16 pc [b][h][n][16]) + top-8 selection bitmask.
// ------------------------------------------------------------------
__global__ __launch_bounds__(64) void cmp_sel(const short* __restrict__ qkv,
                                              const float* __restrict__ kc,
                                              short* __restrict__ pc,
                                              int* __restrict__ sel) {
  int i = blockIdx.x * 64 + threadIdx.x;  // B*H*N = 32768
  int n = i & 1023;
  int h = (i >> 10) & 15;
  int b = i >> 14;
  const short* qp = qkv + (size_t)(b * NSEQ + n) * QKV_STR + h * HDIM;
  const int nv = (n + 1) >> 6;
  float s[NBLK];
#pragma unroll
  for (int m = 0; m < NBLK; ++m) s[m] = 0.f;
  for (int d0 = 0; d0 < HDIM; d0 += 8) {
    bfrag qv = *(const bfrag*)&qp[d0];
    float qf[8];
#pragma unroll
    for (int dd = 0; dd < 8; ++dd) qf[dd] = bf2f(qv[dd]);
    for (int m = 0; m < nv; ++m) {
      const float4* kp = (const float4*)(kc + ((size_t)((b * NBLK + m) * HN + h) << 7) + d0);
      const float4 k0 = kp[0], k1 = kp[1];
      s[m] += qf[0] * k0.x + qf[1] * k0.y + qf[2] * k0.z + qf[3] * k0.w +
              qf[4] * k1.x + qf[5] * k1.y + qf[6] * k1.z + qf[7] * k1.w;
    }
  }
  float mx = -1e30f;
  for (int m = 0; m < nv; ++m) { s[m] *= SCALE; mx = fmaxf(mx, s[m]); }
  float den = 0.f;
  for (int m = 0; m < nv; ++m) { s[m] = __expf(s[m] - mx); den += s[m]; }
  const float rden = (nv > 0) ? 1.0f / den : 0.f;
  float p[NBLK];
#pragma unroll
  for (int m = 0; m < NBLK; ++m) p[m] = (m < nv) ? s[m] * rden : 0.f;
  bfrag o0, o1;
#pragma unroll
  for (int m = 0; m < 8; ++m) { o0[m] = f2bf(p[m]); o1[m] = f2bf(p[m + 8]); }
  bfrag* pout = (bfrag*)(pc + (size_t)i * 16);
  pout[0] = o0; pout[1] = o1;
  p[n >> 6] += 2.0f;
  int mask = 0;
#pragma unroll
  for (int ss = 0; ss < 8; ++ss) {
    int best = 0;
    float bv = -1e30f;
#pragma unroll
    for (int m = 0; m < NBLK; ++m)
      if (p[m] > bv) { bv = p[m]; best = m; }
    mask |= 1 << best;
    p[best] = -1e30f;
  }
  sel[i] = mask;
}

// ------------------------------------------------------------------
// MFMA attention, LDS-staged (proven R14): one block = 8 waves per
// (b,h), wave wid owns row-tile rt = wid*8 + rblk. Per ct: stage K/V
// tile (ct+1) into XOR-swizzled double-buffered LDS, vmcnt(0)+barrier;
// waves compute their row-tile when active.
// ------------------------------------------------------------------
__global__ __launch_bounds__(512, 1) void attn_mfma(
    const short* __restrict__ qkv, const short* __restrict__ vt,
    const short* __restrict__ vct, const short* __restrict__ pc,
    const int* __restrict__ sel, short* __restrict__ o) {
  const int fid = blockIdx.x;            // 0..255
  const int xcd = fid & 7;
  const int idx = fid >> 3;              // 0..31
  const int pair = (xcd << 2) | (idx & 3);
  const int rblk = idx >> 2;             // 0..7
  const int h = pair & 15, b = pair >> 4;

  const int tid = threadIdx.x;
  const int wid = tid >> 6;              // 0..7
  const int l = tid & 63;
  const int lm = l & 15, hi = l >> 4;
  const int rt = wid * 8 + rblk;         // striped row-tile ownership
  const int nbase = rt * 16;
  const int CTMAX = ((56 + rblk) * 16) >> 6;  // thi of the largest rt in block

  __shared__ short kbuf[2][8192];        // [buf][64 n][128 d] swizzled
  __shared__ short vbuf[2][8192];        // [buf][128 d][64 n] swizzled
  __shared__ short pbuf[8][2][1024];     // per-wave P (slc/swa)
  short* p_slc = &pbuf[wid][0][0];
  short* p_swa = &pbuf[wid][1][0];

  // Q A-fragments
  const short* qrow = qkv + (size_t)(b * NSEQ + nbase + lm) * QKV_STR + h * HDIM;
  bfrag qf[4];
#pragma unroll
  for (int ks = 0; ks < 4; ++ks) qf[ks] = *(const bfrag*)&qrow[32 * ks + 8 * hi];

  // selection bits
  int selrow = sel[(size_t)(b * HN + h) * NSEQ + nbase + lm];
  int uni = selrow;
#pragma unroll
  for (int m = 1; m < 16; m <<= 1) uni |= __shfl_xor(uni, m);
  int sel4[4];
#pragma unroll
  for (int rg = 0; rg < 4; ++rg) sel4[rg] = __shfl(selrow, 4 * hi + rg);

  const int thi = nbase >> 6;
  const int tlo = (nbase >= 64) ? ((nbase - 64) >> 6) : 0;
  const int wmask = (int)((2u << thi) - (1u << tlo));
  const unsigned am = (unsigned)(uni | wmask) & (unsigned)((2u << thi) - 1);

  facc acc_slc[8] = {}, acc_swa[8] = {};
  float ps_s[4] = {0.f, 0.f, 0.f, 0.f}, ps_w[4] = {0.f, 0.f, 0.f, 0.f};

#define STAGEKV(ct_, buf_)                                                   \
  {                                                                          \
    _Pragma("unroll") for (int rr = 0; rr < 2; ++rr) {                       \
      const int i2 = tid + 512 * rr;                                         \
      const int rw = i2 >> 4, cc = i2 & 15;                                  \
      const short* g_ = qkv + (size_t)(b * NSEQ + (ct_) * 64 + rw) * QKV_STR \
                        + KOFS + h * HDIM + 8 * (cc ^ (rw & 7));             \
      ASYNC16(g_, &kbuf[buf_][i2 * 8]);                                      \
    }                                                                        \
    _Pragma("unroll") for (int rr = 0; rr < 2; ++rr) {                       \
      const int i2 = tid + 512 * rr;                                         \
      const int dd = i2 >> 3, cc = i2 & 7;                                   \
      const short* g_ = vt + ((size_t)(b * HN + h) * 128 + dd) * 1024        \
                        + (ct_) * 64 + 8 * (cc ^ (dd & 7));                  \
      ASYNC16(g_, &vbuf[buf_][i2 * 8]);                                      \
    }                                                                        \
  }

#define EXPF(f_)                                                            \
  _Pragma("unroll") for (int rg = 0; rg < 4; ++rg) {                        \
    const int col_ = ct * 64 + 16 * (f_) + lm;                              \
    const int row_ = nbase + 4 * hi + rg;                                   \
    float e_ = __expf(sacc[f_][rg] * SCALE);                                \
    e_ = (col_ <= row_) ? e_ : 0.f;                                         \
    float es_ = ((sel4[rg] >> ct) & 1) ? e_ : 0.f;                          \
    float ew_ = (row_ - col_ <= 64) ? e_ : 0.f;                             \
    ps_s[rg] += es_;                                                        \
    ps_w[rg] += ew_;                                                        \
    const int srow_ = 4 * hi + rg;                                          \
    const int sidx_ = (64 * srow_ + 16 * (f_) + lm) ^ ((srow_ & 7) << 3);   \
    if (do_s) p_slc[sidx_] = f2bf(es_);                                     \
    if (do_w) p_swa[sidx_] = f2bf(ew_);                                     \
  }

  // prologue: stage tile 0 into buf 0
  STAGEKV(0, 0);
  asm volatile("s_waitcnt vmcnt(0)" ::: "memory");
  __syncthreads();

  for (int ct = 0; ct <= CTMAX; ++ct) {
    const int cur = ct & 1;
    if (ct < CTMAX) STAGEKV(ct + 1, cur ^ 1);

    if ((am >> ct) & 1) {
      const bool do_s = (uni >> ct) & 1;
      const bool do_w = (wmask >> ct) & 1;

      // QK^T from LDS K tile
      facc sacc[4] = {};
#pragma unroll
      for (int f = 0; f < 4; ++f) {
        const int row_ = 16 * f + lm;
        const int rx = row_ & 7;
        bfrag k0 = *(const bfrag*)&kbuf[cur][row_ * 128 + 8 * ((0 + hi) ^ rx)];
        bfrag k1 = *(const bfrag*)&kbuf[cur][row_ * 128 + 8 * ((4 + hi) ^ rx)];
        bfrag k2 = *(const bfrag*)&kbuf[cur][row_ * 128 + 8 * ((8 + hi) ^ rx)];
        bfrag k3 = *(const bfrag*)&kbuf[cur][row_ * 128 + 8 * ((12 + hi) ^ rx)];
        sacc[f] = MFMA16(qf[0], k0, sacc[f]);
        sacc[f] = MFMA16(qf[1], k1, sacc[f]);
        sacc[f] = MFMA16(qf[2], k2, sacc[f]);
        sacc[f] = MFMA16(qf[3], k3, sacc[f]);
      }

      EXPF(0); EXPF(1); EXPF(2); EXPF(3);

      // PV from LDS V tile
#pragma unroll
      for (int ks = 0; ks < 2; ++ks) {
        const int ridx = (64 * lm + 8 * hi + 32 * ks) ^ ((lm & 7) << 3);
        bfrag pas = {}, paw = {};
        if (do_s) pas = *(const bfrag*)&p_slc[ridx];
        if (do_w) paw = *(const bfrag*)&p_swa[ridx];
#pragma unroll
        for (int df = 0; df < 8; ++df) {
          const int d_ = 16 * df + lm;
          bfrag vb = *(const bfrag*)&vbuf[cur][d_ * 64 + 8 * ((4 * ks + hi) ^ (d_ & 7))];
          if (do_s) acc_slc[df] = MFMA16(pas, vb, acc_slc[df]);
          if (do_w) acc_swa[df] = MFMA16(paw, vb, acc_swa[df]);
        }
      }
    }

    asm volatile("s_waitcnt vmcnt(0)" ::: "memory");
    __syncthreads();
  }
#undef STAGEKV
#undef EXPF

  // ---- compressed branch: O_cmp = Pc[16x16] * Vc[16x128], K padded to 32
  facc acc_cmp[8] = {};
  {
    bfrag pa = {};
    if (hi < 2)
      pa = *(const bfrag*)&pc[((size_t)(b * HN + h) * NSEQ + nbase + lm) * 16 + 8 * hi];
#pragma unroll
    for (int df = 0; df < 8; ++df) {
      bfrag vb = {};
      if (hi < 2)
        vb = *(const bfrag*)&vct[(((size_t)(b * HN + h) * 128) + 16 * df + lm) * 16 + 8 * hi];
      acc_cmp[df] = MFMA16(pa, vb, acc_cmp[df]);
    }
  }

  // ---- denominators: reduce across the 16 col-lanes
#pragma unroll
  for (int m = 1; m < 16; m <<= 1) {
#pragma unroll
    for (int rg = 0; rg < 4; ++rg) {
      ps_s[rg] += __shfl_xor(ps_s[rg], m);
      ps_w[rg] += __shfl_xor(ps_w[rg], m);
    }
  }

  float inv_s[4], inv_w[4], gcv[4], gsv[4], gwv[4];
#pragma unroll
  for (int rg = 0; rg < 4; ++rg) {
    inv_s[rg] = 1.0f / ps_s[rg];
    inv_w[rg] = 1.0f / ps_w[rg];
    const short* gp = qkv + (size_t)(b * NSEQ + nbase + 4 * hi + rg) * QKV_STR + GOFS;
    gcv[rg] = 1.0f / (1.0f + __expf(-bf2f(gp[h])));
    gsv[rg] = 1.0f / (1.0f + __expf(-bf2f(gp[16 + h])));
    gwv[rg] = 1.0f / (1.0f + __expf(-bf2f(gp[32 + h])));
  }

  short* obase = o + (size_t)(b * NSEQ + nbase) * 2048 + h * HDIM;
#pragma unroll
  for (int df = 0; df < 8; ++df)
#pragma unroll
    for (int rg = 0; rg < 4; ++rg) {
      float val = gcv[rg] * acc_cmp[df][rg] +
                  gsv[rg] * acc_slc[df][rg] * inv_s[rg] +
                  gwv[rg] * acc_swa[df][rg] * inv_w[rg];
      obase[(size_t)(4 * hi + rg) * 2048 + 16 * df + lm] = f2bf(val);
    }
}

// ------------------------------------------------------------------
extern "C" void kernel_launch(void* const* d_in, const int* in_sizes, int n_in,
                              void* d_out, int out_size, void* d_ws, size_t ws_size,
                              hipStream_t stream) {
  const float* x  = (const float*)d_in[0];
  const float* Wq = (const float*)d_in[1];
  const float* Wk = (const float*)d_in[2];
  const float* Wv = (const float*)d_in[3];
  const float* Wg = (const float*)d_in[4];
  const float* Wo = (const float*)d_in[5];
  float* out = (float*)d_out;

  char* w = (char*)d_ws;
  short* x_bf = (short*)w;            // 8.4 MB (reused as o_bf)
  short* o_bf = x_bf;
  w += (size_t)2048 * 2048 * 2;
  short* w_t  = (short*)w;            // 26.2 MB (rows 6272..6399 unused pad)
  w += (size_t)6400 * 2048 * 2;
  short* qkv  = (short*)w;            // 26.2 MB (stride 6400; gate at 6144)
  w += (size_t)2048 * 6400 * 2;
  float* kc   = (float*)w; w += (size_t)65536 * 4;
  short* vct  = (short*)w; w += (size_t)65536 * 2;
  short* pcb  = (short*)w; w += (size_t)524288 * 2;
  int*   sel  = (int*)w;   w += (size_t)32768 * 4;
  short* vt   = (short*)w; w += (size_t)4194304 * 2;  // 8.4 MB
  float2* tbl = (float2*)w; w += (size_t)65536 * 8;   // 0.5 MB
  short* wo_t = (short*)w; w += (size_t)2048 * 2048 * 2;  // 8.4 MB

  const dim3 blk(256);
  prep<<<dim3(64, 64, 7), blk, 0, stream>>>(Wq, Wk, Wv, Wg, Wo, x, w_t, wo_t, x_bf, tbl);
  gemm256<<<200, dim3(512), 0, stream>>>(x_bf, w_t, qkv, 2048, 6400, 2048);
  rope_qk<<<2048, blk, 0, stream>>>(qkv, tbl);
  block_mean<<<256, blk, 0, stream>>>(qkv + KOFS, kc);
  v_transpose<<<dim3(16, 16, 2), blk, 0, stream>>>(qkv, vt, vct);
  cmp_sel<<<512, dim3(64), 0, stream>>>(qkv, kc, pcb, sel);
  attn_mfma<<<256, dim3(512), 0, stream>>>(qkv, vt, vct, pcb, sel, o_bf);
  gemm_bf16_bt<float><<<256, blk, 0, stream>>>(o_bf, wo_t, out, 2048, 2048, 2048);
}

// Round 16
// 230.383 us; speedup vs baseline: 1.1508x; 1.0320x over previous
//
#include <hip/hip_runtime.h>
#include <hip/hip_bf16.h>

// NSA forward: B=2, N=1024, D=2048, H=16, HD=128, BS=64, SEL=8, WIN=64
#define HN   16
#define HDIM 128
#define NSEQ 1024
#define NBLK 16
#define BSZ  64
#define SCALE 0.08838834764831845f
#define QKV_STR 6400   // row stride of fused qkv+gate buffer (bf16), padded to 25*256
#define KOFS 2048
#define VOFS 4096
#define GOFS 6144

typedef __attribute__((ext_vector_type(8))) short bfrag;   // 8 bf16 (4 VGPRs)
typedef __attribute__((ext_vector_type(4))) float facc;    // MFMA accumulator

__device__ __forceinline__ float bf2f(short s) {
  union { unsigned u; float f; } cv;
  cv.u = ((unsigned)(unsigned short)s) << 16;
  return cv.f;
}
__device__ __forceinline__ short f2bf(float f) {
  unsigned u = __float_as_uint(f);
  u = (u + 0x7fff + ((u >> 16) & 1)) >> 16;  // RNE
  return (short)u;
}

#define ASYNC16(gp, lp)                                                    \
  __builtin_amdgcn_global_load_lds(                                        \
      (const __attribute__((address_space(1))) void*)(gp),                 \
      (__attribute__((address_space(3))) void*)(lp), 16, 0, 0)

#define MFMA16(a, b, c) __builtin_amdgcn_mfma_f32_16x16x32_bf16(a, b, c, 0, 0, 0)

// ------------------------------------------------------------------
// prep: z=0..2 -> Wq/Wk/Wv transpose-cast into w_t rows z*2048..
//       z=3   -> Wg transposed + zero-padded to rows 6144..6271
//       z=4   -> x cast to bf16
//       z=5   -> RoPE cos/sin table
//       z=6   -> Wo transpose-cast into wo_t
// ------------------------------------------------------------------
__global__ __launch_bounds__(256) void prep(const float* __restrict__ Wq,
                                            const float* __restrict__ Wk,
                                            const float* __restrict__ Wv,
                                            const float* __restrict__ Wg,
                                            const float* __restrict__ Wo,
                                            const float* __restrict__ x,
                                            short* __restrict__ w_t,
                                            short* __restrict__ wo_t,
                                            short* __restrict__ x_bf,
                                            float2* __restrict__ tbl) {
  __shared__ float tile[32][33];
  const int z = blockIdx.z;
  const int bx = blockIdx.x * 32, by = blockIdx.y * 32;
  const int tx = threadIdx.x & 31, ty = threadIdx.x >> 5;
  if (z == 5) {
    if (blockIdx.y >= 4) return;
    int i = (blockIdx.y * 64 + blockIdx.x) * 256 + threadIdx.x;  // < 65536
    int d = i & 63, n = i >> 6;
    float inv = expf(-(float)d * (9.210340371976184f / 64.0f));
    float sn, cs;
    sincosf((float)n * inv, &sn, &cs);
    tbl[i] = make_float2(cs, sn);
    return;
  }
  if (z == 4) {
#pragma unroll
    for (int i = 0; i < 4; ++i) {
      const int row = by + ty + 8 * i;
      x_bf[(size_t)row * 2048 + bx + tx] = f2bf(x[(size_t)row * 2048 + bx + tx]);
    }
    return;
  }
  if (z == 3) {
    if (blockIdx.x >= 4) return;  // only 128 dst rows
#pragma unroll
    for (int i = 0; i < 4; ++i) {
      const int c = bx + tx;
      tile[ty + 8 * i][tx] = (c < 48) ? Wg[(size_t)(by + ty + 8 * i) * 48 + c] : 0.f;
    }
    __syncthreads();
#pragma unroll
    for (int i = 0; i < 4; ++i)
      w_t[(size_t)(GOFS + bx + ty + 8 * i) * 2048 + by + tx] = f2bf(tile[tx][ty + 8 * i]);
    return;
  }
  if (z == 6) {
#pragma unroll
    for (int i = 0; i < 4; ++i)
      tile[ty + 8 * i][tx] = Wo[(size_t)(by + ty + 8 * i) * 2048 + bx + tx];
    __syncthreads();
#pragma unroll
    for (int i = 0; i < 4; ++i)
      wo_t[(size_t)(bx + ty + 8 * i) * 2048 + by + tx] = f2bf(tile[tx][ty + 8 * i]);
    return;
  }
  const float* src = (z == 0) ? Wq : (z == 1) ? Wk : Wv;
#pragma unroll
  for (int i = 0; i < 4; ++i)
    tile[ty + 8 * i][tx] = src[(size_t)(by + ty + 8 * i) * 2048 + bx + tx];
  __syncthreads();
#pragma unroll
  for (int i = 0; i < 4; ++i)
    w_t[(size_t)(z * 2048 + bx + ty + 8 * i) * 2048 + by + tx] = f2bf(tile[tx][ty + 8 * i]);
}

// ------------------------------------------------------------------
// 8-phase 256x256 bf16 GEMM (T2+T3+T4+T5): C[M][N] = A[M][K]*Bt[N][K]^T
// ------------------------------------------------------------------
__global__ __launch_bounds__(512, 1) void gemm256(const short* __restrict__ A,
                                                  const short* __restrict__ Bt,
                                                  short* __restrict__ C,
                                                  int M, int N, int K) {
  __shared__ short lds[2][2][16384];  // [buf][A/B][256*64]
  const int t = threadIdx.x;
  const int l = t & 63, w = t >> 6;
  const int wm = w >> 2, wn = w & 3;
  const int lm = l & 15, hi = l >> 4;
  const int lanexor = (lm & 7) << 3;            // shorts
  const int kk0 = (hi * 8) ^ lanexor;           // ks=0 column (shorts)
  const int L = blockIdx.x;
  const int item = (L & 7) * (gridDim.x >> 3) + (L >> 3);  // bijective (nwg%8==0)
  const int nrow = M >> 8;
  const int row0 = (item % nrow) * 256, col0 = (item / nrow) * 256;
  const int nt = K >> 6;
  const int ni = nt >> 1;

  const int srow = t >> 3;
  const int scol = 8 * ((t & 7) ^ (srow & 7));
  const short* Ab = A + (size_t)(row0 + srow) * K + scol;
  const short* Bb = Bt + (size_t)(col0 + srow) * K + scol;

#define STAGE(mat, srcbase, h, tau, buf)                                     \
  {                                                                          \
    const short* g_ = (srcbase) + (size_t)(h) * 128 * K + (size_t)(tau) * 64;\
    short* d_ = &lds[buf][mat][(h) * 8192 + t * 8];                          \
    ASYNC16(g_, d_);                                                         \
    ASYNC16(g_ + (size_t)64 * K, d_ + 4096);                                 \
  }

#define DS_A(qm, cb)                                                         \
  _Pragma("unroll") for (int ii = 0; ii < 4; ++ii) {                         \
    const int row_ = wm * 128 + (qm) * 64 + ii * 16 + lm;                    \
    af[ii * 2 + 0] = *(const bfrag*)&lds[cb][0][row_ * 64 + kk0];            \
    af[ii * 2 + 1] = *(const bfrag*)&lds[cb][0][row_ * 64 + (kk0 ^ 32)];     \
  }
#define DS_B(qn, arr, cb)                                                    \
  _Pragma("unroll") for (int jj = 0; jj < 2; ++jj) {                         \
    const int row_ = wn * 64 + (qn) * 32 + jj * 16 + lm;                     \
    arr[jj * 2 + 0] = *(const bfrag*)&lds[cb][1][row_ * 64 + kk0];           \
    arr[jj * 2 + 1] = *(const bfrag*)&lds[cb][1][row_ * 64 + (kk0 ^ 32)];    \
  }
#define QUAD(qm, qn, arr)                                                    \
  _Pragma("unroll") for (int ii = 0; ii < 4; ++ii)                           \
  _Pragma("unroll") for (int jj = 0; jj < 2; ++jj) {                         \
    acc[(qm)*4+ii][(qn)*2+jj] = MFMA16(af[ii*2+0], arr[jj*2+0], acc[(qm)*4+ii][(qn)*2+jj]); \
    acc[(qm)*4+ii][(qn)*2+jj] = MFMA16(af[ii*2+1], arr[jj*2+1], acc[(qm)*4+ii][(qn)*2+jj]); \
  }
#define BARLG                                                                \
  __builtin_amdgcn_s_barrier();                                              \
  asm volatile("s_waitcnt lgkmcnt(0)" ::: "memory");                         \
  __builtin_amdgcn_sched_barrier(0)
#define PRIO1 __builtin_amdgcn_s_setprio(1)
#define PRIO0 __builtin_amdgcn_s_setprio(0)
#define BAR __builtin_amdgcn_s_barrier()

  facc acc[8][4] = {};
  bfrag af[8], bf0[4], bf1[4];

  // prologue: full tile 0 -> buf0, B halves of tile 1 -> buf1
  STAGE(0, Ab, 0, 0, 0); STAGE(0, Ab, 1, 0, 0);
  STAGE(1, Bb, 0, 0, 0); STAGE(1, Bb, 1, 0, 0);
  STAGE(1, Bb, 0, 1, 1); STAGE(1, Bb, 1, 1, 1);
  asm volatile("s_waitcnt vmcnt(4)" ::: "memory");
  BAR;

  for (int i = 0; i < ni; ++i) {
    const int t1 = 2 * i + 1;
    const int g2 = (2 * i + 2 < nt) ? 2 * i + 2 : 2 * i;
    const int g3 = (2 * i + 3 < nt) ? 2 * i + 3 : t1;

    // ======== K-tile tau0 = 2i (buf0) ========
    DS_A(0, 0); DS_B(0, bf0, 0);
    STAGE(0, Ab, 0, t1, 1);
    BARLG; PRIO1; QUAD(0, 0, bf0); PRIO0; BAR;

    DS_B(1, bf1, 0);
    STAGE(0, Ab, 1, t1, 1);
    BARLG; PRIO1; QUAD(0, 1, bf1); PRIO0; BAR;

    DS_A(1, 0);
    STAGE(1, Bb, 0, g2, 0);
    BARLG; PRIO1; QUAD(1, 1, bf1); PRIO0; BAR;

    STAGE(1, Bb, 1, g2, 0);
    PRIO1; QUAD(1, 0, bf0); PRIO0;
    asm volatile("s_waitcnt vmcnt(4)" ::: "memory");
    BAR;

    // ======== K-tile tau1 = 2i+1 (buf1) ========
    DS_A(0, 1); DS_B(0, bf0, 1);
    STAGE(0, Ab, 0, g2, 0);
    BARLG; PRIO1; QUAD(0, 0, bf0); PRIO0; BAR;

    DS_B(1, bf1, 1);
    STAGE(0, Ab, 1, g2, 0);
    BARLG; PRIO1; QUAD(0, 1, bf1); PRIO0; BAR;

    DS_A(1, 1);
    STAGE(1, Bb, 0, g3, 1);
    BARLG; PRIO1; QUAD(1, 1, bf1); PRIO0; BAR;

    STAGE(1, Bb, 1, g3, 1);
    PRIO1; QUAD(1, 0, bf0); PRIO0;
    asm volatile("s_waitcnt vmcnt(4)" ::: "memory");
    BAR;
  }

#pragma unroll
  for (int i = 0; i < 8; ++i)
#pragma unroll
    for (int j = 0; j < 4; ++j)
#pragma unroll
      for (int rr = 0; rr < 4; ++rr)
        C[(size_t)(row0 + wm * 128 + i * 16 + hi * 4 + rr) * N +
          col0 + wn * 64 + j * 16 + lm] = f2bf(acc[i][j][rr]);
#undef STAGE
#undef DS_A
#undef DS_B
#undef QUAD
#undef BARLG
#undef PRIO1
#undef PRIO0
#undef BAR
}

// ------------------------------------------------------------------
// bf16 MFMA GEMM, 8-wave m97 variant (out proj): C = A * Bt^T.
// 512 thr = 8 waves (2M x 4N), per-wave 64x32 output; with a 256-block
// grid this gives 8 waves/CU = 2/SIMD (the 256-thr version at 1
// block/CU was 1 wave/SIMD -> fully exposed staging drains).
// ------------------------------------------------------------------
__device__ __forceinline__ void store_c(float* p, float v) { *p = v; }
__device__ __forceinline__ void store_c(short* p, float v) { *p = f2bf(v); }

template <typename OT>
__global__ __launch_bounds__(512, 1) void gemm_bf16_bt(const short* __restrict__ A,
                                                       const short* __restrict__ Bt,
                                                       OT* __restrict__ C,
                                                       int M, int N, int K) {
  __shared__ short As[128 * 32];
  __shared__ short Bs[128 * 32];
  const int t = threadIdx.x;          // 0..511
  const int l = t & 63, w = t >> 6;   // 8 waves
  const int wr = w >> 2, wc = w & 3;  // 2 x 4
  const int lm = l & 15, lk = (l >> 4) * 8;
  const int nwg = gridDim.x;
  const int L = blockIdx.x;
  const int wg = (L & 7) * (nwg >> 3) + (L >> 3);
  const int nrow = M >> 7;
  const int row0 = (wg % nrow) * 128, col0 = (wg / nrow) * 128;
  facc acc[4][2] = {};

  const int sr = t >> 2;              // 0..127
  const int sk = (t & 3) * 8;
  const short* Ag = A + (size_t)(row0 + sr) * K + sk;
  const short* Bg = Bt + (size_t)(col0 + sr) * K + sk;
  short* la = As + t * 8;
  short* lb = Bs + t * 8;

  for (int k0 = 0; k0 < K; k0 += 32) {
    ASYNC16(Ag + k0, la);
    ASYNC16(Bg + k0, lb);
    __syncthreads();
    bfrag af[4], bf[2];
#pragma unroll
    for (int i = 0; i < 4; ++i)
      af[i] = *(const bfrag*)&As[(wr * 64 + i * 16 + lm) * 32 + lk];
#pragma unroll
    for (int j = 0; j < 2; ++j)
      bf[j] = *(const bfrag*)&Bs[(wc * 32 + j * 16 + lm) * 32 + lk];
#pragma unroll
    for (int i = 0; i < 4; ++i)
#pragma unroll
      for (int j = 0; j < 2; ++j)
        acc[i][j] = MFMA16(af[i], bf[j], acc[i][j]);
    __syncthreads();
  }

  const int orow = row0 + wr * 64 + (l >> 4) * 4;
  const int ocol = col0 + wc * 32 + lm;
#pragma unroll
  for (int i = 0; i < 4; ++i)
#pragma unroll
    for (int j = 0; j < 2; ++j)
#pragma unroll
      for (int rr = 0; rr < 4; ++rr)
        store_c(&C[(size_t)(orow + i * 16 + rr) * N + ocol + j * 16], acc[i][j][rr]);
}

// ------------------------------------------------------------------
// RoPE in place on q AND k slices, table-based, 8 dims/thread
// ------------------------------------------------------------------
__global__ __launch_bounds__(256) void rope_qk(short* __restrict__ qkv,
                                               const float2* __restrict__ tbl) {
  int i = blockIdx.x * 256 + threadIdx.x;  // 524288
  int c = i & 7;
  int h = (i >> 3) & 15;
  int qk = (i >> 7) & 1;
  int n = (i >> 8) & 1023;
  int b = i >> 18;
  short* base = qkv + (size_t)(b * NSEQ + n) * QKV_STR + qk * KOFS + h * HDIM + c * 8;
  const float2* tp = tbl + n * 64 + c * 8;
  bfrag t1 = *(const bfrag*)base, t2 = *(const bfrag*)(base + 64);
  bfrag o1, o2;
#pragma unroll
  for (int j = 0; j < 8; ++j) {
    float2 cssn = tp[j];
    float a = bf2f(t1[j]), bb = bf2f(t2[j]);
    o1[j] = f2bf(a * cssn.x - bb * cssn.y);
    o2[j] = f2bf(a * cssn.y + bb * cssn.x);
  }
  *(bfrag*)base = o1;
  *(bfrag*)(base + 64) = o2;
}

// ------------------------------------------------------------------
// Block mean (roped K) -> f32 kc [b][m][h][d]
// ------------------------------------------------------------------
__global__ __launch_bounds__(256) void block_mean(const short* __restrict__ src,
                                                  float* __restrict__ dst) {
  int i = blockIdx.x * 256 + threadIdx.x;  // 65536
  int d = i & 127;
  int h = (i >> 7) & 15;
  int m = (i >> 11) & 15;
  int b = i >> 15;
  const short* p = src + (size_t)(b * NSEQ + m * BSZ) * QKV_STR + h * HDIM + d;
  float acc = 0.f;
#pragma unroll 8
  for (int j = 0; j < 64; ++j) acc += bf2f(p[(size_t)j * QKV_STR]);
  dst[i] = acc * (1.0f / 64.0f);
}

// ------------------------------------------------------------------
// V transpose -> vt[b][h][d][n], fused V block-mean -> vct[b][h][d][m]
// ------------------------------------------------------------------
__global__ __launch_bounds__(256) void v_transpose(const short* __restrict__ qkv,
                                                   short* __restrict__ vt,
                                                   short* __restrict__ vct) {
  __shared__ short tile[64][136];
  const int n0 = blockIdx.x * 64;
  const int h = blockIdx.y, b = blockIdx.z;
  const int t = threadIdx.x;
#pragma unroll
  for (int it = 0; it < 4; ++it) {
    int idx = t + 256 * it;
    int row = idx >> 4, ch = idx & 15;
    *(bfrag*)&tile[row][ch * 8] =
        *(const bfrag*)&qkv[(size_t)(b * NSEQ + n0 + row) * QKV_STR + VOFS + h * HDIM + ch * 8];
  }
  __syncthreads();
#pragma unroll
  for (int it = 0; it < 4; ++it) {
    int idx = t + 256 * it;
    int d = idx >> 3, ch = idx & 7;
    bfrag tv;
    float s = 0.f;
#pragma unroll
    for (int j = 0; j < 8; ++j) {
      tv[j] = tile[ch * 8 + j][d];
      s += bf2f(tv[j]);
    }
    *(bfrag*)&vt[(((size_t)(b * HN + h) * 128) + d) * 1024 + n0 + ch * 8] = tv;
    s += __shfl_down(s, 4);
    s += __shfl_down(s, 2);
    s += __shfl_down(s, 1);
    if ((t & 7) == 0)
      vct[(((size_t)(b * HN + h) * 128) + d) * 16 + (n0 >> 6)] = f2bf(s * (1.0f / 64.0f));
  }
}

// ------------------------------------------------------------------
// Compressed probs (bf16 pc [b][h][n][16]) + top-8 selection bitmask.
// ------------------------------------------------------------------
__global__ __launch_bounds__(64) void cmp_sel(const short* __restrict__ qkv,
                                              const float* __restrict__ kc,
                                              short* __restrict__ pc,
                                              int* __restrict__ sel) {
  int i = blockIdx.x * 64 + threadIdx.x;  // B*H*N = 32768
  int n = i & 1023;
  int h = (i >> 10) & 15;
  int b = i >> 14;
  const short* qp = qkv + (size_t)(b * NSEQ + n) * QKV_STR + h * HDIM;
  const int nv = (n + 1) >> 6;
  float s[NBLK];
#pragma unroll
  for (int m = 0; m < NBLK; ++m) s[m] = 0.f;
  for (int d0 = 0; d0 < HDIM; d0 += 8) {
    bfrag qv = *(const bfrag*)&qp[d0];
    float qf[8];
#pragma unroll
    for (int dd = 0; dd < 8; ++dd) qf[dd] = bf2f(qv[dd]);
    for (int m = 0; m < nv; ++m) {
      const float4* kp = (const float4*)(kc + ((size_t)((b * NBLK + m) * HN + h) << 7) + d0);
      const float4 k0 = kp[0], k1 = kp[1];
      s[m] += qf[0] * k0.x + qf[1] * k0.y + qf[2] * k0.z + qf[3] * k0.w +
              qf[4] * k1.x + qf[5] * k1.y + qf[6] * k1.z + qf[7] * k1.w;
    }
  }
  float mx = -1e30f;
  for (int m = 0; m < nv; ++m) { s[m] *= SCALE; mx = fmaxf(mx, s[m]); }
  float den = 0.f;
  for (int m = 0; m < nv; ++m) { s[m] = __expf(s[m] - mx); den += s[m]; }
  const float rden = (nv > 0) ? 1.0f / den : 0.f;
  float p[NBLK];
#pragma unroll
  for (int m = 0; m < NBLK; ++m) p[m] = (m < nv) ? s[m] * rden : 0.f;
  bfrag o0, o1;
#pragma unroll
  for (int m = 0; m < 8; ++m) { o0[m] = f2bf(p[m]); o1[m] = f2bf(p[m + 8]); }
  bfrag* pout = (bfrag*)(pc + (size_t)i * 16);
  pout[0] = o0; pout[1] = o1;
  p[n >> 6] += 2.0f;
  int mask = 0;
#pragma unroll
  for (int ss = 0; ss < 8; ++ss) {
    int best = 0;
    float bv = -1e30f;
#pragma unroll
    for (int m = 0; m < NBLK; ++m)
      if (p[m] > bv) { bv = p[m]; best = m; }
    mask |= 1 << best;
    p[best] = -1e30f;
  }
  sel[i] = mask;
}

// ------------------------------------------------------------------
// MFMA attention, LDS-staged (proven R14): one block = 8 waves per
// (b,h), wave wid owns row-tile rt = wid*8 + rblk. Per ct: stage K/V
// tile (ct+1) into XOR-swizzled double-buffered LDS, vmcnt(0)+barrier;
// waves compute their row-tile when active.
// ------------------------------------------------------------------
__global__ __launch_bounds__(512, 1) void attn_mfma(
    const short* __restrict__ qkv, const short* __restrict__ vt,
    const short* __restrict__ vct, const short* __restrict__ pc,
    const int* __restrict__ sel, short* __restrict__ o) {
  const int fid = blockIdx.x;            // 0..255
  const int xcd = fid & 7;
  const int idx = fid >> 3;              // 0..31
  const int pair = (xcd << 2) | (idx & 3);
  const int rblk = idx >> 2;             // 0..7
  const int h = pair & 15, b = pair >> 4;

  const int tid = threadIdx.x;
  const int wid = tid >> 6;              // 0..7
  const int l = tid & 63;
  const int lm = l & 15, hi = l >> 4;
  const int rt = wid * 8 + rblk;         // striped row-tile ownership
  const int nbase = rt * 16;
  const int CTMAX = ((56 + rblk) * 16) >> 6;  // thi of the largest rt in block

  __shared__ short kbuf[2][8192];        // [buf][64 n][128 d] swizzled
  __shared__ short vbuf[2][8192];        // [buf][128 d][64 n] swizzled
  __shared__ short pbuf[8][2][1024];     // per-wave P (slc/swa)
  short* p_slc = &pbuf[wid][0][0];
  short* p_swa = &pbuf[wid][1][0];

  // Q A-fragments
  const short* qrow = qkv + (size_t)(b * NSEQ + nbase + lm) * QKV_STR + h * HDIM;
  bfrag qf[4];
#pragma unroll
  for (int ks = 0; ks < 4; ++ks) qf[ks] = *(const bfrag*)&qrow[32 * ks + 8 * hi];

  // selection bits
  int selrow = sel[(size_t)(b * HN + h) * NSEQ + nbase + lm];
  int uni = selrow;
#pragma unroll
  for (int m = 1; m < 16; m <<= 1) uni |= __shfl_xor(uni, m);
  int sel4[4];
#pragma unroll
  for (int rg = 0; rg < 4; ++rg) sel4[rg] = __shfl(selrow, 4 * hi + rg);

  const int thi = nbase >> 6;
  const int tlo = (nbase >= 64) ? ((nbase - 64) >> 6) : 0;
  const int wmask = (int)((2u << thi) - (1u << tlo));
  const unsigned am = (unsigned)(uni | wmask) & (unsigned)((2u << thi) - 1);

  facc acc_slc[8] = {}, acc_swa[8] = {};
  float ps_s[4] = {0.f, 0.f, 0.f, 0.f}, ps_w[4] = {0.f, 0.f, 0.f, 0.f};

#define STAGEKV(ct_, buf_)                                                   \
  {                                                                          \
    _Pragma("unroll") for (int rr = 0; rr < 2; ++rr) {                       \
      const int i2 = tid + 512 * rr;                                         \
      const int rw = i2 >> 4, cc = i2 & 15;                                  \
      const short* g_ = qkv + (size_t)(b * NSEQ + (ct_) * 64 + rw) * QKV_STR \
                        + KOFS + h * HDIM + 8 * (cc ^ (rw & 7));             \
      ASYNC16(g_, &kbuf[buf_][i2 * 8]);                                      \
    }                                                                        \
    _Pragma("unroll") for (int rr = 0; rr < 2; ++rr) {                       \
      const int i2 = tid + 512 * rr;                                         \
      const int dd = i2 >> 3, cc = i2 & 7;                                   \
      const short* g_ = vt + ((size_t)(b * HN + h) * 128 + dd) * 1024        \
                        + (ct_) * 64 + 8 * (cc ^ (dd & 7));                  \
      ASYNC16(g_, &vbuf[buf_][i2 * 8]);                                      \
    }                                                                        \
  }

#define EXPF(f_)                                                            \
  _Pragma("unroll") for (int rg = 0; rg < 4; ++rg) {                        \
    const int col_ = ct * 64 + 16 * (f_) + lm;                              \
    const int row_ = nbase + 4 * hi + rg;                                   \
    float e_ = __expf(sacc[f_][rg] * SCALE);                                \
    e_ = (col_ <= row_) ? e_ : 0.f;                                         \
    float es_ = ((sel4[rg] >> ct) & 1) ? e_ : 0.f;                          \
    float ew_ = (row_ - col_ <= 64) ? e_ : 0.f;                             \
    ps_s[rg] += es_;                                                        \
    ps_w[rg] += ew_;                                                        \
    const int srow_ = 4 * hi + rg;                                          \
    const int sidx_ = (64 * srow_ + 16 * (f_) + lm) ^ ((srow_ & 7) << 3);   \
    if (do_s) p_slc[sidx_] = f2bf(es_);                                     \
    if (do_w) p_swa[sidx_] = f2bf(ew_);                                     \
  }

  // prologue: stage tile 0 into buf 0
  STAGEKV(0, 0);
  asm volatile("s_waitcnt vmcnt(0)" ::: "memory");
  __syncthreads();

  for (int ct = 0; ct <= CTMAX; ++ct) {
    const int cur = ct & 1;
    if (ct < CTMAX) STAGEKV(ct + 1, cur ^ 1);

    if ((am >> ct) & 1) {
      const bool do_s = (uni >> ct) & 1;
      const bool do_w = (wmask >> ct) & 1;

      // QK^T from LDS K tile
      facc sacc[4] = {};
#pragma unroll
      for (int f = 0; f < 4; ++f) {
        const int row_ = 16 * f + lm;
        const int rx = row_ & 7;
        bfrag k0 = *(const bfrag*)&kbuf[cur][row_ * 128 + 8 * ((0 + hi) ^ rx)];
        bfrag k1 = *(const bfrag*)&kbuf[cur][row_ * 128 + 8 * ((4 + hi) ^ rx)];
        bfrag k2 = *(const bfrag*)&kbuf[cur][row_ * 128 + 8 * ((8 + hi) ^ rx)];
        bfrag k3 = *(const bfrag*)&kbuf[cur][row_ * 128 + 8 * ((12 + hi) ^ rx)];
        sacc[f] = MFMA16(qf[0], k0, sacc[f]);
        sacc[f] = MFMA16(qf[1], k1, sacc[f]);
        sacc[f] = MFMA16(qf[2], k2, sacc[f]);
        sacc[f] = MFMA16(qf[3], k3, sacc[f]);
      }

      EXPF(0); EXPF(1); EXPF(2); EXPF(3);

      // PV from LDS V tile
#pragma unroll
      for (int ks = 0; ks < 2; ++ks) {
        const int ridx = (64 * lm + 8 * hi + 32 * ks) ^ ((lm & 7) << 3);
        bfrag pas = {}, paw = {};
        if (do_s) pas = *(const bfrag*)&p_slc[ridx];
        if (do_w) paw = *(const bfrag*)&p_swa[ridx];
#pragma unroll
        for (int df = 0; df < 8; ++df) {
          const int d_ = 16 * df + lm;
          bfrag vb = *(const bfrag*)&vbuf[cur][d_ * 64 + 8 * ((4 * ks + hi) ^ (d_ & 7))];
          if (do_s) acc_slc[df] = MFMA16(pas, vb, acc_slc[df]);
          if (do_w) acc_swa[df] = MFMA16(paw, vb, acc_swa[df]);
        }
      }
    }

    asm volatile("s_waitcnt vmcnt(0)" ::: "memory");
    __syncthreads();
  }
#undef STAGEKV
#undef EXPF

  // ---- compressed branch: O_cmp = Pc[16x16] * Vc[16x128], K padded to 32
  facc acc_cmp[8] = {};
  {
    bfrag pa = {};
    if (hi < 2)
      pa = *(const bfrag*)&pc[((size_t)(b * HN + h) * NSEQ + nbase + lm) * 16 + 8 * hi];
#pragma unroll
    for (int df = 0; df < 8; ++df) {
      bfrag vb = {};
      if (hi < 2)
        vb = *(const bfrag*)&vct[(((size_t)(b * HN + h) * 128) + 16 * df + lm) * 16 + 8 * hi];
      acc_cmp[df] = MFMA16(pa, vb, acc_cmp[df]);
    }
  }

  // ---- denominators: reduce across the 16 col-lanes
#pragma unroll
  for (int m = 1; m < 16; m <<= 1) {
#pragma unroll
    for (int rg = 0; rg < 4; ++rg) {
      ps_s[rg] += __shfl_xor(ps_s[rg], m);
      ps_w[rg] += __shfl_xor(ps_w[rg], m);
    }
  }

  float inv_s[4], inv_w[4], gcv[4], gsv[4], gwv[4];
#pragma unroll
  for (int rg = 0; rg < 4; ++rg) {
    inv_s[rg] = 1.0f / ps_s[rg];
    inv_w[rg] = 1.0f / ps_w[rg];
    const short* gp = qkv + (size_t)(b * NSEQ + nbase + 4 * hi + rg) * QKV_STR + GOFS;
    gcv[rg] = 1.0f / (1.0f + __expf(-bf2f(gp[h])));
    gsv[rg] = 1.0f / (1.0f + __expf(-bf2f(gp[16 + h])));
    gwv[rg] = 1.0f / (1.0f + __expf(-bf2f(gp[32 + h])));
  }

  short* obase = o + (size_t)(b * NSEQ + nbase) * 2048 + h * HDIM;
#pragma unroll
  for (int df = 0; df < 8; ++df)
#pragma unroll
    for (int rg = 0; rg < 4; ++rg) {
      float val = gcv[rg] * acc_cmp[df][rg] +
                  gsv[rg] * acc_slc[df][rg] * inv_s[rg] +
                  gwv[rg] * acc_swa[df][rg] * inv_w[rg];
      obase[(size_t)(4 * hi + rg) * 2048 + 16 * df + lm] = f2bf(val);
    }
}

// ------------------------------------------------------------------
extern "C" void kernel_launch(void* const* d_in, const int* in_sizes, int n_in,
                              void* d_out, int out_size, void* d_ws, size_t ws_size,
                              hipStream_t stream) {
  const float* x  = (const float*)d_in[0];
  const float* Wq = (const float*)d_in[1];
  const float* Wk = (const float*)d_in[2];
  const float* Wv = (const float*)d_in[3];
  const float* Wg = (const float*)d_in[4];
  const float* Wo = (const float*)d_in[5];
  float* out = (float*)d_out;

  char* w = (char*)d_ws;
  short* x_bf = (short*)w;            // 8.4 MB (reused as o_bf)
  short* o_bf = x_bf;
  w += (size_t)2048 * 2048 * 2;
  short* w_t  = (short*)w;            // 26.2 MB (rows 6272..6399 unused pad)
  w += (size_t)6400 * 2048 * 2;
  short* qkv  = (short*)w;            // 26.2 MB (stride 6400; gate at 6144)
  w += (size_t)2048 * 6400 * 2;
  float* kc   = (float*)w; w += (size_t)65536 * 4;
  short* vct  = (short*)w; w += (size_t)65536 * 2;
  short* pcb  = (short*)w; w += (size_t)524288 * 2;
  int*   sel  = (int*)w;   w += (size_t)32768 * 4;
  short* vt   = (short*)w; w += (size_t)4194304 * 2;  // 8.4 MB
  float2* tbl = (float2*)w; w += (size_t)65536 * 8;   // 0.5 MB
  short* wo_t = (short*)w; w += (size_t)2048 * 2048 * 2;  // 8.4 MB

  const dim3 blk(256);
  prep<<<dim3(64, 64, 7), blk, 0, stream>>>(Wq, Wk, Wv, Wg, Wo, x, w_t, wo_t, x_bf, tbl);
  gemm256<<<200, dim3(512), 0, stream>>>(x_bf, w_t, qkv, 2048, 6400, 2048);
  rope_qk<<<2048, blk, 0, stream>>>(qkv, tbl);
  block_mean<<<256, blk, 0, stream>>>(qkv + KOFS, kc);
  v_transpose<<<dim3(16, 16, 2), blk, 0, stream>>>(qkv, vt, vct);
  cmp_sel<<<512, dim3(64), 0, stream>>>(qkv, kc, pcb, sel);
  attn_mfma<<<256, dim3(512), 0, stream>>>(qkv, vt, vct, pcb, sel, o_bf);
  gemm_bf16_bt<float><<<256, dim3(512), 0, stream>>>(o_bf, wo_t, out, 2048, 2048, 2048);
}

// Round 17
// 227.424 us; speedup vs baseline: 1.1658x; 1.0130x over previous
//
#include <hip/hip_runtime.h>
#include <hip/hip_bf16.h>

// NSA forward: B=2, N=1024, D=2048, H=16, HD=128, BS=64, SEL=8, WIN=64
#define HN   16
#define HDIM 128
#define NSEQ 1024
#define NBLK 16
#define BSZ  64
#define SCALE 0.08838834764831845f
#define QKV_STR 6400   // row stride of fused qkv+gate buffer (bf16), padded to 25*256
#define KOFS 2048
#define VOFS 4096
#define GOFS 6144

typedef __attribute__((ext_vector_type(8))) short bfrag;   // 8 bf16 (4 VGPRs)
typedef __attribute__((ext_vector_type(4))) float facc;    // MFMA accumulator

__device__ __forceinline__ float bf2f(short s) {
  union { unsigned u; float f; } cv;
  cv.u = ((unsigned)(unsigned short)s) << 16;
  return cv.f;
}
__device__ __forceinline__ short f2bf(float f) {
  unsigned u = __float_as_uint(f);
  u = (u + 0x7fff + ((u >> 16) & 1)) >> 16;  // RNE
  return (short)u;
}

#define ASYNC16(gp, lp)                                                    \
  __builtin_amdgcn_global_load_lds(                                        \
      (const __attribute__((address_space(1))) void*)(gp),                 \
      (__attribute__((address_space(3))) void*)(lp), 16, 0, 0)

#define MFMA16(a, b, c) __builtin_amdgcn_mfma_f32_16x16x32_bf16(a, b, c, 0, 0, 0)

// ------------------------------------------------------------------
// prep: z=0..2 -> Wq/Wk/Wv transpose-cast into w_t rows z*2048..
//       z=3   -> Wg transposed + zero-padded to rows 6144..6271
//       z=4   -> x cast to bf16
//       z=5   -> RoPE cos/sin table
//       z=6   -> Wo transpose-cast into wo_t
// ------------------------------------------------------------------
__global__ __launch_bounds__(256) void prep(const float* __restrict__ Wq,
                                            const float* __restrict__ Wk,
                                            const float* __restrict__ Wv,
                                            const float* __restrict__ Wg,
                                            const float* __restrict__ Wo,
                                            const float* __restrict__ x,
                                            short* __restrict__ w_t,
                                            short* __restrict__ wo_t,
                                            short* __restrict__ x_bf,
                                            float2* __restrict__ tbl) {
  __shared__ float tile[32][33];
  const int z = blockIdx.z;
  const int bx = blockIdx.x * 32, by = blockIdx.y * 32;
  const int tx = threadIdx.x & 31, ty = threadIdx.x >> 5;
  if (z == 5) {
    if (blockIdx.y >= 4) return;
    int i = (blockIdx.y * 64 + blockIdx.x) * 256 + threadIdx.x;  // < 65536
    int d = i & 63, n = i >> 6;
    float inv = expf(-(float)d * (9.210340371976184f / 64.0f));
    float sn, cs;
    sincosf((float)n * inv, &sn, &cs);
    tbl[i] = make_float2(cs, sn);
    return;
  }
  if (z == 4) {
#pragma unroll
    for (int i = 0; i < 4; ++i) {
      const int row = by + ty + 8 * i;
      x_bf[(size_t)row * 2048 + bx + tx] = f2bf(x[(size_t)row * 2048 + bx + tx]);
    }
    return;
  }
  if (z == 3) {
    if (blockIdx.x >= 4) return;  // only 128 dst rows
#pragma unroll
    for (int i = 0; i < 4; ++i) {
      const int c = bx + tx;
      tile[ty + 8 * i][tx] = (c < 48) ? Wg[(size_t)(by + ty + 8 * i) * 48 + c] : 0.f;
    }
    __syncthreads();
#pragma unroll
    for (int i = 0; i < 4; ++i)
      w_t[(size_t)(GOFS + bx + ty + 8 * i) * 2048 + by + tx] = f2bf(tile[tx][ty + 8 * i]);
    return;
  }
  if (z == 6) {
#pragma unroll
    for (int i = 0; i < 4; ++i)
      tile[ty + 8 * i][tx] = Wo[(size_t)(by + ty + 8 * i) * 2048 + bx + tx];
    __syncthreads();
#pragma unroll
    for (int i = 0; i < 4; ++i)
      wo_t[(size_t)(bx + ty + 8 * i) * 2048 + by + tx] = f2bf(tile[tx][ty + 8 * i]);
    return;
  }
  const float* src = (z == 0) ? Wq : (z == 1) ? Wk : Wv;
#pragma unroll
  for (int i = 0; i < 4; ++i)
    tile[ty + 8 * i][tx] = src[(size_t)(by + ty + 8 * i) * 2048 + bx + tx];
  __syncthreads();
#pragma unroll
  for (int i = 0; i < 4; ++i)
    w_t[(size_t)(z * 2048 + bx + ty + 8 * i) * 2048 + by + tx] = f2bf(tile[tx][ty + 8 * i]);
}

// ------------------------------------------------------------------
// 8-phase 256x256 bf16 GEMM (T2+T3+T4+T5): C[M][N] = A[M][K]*Bt[N][K]^T
// ------------------------------------------------------------------
__global__ __launch_bounds__(512, 1) void gemm256(const short* __restrict__ A,
                                                  const short* __restrict__ Bt,
                                                  short* __restrict__ C,
                                                  int M, int N, int K) {
  __shared__ short lds[2][2][16384];  // [buf][A/B][256*64]
  const int t = threadIdx.x;
  const int l = t & 63, w = t >> 6;
  const int wm = w >> 2, wn = w & 3;
  const int lm = l & 15, hi = l >> 4;
  const int lanexor = (lm & 7) << 3;            // shorts
  const int kk0 = (hi * 8) ^ lanexor;           // ks=0 column (shorts)
  const int L = blockIdx.x;
  const int item = (L & 7) * (gridDim.x >> 3) + (L >> 3);  // bijective (nwg%8==0)
  const int nrow = M >> 8;
  const int row0 = (item % nrow) * 256, col0 = (item / nrow) * 256;
  const int nt = K >> 6;
  const int ni = nt >> 1;

  const int srow = t >> 3;
  const int scol = 8 * ((t & 7) ^ (srow & 7));
  const short* Ab = A + (size_t)(row0 + srow) * K + scol;
  const short* Bb = Bt + (size_t)(col0 + srow) * K + scol;

#define STAGE(mat, srcbase, h, tau, buf)                                     \
  {                                                                          \
    const short* g_ = (srcbase) + (size_t)(h) * 128 * K + (size_t)(tau) * 64;\
    short* d_ = &lds[buf][mat][(h) * 8192 + t * 8];                          \
    ASYNC16(g_, d_);                                                         \
    ASYNC16(g_ + (size_t)64 * K, d_ + 4096);                                 \
  }

#define DS_A(qm, cb)                                                         \
  _Pragma("unroll") for (int ii = 0; ii < 4; ++ii) {                         \
    const int row_ = wm * 128 + (qm) * 64 + ii * 16 + lm;                    \
    af[ii * 2 + 0] = *(const bfrag*)&lds[cb][0][row_ * 64 + kk0];            \
    af[ii * 2 + 1] = *(const bfrag*)&lds[cb][0][row_ * 64 + (kk0 ^ 32)];     \
  }
#define DS_B(qn, arr, cb)                                                    \
  _Pragma("unroll") for (int jj = 0; jj < 2; ++jj) {                         \
    const int row_ = wn * 64 + (qn) * 32 + jj * 16 + lm;                     \
    arr[jj * 2 + 0] = *(const bfrag*)&lds[cb][1][row_ * 64 + kk0];           \
    arr[jj * 2 + 1] = *(const bfrag*)&lds[cb][1][row_ * 64 + (kk0 ^ 32)];    \
  }
#define QUAD(qm, qn, arr)                                                    \
  _Pragma("unroll") for (int ii = 0; ii < 4; ++ii)                           \
  _Pragma("unroll") for (int jj = 0; jj < 2; ++jj) {                         \
    acc[(qm)*4+ii][(qn)*2+jj] = MFMA16(af[ii*2+0], arr[jj*2+0], acc[(qm)*4+ii][(qn)*2+jj]); \
    acc[(qm)*4+ii][(qn)*2+jj] = MFMA16(af[ii*2+1], arr[jj*2+1], acc[(qm)*4+ii][(qn)*2+jj]); \
  }
#define BARLG                                                                \
  __builtin_amdgcn_s_barrier();                                              \
  asm volatile("s_waitcnt lgkmcnt(0)" ::: "memory");                         \
  __builtin_amdgcn_sched_barrier(0)
#define PRIO1 __builtin_amdgcn_s_setprio(1)
#define PRIO0 __builtin_amdgcn_s_setprio(0)
#define BAR __builtin_amdgcn_s_barrier()

  facc acc[8][4] = {};
  bfrag af[8], bf0[4], bf1[4];

  // prologue: full tile 0 -> buf0, B halves of tile 1 -> buf1
  STAGE(0, Ab, 0, 0, 0); STAGE(0, Ab, 1, 0, 0);
  STAGE(1, Bb, 0, 0, 0); STAGE(1, Bb, 1, 0, 0);
  STAGE(1, Bb, 0, 1, 1); STAGE(1, Bb, 1, 1, 1);
  asm volatile("s_waitcnt vmcnt(4)" ::: "memory");
  BAR;

  for (int i = 0; i < ni; ++i) {
    const int t1 = 2 * i + 1;
    const int g2 = (2 * i + 2 < nt) ? 2 * i + 2 : 2 * i;
    const int g3 = (2 * i + 3 < nt) ? 2 * i + 3 : t1;

    // ======== K-tile tau0 = 2i (buf0) ========
    DS_A(0, 0); DS_B(0, bf0, 0);
    STAGE(0, Ab, 0, t1, 1);
    BARLG; PRIO1; QUAD(0, 0, bf0); PRIO0; BAR;

    DS_B(1, bf1, 0);
    STAGE(0, Ab, 1, t1, 1);
    BARLG; PRIO1; QUAD(0, 1, bf1); PRIO0; BAR;

    DS_A(1, 0);
    STAGE(1, Bb, 0, g2, 0);
    BARLG; PRIO1; QUAD(1, 1, bf1); PRIO0; BAR;

    STAGE(1, Bb, 1, g2, 0);
    PRIO1; QUAD(1, 0, bf0); PRIO0;
    asm volatile("s_waitcnt vmcnt(4)" ::: "memory");
    BAR;

    // ======== K-tile tau1 = 2i+1 (buf1) ========
    DS_A(0, 1); DS_B(0, bf0, 1);
    STAGE(0, Ab, 0, g2, 0);
    BARLG; PRIO1; QUAD(0, 0, bf0); PRIO0; BAR;

    DS_B(1, bf1, 1);
    STAGE(0, Ab, 1, g2, 0);
    BARLG; PRIO1; QUAD(0, 1, bf1); PRIO0; BAR;

    DS_A(1, 1);
    STAGE(1, Bb, 0, g3, 1);
    BARLG; PRIO1; QUAD(1, 1, bf1); PRIO0; BAR;

    STAGE(1, Bb, 1, g3, 1);
    PRIO1; QUAD(1, 0, bf0); PRIO0;
    asm volatile("s_waitcnt vmcnt(4)" ::: "memory");
    BAR;
  }

#pragma unroll
  for (int i = 0; i < 8; ++i)
#pragma unroll
    for (int j = 0; j < 4; ++j)
#pragma unroll
      for (int rr = 0; rr < 4; ++rr)
        C[(size_t)(row0 + wm * 128 + i * 16 + hi * 4 + rr) * N +
          col0 + wn * 64 + j * 16 + lm] = f2bf(acc[i][j][rr]);
#undef STAGE
#undef DS_A
#undef DS_B
#undef QUAD
#undef BARLG
#undef PRIO1
#undef PRIO0
#undef BAR
}

// ------------------------------------------------------------------
// bf16 MFMA GEMM, 8-wave m97 variant (out proj): C = A * Bt^T.
// ------------------------------------------------------------------
__device__ __forceinline__ void store_c(float* p, float v) { *p = v; }
__device__ __forceinline__ void store_c(short* p, float v) { *p = f2bf(v); }

template <typename OT>
__global__ __launch_bounds__(512, 1) void gemm_bf16_bt(const short* __restrict__ A,
                                                       const short* __restrict__ Bt,
                                                       OT* __restrict__ C,
                                                       int M, int N, int K) {
  __shared__ short As[128 * 32];
  __shared__ short Bs[128 * 32];
  const int t = threadIdx.x;          // 0..511
  const int l = t & 63, w = t >> 6;   // 8 waves
  const int wr = w >> 2, wc = w & 3;  // 2 x 4
  const int lm = l & 15, lk = (l >> 4) * 8;
  const int nwg = gridDim.x;
  const int L = blockIdx.x;
  const int wg = (L & 7) * (nwg >> 3) + (L >> 3);
  const int nrow = M >> 7;
  const int row0 = (wg % nrow) * 128, col0 = (wg / nrow) * 128;
  facc acc[4][2] = {};

  const int sr = t >> 2;              // 0..127
  const int sk = (t & 3) * 8;
  const short* Ag = A + (size_t)(row0 + sr) * K + sk;
  const short* Bg = Bt + (size_t)(col0 + sr) * K + sk;
  short* la = As + t * 8;
  short* lb = Bs + t * 8;

  for (int k0 = 0; k0 < K; k0 += 32) {
    ASYNC16(Ag + k0, la);
    ASYNC16(Bg + k0, lb);
    __syncthreads();
    bfrag af[4], bf[2];
#pragma unroll
    for (int i = 0; i < 4; ++i)
      af[i] = *(const bfrag*)&As[(wr * 64 + i * 16 + lm) * 32 + lk];
#pragma unroll
    for (int j = 0; j < 2; ++j)
      bf[j] = *(const bfrag*)&Bs[(wc * 32 + j * 16 + lm) * 32 + lk];
#pragma unroll
    for (int i = 0; i < 4; ++i)
#pragma unroll
      for (int j = 0; j < 2; ++j)
        acc[i][j] = MFMA16(af[i], bf[j], acc[i][j]);
    __syncthreads();
  }

  const int orow = row0 + wr * 64 + (l >> 4) * 4;
  const int ocol = col0 + wc * 32 + lm;
#pragma unroll
  for (int i = 0; i < 4; ++i)
#pragma unroll
    for (int j = 0; j < 2; ++j)
#pragma unroll
      for (int rr = 0; rr < 4; ++rr)
        store_c(&C[(size_t)(orow + i * 16 + rr) * N + ocol + j * 16], acc[i][j][rr]);
}

// ------------------------------------------------------------------
// postqkv: fused rope(q,k) + K block-mean + V transpose + V block-mean.
// One block per (n-block, h, b). K slice read once (roped in regs,
// staged to LDS for the column mean); V read once.
// ------------------------------------------------------------------
__global__ __launch_bounds__(256) void postqkv(short* __restrict__ qkv,
                                               const float2* __restrict__ tbl,
                                               float* __restrict__ kc,
                                               short* __restrict__ vt,
                                               short* __restrict__ vct) {
  const int nb = blockIdx.x, h = blockIdx.y, b = blockIdx.z;
  const int t = threadIdx.x;
  const int n0 = nb * 64;
  __shared__ short tile[64][136];

  const int row = t >> 2;        // 0..63
  const int c16 = (t & 3) * 16;  // lower-half dim base: 0,16,32,48
  const float2* tp = tbl + (size_t)(n0 + row) * 64 + c16;

#pragma unroll
  for (int qk = 0; qk < 2; ++qk) {
    short* base = qkv + (size_t)(b * NSEQ + n0 + row) * QKV_STR + qk * KOFS + h * HDIM + c16;
    bfrag lo0 = *(const bfrag*)base;
    bfrag lo1 = *(const bfrag*)(base + 8);
    bfrag hi0 = *(const bfrag*)(base + 64);
    bfrag hi1 = *(const bfrag*)(base + 72);
    bfrag olo0, olo1, ohi0, ohi1;
#pragma unroll
    for (int j = 0; j < 8; ++j) {
      float2 cs0 = tp[j], cs1 = tp[j + 8];
      float a0 = bf2f(lo0[j]), b0 = bf2f(hi0[j]);
      float a1 = bf2f(lo1[j]), b1 = bf2f(hi1[j]);
      olo0[j] = f2bf(a0 * cs0.x - b0 * cs0.y);
      ohi0[j] = f2bf(a0 * cs0.y + b0 * cs0.x);
      olo1[j] = f2bf(a1 * cs1.x - b1 * cs1.y);
      ohi1[j] = f2bf(a1 * cs1.y + b1 * cs1.x);
    }
    *(bfrag*)base = olo0;
    *(bfrag*)(base + 8) = olo1;
    *(bfrag*)(base + 64) = ohi0;
    *(bfrag*)(base + 72) = ohi1;
    if (qk == 1) {  // stash roped K tile for the block mean
      *(bfrag*)&tile[row][c16] = olo0;
      *(bfrag*)&tile[row][c16 + 8] = olo1;
      *(bfrag*)&tile[row][c16 + 64] = ohi0;
      *(bfrag*)&tile[row][c16 + 72] = ohi1;
    }
  }
  __syncthreads();

  // K block mean (roped): kc[b][nb][h][d]
  if (t < 128) {
    float s = 0.f;
#pragma unroll 8
    for (int r = 0; r < 64; ++r) s += bf2f(tile[r][t]);
    kc[(((size_t)(b * NBLK + nb) * HN) + h) * 128 + t] = s * (1.0f / 64.0f);
  }
  __syncthreads();

  // V tile into LDS
#pragma unroll
  for (int it = 0; it < 4; ++it) {
    int idx = t + 256 * it;
    int r2 = idx >> 4, ch = idx & 15;
    *(bfrag*)&tile[r2][ch * 8] =
        *(const bfrag*)&qkv[(size_t)(b * NSEQ + n0 + r2) * QKV_STR + VOFS + h * HDIM + ch * 8];
  }
  __syncthreads();

  // transpose out + V block mean
#pragma unroll
  for (int it = 0; it < 4; ++it) {
    int idx = t + 256 * it;
    int d = idx >> 3, ch = idx & 7;
    bfrag tv;
    float s = 0.f;
#pragma unroll
    for (int j = 0; j < 8; ++j) {
      tv[j] = tile[ch * 8 + j][d];
      s += bf2f(tv[j]);
    }
    *(bfrag*)&vt[(((size_t)(b * HN + h) * 128) + d) * 1024 + n0 + ch * 8] = tv;
    s += __shfl_down(s, 4);
    s += __shfl_down(s, 2);
    s += __shfl_down(s, 1);
    if ((t & 7) == 0)
      vct[(((size_t)(b * HN + h) * 128) + d) * 16 + nb] = f2bf(s * (1.0f / 64.0f));
  }
}

// ------------------------------------------------------------------
// Compressed probs (bf16 pc [b][h][n][16]) + top-8 selection bitmask.
// ------------------------------------------------------------------
__global__ __launch_bounds__(64) void cmp_sel(const short* __restrict__ qkv,
                                              const float* __restrict__ kc,
                                              short* __restrict__ pc,
                                              int* __restrict__ sel) {
  int i = blockIdx.x * 64 + threadIdx.x;  // B*H*N = 32768
  int n = i & 1023;
  int h = (i >> 10) & 15;
  int b = i >> 14;
  const short* qp = qkv + (size_t)(b * NSEQ + n) * QKV_STR + h * HDIM;
  const int nv = (n + 1) >> 6;
  float s[NBLK];
#pragma unroll
  for (int m = 0; m < NBLK; ++m) s[m] = 0.f;
  for (int d0 = 0; d0 < HDIM; d0 += 8) {
    bfrag qv = *(const bfrag*)&qp[d0];
    float qf[8];
#pragma unroll
    for (int dd = 0; dd < 8; ++dd) qf[dd] = bf2f(qv[dd]);
    for (int m = 0; m < nv; ++m) {
      const float4* kp = (const float4*)(kc + ((size_t)((b * NBLK + m) * HN + h) << 7) + d0);
      const float4 k0 = kp[0], k1 = kp[1];
      s[m] += qf[0] * k0.x + qf[1] * k0.y + qf[2] * k0.z + qf[3] * k0.w +
              qf[4] * k1.x + qf[5] * k1.y + qf[6] * k1.z + qf[7] * k1.w;
    }
  }
  float mx = -1e30f;
  for (int m = 0; m < nv; ++m) { s[m] *= SCALE; mx = fmaxf(mx, s[m]); }
  float den = 0.f;
  for (int m = 0; m < nv; ++m) { s[m] = __expf(s[m] - mx); den += s[m]; }
  const float rden = (nv > 0) ? 1.0f / den : 0.f;
  float p[NBLK];
#pragma unroll
  for (int m = 0; m < NBLK; ++m) p[m] = (m < nv) ? s[m] * rden : 0.f;
  bfrag o0, o1;
#pragma unroll
  for (int m = 0; m < 8; ++m) { o0[m] = f2bf(p[m]); o1[m] = f2bf(p[m + 8]); }
  bfrag* pout = (bfrag*)(pc + (size_t)i * 16);
  pout[0] = o0; pout[1] = o1;
  p[n >> 6] += 2.0f;
  int mask = 0;
#pragma unroll
  for (int ss = 0; ss < 8; ++ss) {
    int best = 0;
    float bv = -1e30f;
#pragma unroll
    for (int m = 0; m < NBLK; ++m)
      if (p[m] > bv) { bv = p[m]; best = m; }
    mask |= 1 << best;
    p[best] = -1e30f;
  }
  sel[i] = mask;
}

// ------------------------------------------------------------------
// MFMA attention, LDS-staged (proven R14): one block = 8 waves per
// (b,h), wave wid owns row-tile rt = wid*8 + rblk. Per ct: stage K/V
// tile (ct+1) into XOR-swizzled double-buffered LDS, vmcnt(0)+barrier;
// waves compute their row-tile when active.
// ------------------------------------------------------------------
__global__ __launch_bounds__(512, 1) void attn_mfma(
    const short* __restrict__ qkv, const short* __restrict__ vt,
    const short* __restrict__ vct, const short* __restrict__ pc,
    const int* __restrict__ sel, short* __restrict__ o) {
  const int fid = blockIdx.x;            // 0..255
  const int xcd = fid & 7;
  const int idx = fid >> 3;              // 0..31
  const int pair = (xcd << 2) | (idx & 3);
  const int rblk = idx >> 2;             // 0..7
  const int h = pair & 15, b = pair >> 4;

  const int tid = threadIdx.x;
  const int wid = tid >> 6;              // 0..7
  const int l = tid & 63;
  const int lm = l & 15, hi = l >> 4;
  const int rt = wid * 8 + rblk;         // striped row-tile ownership
  const int nbase = rt * 16;
  const int CTMAX = ((56 + rblk) * 16) >> 6;  // thi of the largest rt in block

  __shared__ short kbuf[2][8192];        // [buf][64 n][128 d] swizzled
  __shared__ short vbuf[2][8192];        // [buf][128 d][64 n] swizzled
  __shared__ short pbuf[8][2][1024];     // per-wave P (slc/swa)
  short* p_slc = &pbuf[wid][0][0];
  short* p_swa = &pbuf[wid][1][0];

  // Q A-fragments
  const short* qrow = qkv + (size_t)(b * NSEQ + nbase + lm) * QKV_STR + h * HDIM;
  bfrag qf[4];
#pragma unroll
  for (int ks = 0; ks < 4; ++ks) qf[ks] = *(const bfrag*)&qrow[32 * ks + 8 * hi];

  // selection bits
  int selrow = sel[(size_t)(b * HN + h) * NSEQ + nbase + lm];
  int uni = selrow;
#pragma unroll
  for (int m = 1; m < 16; m <<= 1) uni |= __shfl_xor(uni, m);
  int sel4[4];
#pragma unroll
  for (int rg = 0; rg < 4; ++rg) sel4[rg] = __shfl(selrow, 4 * hi + rg);

  const int thi = nbase >> 6;
  const int tlo = (nbase >= 64) ? ((nbase - 64) >> 6) : 0;
  const int wmask = (int)((2u << thi) - (1u << tlo));
  const unsigned am = (unsigned)(uni | wmask) & (unsigned)((2u << thi) - 1);

  facc acc_slc[8] = {}, acc_swa[8] = {};
  float ps_s[4] = {0.f, 0.f, 0.f, 0.f}, ps_w[4] = {0.f, 0.f, 0.f, 0.f};

#define STAGEKV(ct_, buf_)                                                   \
  {                                                                          \
    _Pragma("unroll") for (int rr = 0; rr < 2; ++rr) {                       \
      const int i2 = tid + 512 * rr;                                         \
      const int rw = i2 >> 4, cc = i2 & 15;                                  \
      const short* g_ = qkv + (size_t)(b * NSEQ + (ct_) * 64 + rw) * QKV_STR \
                        + KOFS + h * HDIM + 8 * (cc ^ (rw & 7));             \
      ASYNC16(g_, &kbuf[buf_][i2 * 8]);                                      \
    }                                                                        \
    _Pragma("unroll") for (int rr = 0; rr < 2; ++rr) {                       \
      const int i2 = tid + 512 * rr;                                         \
      const int dd = i2 >> 3, cc = i2 & 7;                                   \
      const short* g_ = vt + ((size_t)(b * HN + h) * 128 + dd) * 1024        \
                        + (ct_) * 64 + 8 * (cc ^ (dd & 7));                  \
      ASYNC16(g_, &vbuf[buf_][i2 * 8]);                                      \
    }                                                                        \
  }

#define EXPF(f_)                                                            \
  _Pragma("unroll") for (int rg = 0; rg < 4; ++rg) {                        \
    const int col_ = ct * 64 + 16 * (f_) + lm;                              \
    const int row_ = nbase + 4 * hi + rg;                                   \
    float e_ = __expf(sacc[f_][rg] * SCALE);                                \
    e_ = (col_ <= row_) ? e_ : 0.f;                                         \
    float es_ = ((sel4[rg] >> ct) & 1) ? e_ : 0.f;                          \
    float ew_ = (row_ - col_ <= 64) ? e_ : 0.f;                             \
    ps_s[rg] += es_;                                                        \
    ps_w[rg] += ew_;                                                        \
    const int srow_ = 4 * hi + rg;                                          \
    const int sidx_ = (64 * srow_ + 16 * (f_) + lm) ^ ((srow_ & 7) << 3);   \
    if (do_s) p_slc[sidx_] = f2bf(es_);                                     \
    if (do_w) p_swa[sidx_] = f2bf(ew_);                                     \
  }

  // prologue: stage tile 0 into buf 0
  STAGEKV(0, 0);
  asm volatile("s_waitcnt vmcnt(0)" ::: "memory");
  __syncthreads();

  for (int ct = 0; ct <= CTMAX; ++ct) {
    const int cur = ct & 1;
    if (ct < CTMAX) STAGEKV(ct + 1, cur ^ 1);

    if ((am >> ct) & 1) {
      const bool do_s = (uni >> ct) & 1;
      const bool do_w = (wmask >> ct) & 1;

      // QK^T from LDS K tile
      facc sacc[4] = {};
#pragma unroll
      for (int f = 0; f < 4; ++f) {
        const int row_ = 16 * f + lm;
        const int rx = row_ & 7;
        bfrag k0 = *(const bfrag*)&kbuf[cur][row_ * 128 + 8 * ((0 + hi) ^ rx)];
        bfrag k1 = *(const bfrag*)&kbuf[cur][row_ * 128 + 8 * ((4 + hi) ^ rx)];
        bfrag k2 = *(const bfrag*)&kbuf[cur][row_ * 128 + 8 * ((8 + hi) ^ rx)];
        bfrag k3 = *(const bfrag*)&kbuf[cur][row_ * 128 + 8 * ((12 + hi) ^ rx)];
        sacc[f] = MFMA16(qf[0], k0, sacc[f]);
        sacc[f] = MFMA16(qf[1], k1, sacc[f]);
        sacc[f] = MFMA16(qf[2], k2, sacc[f]);
        sacc[f] = MFMA16(qf[3], k3, sacc[f]);
      }

      EXPF(0); EXPF(1); EXPF(2); EXPF(3);

      // PV from LDS V tile
#pragma unroll
      for (int ks = 0; ks < 2; ++ks) {
        const int ridx = (64 * lm + 8 * hi + 32 * ks) ^ ((lm & 7) << 3);
        bfrag pas = {}, paw = {};
        if (do_s) pas = *(const bfrag*)&p_slc[ridx];
        if (do_w) paw = *(const bfrag*)&p_swa[ridx];
#pragma unroll
        for (int df = 0; df < 8; ++df) {
          const int d_ = 16 * df + lm;
          bfrag vb = *(const bfrag*)&vbuf[cur][d_ * 64 + 8 * ((4 * ks + hi) ^ (d_ & 7))];
          if (do_s) acc_slc[df] = MFMA16(pas, vb, acc_slc[df]);
          if (do_w) acc_swa[df] = MFMA16(paw, vb, acc_swa[df]);
        }
      }
    }

    asm volatile("s_waitcnt vmcnt(0)" ::: "memory");
    __syncthreads();
  }
#undef STAGEKV
#undef EXPF

  // ---- compressed branch: O_cmp = Pc[16x16] * Vc[16x128], K padded to 32
  facc acc_cmp[8] = {};
  {
    bfrag pa = {};
    if (hi < 2)
      pa = *(const bfrag*)&pc[((size_t)(b * HN + h) * NSEQ + nbase + lm) * 16 + 8 * hi];
#pragma unroll
    for (int df = 0; df < 8; ++df) {
      bfrag vb = {};
      if (hi < 2)
        vb = *(const bfrag*)&vct[(((size_t)(b * HN + h) * 128) + 16 * df + lm) * 16 + 8 * hi];
      acc_cmp[df] = MFMA16(pa, vb, acc_cmp[df]);
    }
  }

  // ---- denominators: reduce across the 16 col-lanes
#pragma unroll
  for (int m = 1; m < 16; m <<= 1) {
#pragma unroll
    for (int rg = 0; rg < 4; ++rg) {
      ps_s[rg] += __shfl_xor(ps_s[rg], m);
      ps_w[rg] += __shfl_xor(ps_w[rg], m);
    }
  }

  float inv_s[4], inv_w[4], gcv[4], gsv[4], gwv[4];
#pragma unroll
  for (int rg = 0; rg < 4; ++rg) {
    inv_s[rg] = 1.0f / ps_s[rg];
    inv_w[rg] = 1.0f / ps_w[rg];
    const short* gp = qkv + (size_t)(b * NSEQ + nbase + 4 * hi + rg) * QKV_STR + GOFS;
    gcv[rg] = 1.0f / (1.0f + __expf(-bf2f(gp[h])));
    gsv[rg] = 1.0f / (1.0f + __expf(-bf2f(gp[16 + h])));
    gwv[rg] = 1.0f / (1.0f + __expf(-bf2f(gp[32 + h])));
  }

  short* obase = o + (size_t)(b * NSEQ + nbase) * 2048 + h * HDIM;
#pragma unroll
  for (int df = 0; df < 8; ++df)
#pragma unroll
    for (int rg = 0; rg < 4; ++rg) {
      float val = gcv[rg] * acc_cmp[df][rg] +
                  gsv[rg] * acc_slc[df][rg] * inv_s[rg] +
                  gwv[rg] * acc_swa[df][rg] * inv_w[rg];
      obase[(size_t)(4 * hi + rg) * 2048 + 16 * df + lm] = f2bf(val);
    }
}

// ------------------------------------------------------------------
extern "C" void kernel_launch(void* const* d_in, const int* in_sizes, int n_in,
                              void* d_out, int out_size, void* d_ws, size_t ws_size,
                              hipStream_t stream) {
  const float* x  = (const float*)d_in[0];
  const float* Wq = (const float*)d_in[1];
  const float* Wk = (const float*)d_in[2];
  const float* Wv = (const float*)d_in[3];
  const float* Wg = (const float*)d_in[4];
  const float* Wo = (const float*)d_in[5];
  float* out = (float*)d_out;

  char* w = (char*)d_ws;
  short* x_bf = (short*)w;            // 8.4 MB (reused as o_bf)
  short* o_bf = x_bf;
  w += (size_t)2048 * 2048 * 2;
  short* w_t  = (short*)w;            // 26.2 MB (rows 6272..6399 unused pad)
  w += (size_t)6400 * 2048 * 2;
  short* qkv  = (short*)w;            // 26.2 MB (stride 6400; gate at 6144)
  w += (size_t)2048 * 6400 * 2;
  float* kc   = (float*)w; w += (size_t)65536 * 4;
  short* vct  = (short*)w; w += (size_t)65536 * 2;
  short* pcb  = (short*)w; w += (size_t)524288 * 2;
  int*   sel  = (int*)w;   w += (size_t)32768 * 4;
  short* vt   = (short*)w; w += (size_t)4194304 * 2;  // 8.4 MB
  float2* tbl = (float2*)w; w += (size_t)65536 * 8;   // 0.5 MB
  short* wo_t = (short*)w; w += (size_t)2048 * 2048 * 2;  // 8.4 MB

  const dim3 blk(256);
  prep<<<dim3(64, 64, 7), blk, 0, stream>>>(Wq, Wk, Wv, Wg, Wo, x, w_t, wo_t, x_bf, tbl);
  gemm256<<<200, dim3(512), 0, stream>>>(x_bf, w_t, qkv, 2048, 6400, 2048);
  postqkv<<<dim3(16, 16, 2), blk, 0, stream>>>(qkv, tbl, kc, vt, vct);
  cmp_sel<<<512, dim3(64), 0, stream>>>(qkv, kc, pcb, sel);
  attn_mfma<<<256, dim3(512), 0, stream>>>(qkv, vt, vct, pcb, sel, o_bf);
  gemm_bf16_bt<float><<<256, dim3(512), 0, stream>>>(o_bf, wo_t, out, 2048, 2048, 2048);
}

// Round 18
// 226.379 us; speedup vs baseline: 1.1712x; 1.0046x over previous
//
#include <hip/hip_runtime.h>
#include <hip/hip_bf16.h>

// NSA forward: B=2, N=1024, D=2048, H=16, HD=128, BS=64, SEL=8, WIN=64
#define HN   16
#define HDIM 128
#define NSEQ 1024
#define NBLK 16
#define BSZ  64
#define SCALE 0.08838834764831845f
#define QKV_STR 6400   // row stride of fused qkv+gate buffer (bf16), padded to 25*256
#define KOFS 2048
#define VOFS 4096
#define GOFS 6144

typedef __attribute__((ext_vector_type(8))) short bfrag;   // 8 bf16 (4 VGPRs)
typedef __attribute__((ext_vector_type(4))) float facc;    // MFMA accumulator

__device__ __forceinline__ float bf2f(short s) {
  union { unsigned u; float f; } cv;
  cv.u = ((unsigned)(unsigned short)s) << 16;
  return cv.f;
}
__device__ __forceinline__ short f2bf(float f) {
  unsigned u = __float_as_uint(f);
  u = (u + 0x7fff + ((u >> 16) & 1)) >> 16;  // RNE
  return (short)u;
}

#define ASYNC16(gp, lp)                                                    \
  __builtin_amdgcn_global_load_lds(                                        \
      (const __attribute__((address_space(1))) void*)(gp),                 \
      (__attribute__((address_space(3))) void*)(lp), 16, 0, 0)

#define MFMA16(a, b, c) __builtin_amdgcn_mfma_f32_16x16x32_bf16(a, b, c, 0, 0, 0)

// ------------------------------------------------------------------
// prep: z=0..2 -> Wq/Wk/Wv transpose-cast into w_t rows z*2048..
//       z=3   -> Wg transposed + zero-padded to rows 6144..6271
//       z=4   -> x cast to bf16
//       z=5   -> RoPE cos/sin table
//       z=6   -> Wo transpose-cast into wo_t
// ------------------------------------------------------------------
__global__ __launch_bounds__(256) void prep(const float* __restrict__ Wq,
                                            const float* __restrict__ Wk,
                                            const float* __restrict__ Wv,
                                            const float* __restrict__ Wg,
                                            const float* __restrict__ Wo,
                                            const float* __restrict__ x,
                                            short* __restrict__ w_t,
                                            short* __restrict__ wo_t,
                                            short* __restrict__ x_bf,
                                            float2* __restrict__ tbl) {
  __shared__ float tile[32][33];
  const int z = blockIdx.z;
  const int bx = blockIdx.x * 32, by = blockIdx.y * 32;
  const int tx = threadIdx.x & 31, ty = threadIdx.x >> 5;
  if (z == 5) {
    if (blockIdx.y >= 4) return;
    int i = (blockIdx.y * 64 + blockIdx.x) * 256 + threadIdx.x;  // < 65536
    int d = i & 63, n = i >> 6;
    float inv = expf(-(float)d * (9.210340371976184f / 64.0f));
    float sn, cs;
    sincosf((float)n * inv, &sn, &cs);
    tbl[i] = make_float2(cs, sn);
    return;
  }
  if (z == 4) {
#pragma unroll
    for (int i = 0; i < 4; ++i) {
      const int row = by + ty + 8 * i;
      x_bf[(size_t)row * 2048 + bx + tx] = f2bf(x[(size_t)row * 2048 + bx + tx]);
    }
    return;
  }
  if (z == 3) {
    if (blockIdx.x >= 4) return;  // only 128 dst rows
#pragma unroll
    for (int i = 0; i < 4; ++i) {
      const int c = bx + tx;
      tile[ty + 8 * i][tx] = (c < 48) ? Wg[(size_t)(by + ty + 8 * i) * 48 + c] : 0.f;
    }
    __syncthreads();
#pragma unroll
    for (int i = 0; i < 4; ++i)
      w_t[(size_t)(GOFS + bx + ty + 8 * i) * 2048 + by + tx] = f2bf(tile[tx][ty + 8 * i]);
    return;
  }
  if (z == 6) {
#pragma unroll
    for (int i = 0; i < 4; ++i)
      tile[ty + 8 * i][tx] = Wo[(size_t)(by + ty + 8 * i) * 2048 + bx + tx];
    __syncthreads();
#pragma unroll
    for (int i = 0; i < 4; ++i)
      wo_t[(size_t)(bx + ty + 8 * i) * 2048 + by + tx] = f2bf(tile[tx][ty + 8 * i]);
    return;
  }
  const float* src = (z == 0) ? Wq : (z == 1) ? Wk : Wv;
#pragma unroll
  for (int i = 0; i < 4; ++i)
    tile[ty + 8 * i][tx] = src[(size_t)(by + ty + 8 * i) * 2048 + bx + tx];
  __syncthreads();
#pragma unroll
  for (int i = 0; i < 4; ++i)
    w_t[(size_t)(z * 2048 + bx + ty + 8 * i) * 2048 + by + tx] = f2bf(tile[tx][ty + 8 * i]);
}

// ------------------------------------------------------------------
// 8-phase 256x256 bf16 GEMM (T2+T3+T4+T5): C[M][N] = A[M][K]*Bt[N][K]^T
// ------------------------------------------------------------------
__global__ __launch_bounds__(512, 1) void gemm256(const short* __restrict__ A,
                                                  const short* __restrict__ Bt,
                                                  short* __restrict__ C,
                                                  int M, int N, int K) {
  __shared__ short lds[2][2][16384];  // [buf][A/B][256*64]
  const int t = threadIdx.x;
  const int l = t & 63, w = t >> 6;
  const int wm = w >> 2, wn = w & 3;
  const int lm = l & 15, hi = l >> 4;
  const int lanexor = (lm & 7) << 3;            // shorts
  const int kk0 = (hi * 8) ^ lanexor;           // ks=0 column (shorts)
  const int L = blockIdx.x;
  const int item = (L & 7) * (gridDim.x >> 3) + (L >> 3);  // bijective (nwg%8==0)
  const int nrow = M >> 8;
  const int row0 = (item % nrow) * 256, col0 = (item / nrow) * 256;
  const int nt = K >> 6;
  const int ni = nt >> 1;

  const int srow = t >> 3;
  const int scol = 8 * ((t & 7) ^ (srow & 7));
  const short* Ab = A + (size_t)(row0 + srow) * K + scol;
  const short* Bb = Bt + (size_t)(col0 + srow) * K + scol;

#define STAGE(mat, srcbase, h, tau, buf)                                     \
  {                                                                          \
    const short* g_ = (srcbase) + (size_t)(h) * 128 * K + (size_t)(tau) * 64;\
    short* d_ = &lds[buf][mat][(h) * 8192 + t * 8];                          \
    ASYNC16(g_, d_);                                                         \
    ASYNC16(g_ + (size_t)64 * K, d_ + 4096);                                 \
  }

#define DS_A(qm, cb)                                                         \
  _Pragma("unroll") for (int ii = 0; ii < 4; ++ii) {                         \
    const int row_ = wm * 128 + (qm) * 64 + ii * 16 + lm;                    \
    af[ii * 2 + 0] = *(const bfrag*)&lds[cb][0][row_ * 64 + kk0];            \
    af[ii * 2 + 1] = *(const bfrag*)&lds[cb][0][row_ * 64 + (kk0 ^ 32)];     \
  }
#define DS_B(qn, arr, cb)                                                    \
  _Pragma("unroll") for (int jj = 0; jj < 2; ++jj) {                         \
    const int row_ = wn * 64 + (qn) * 32 + jj * 16 + lm;                     \
    arr[jj * 2 + 0] = *(const bfrag*)&lds[cb][1][row_ * 64 + kk0];           \
    arr[jj * 2 + 1] = *(const bfrag*)&lds[cb][1][row_ * 64 + (kk0 ^ 32)];    \
  }
#define QUAD(qm, qn, arr)                                                    \
  _Pragma("unroll") for (int ii = 0; ii < 4; ++ii)                           \
  _Pragma("unroll") for (int jj = 0; jj < 2; ++jj) {                         \
    acc[(qm)*4+ii][(qn)*2+jj] = MFMA16(af[ii*2+0], arr[jj*2+0], acc[(qm)*4+ii][(qn)*2+jj]); \
    acc[(qm)*4+ii][(qn)*2+jj] = MFMA16(af[ii*2+1], arr[jj*2+1], acc[(qm)*4+ii][(qn)*2+jj]); \
  }
#define BARLG                                                                \
  __builtin_amdgcn_s_barrier();                                              \
  asm volatile("s_waitcnt lgkmcnt(0)" ::: "memory");                         \
  __builtin_amdgcn_sched_barrier(0)
#define PRIO1 __builtin_amdgcn_s_setprio(1)
#define PRIO0 __builtin_amdgcn_s_setprio(0)
#define BAR __builtin_amdgcn_s_barrier()

  facc acc[8][4] = {};
  bfrag af[8], bf0[4], bf1[4];

  // prologue: full tile 0 -> buf0, B halves of tile 1 -> buf1
  STAGE(0, Ab, 0, 0, 0); STAGE(0, Ab, 1, 0, 0);
  STAGE(1, Bb, 0, 0, 0); STAGE(1, Bb, 1, 0, 0);
  STAGE(1, Bb, 0, 1, 1); STAGE(1, Bb, 1, 1, 1);
  asm volatile("s_waitcnt vmcnt(4)" ::: "memory");
  BAR;

  for (int i = 0; i < ni; ++i) {
    const int t1 = 2 * i + 1;
    const int g2 = (2 * i + 2 < nt) ? 2 * i + 2 : 2 * i;
    const int g3 = (2 * i + 3 < nt) ? 2 * i + 3 : t1;

    // ======== K-tile tau0 = 2i (buf0) ========
    DS_A(0, 0); DS_B(0, bf0, 0);
    STAGE(0, Ab, 0, t1, 1);
    BARLG; PRIO1; QUAD(0, 0, bf0); PRIO0; BAR;

    DS_B(1, bf1, 0);
    STAGE(0, Ab, 1, t1, 1);
    BARLG; PRIO1; QUAD(0, 1, bf1); PRIO0; BAR;

    DS_A(1, 0);
    STAGE(1, Bb, 0, g2, 0);
    BARLG; PRIO1; QUAD(1, 1, bf1); PRIO0; BAR;

    STAGE(1, Bb, 1, g2, 0);
    PRIO1; QUAD(1, 0, bf0); PRIO0;
    asm volatile("s_waitcnt vmcnt(4)" ::: "memory");
    BAR;

    // ======== K-tile tau1 = 2i+1 (buf1) ========
    DS_A(0, 1); DS_B(0, bf0, 1);
    STAGE(0, Ab, 0, g2, 0);
    BARLG; PRIO1; QUAD(0, 0, bf0); PRIO0; BAR;

    DS_B(1, bf1, 1);
    STAGE(0, Ab, 1, g2, 0);
    BARLG; PRIO1; QUAD(0, 1, bf1); PRIO0; BAR;

    DS_A(1, 1);
    STAGE(1, Bb, 0, g3, 1);
    BARLG; PRIO1; QUAD(1, 1, bf1); PRIO0; BAR;

    STAGE(1, Bb, 1, g3, 1);
    PRIO1; QUAD(1, 0, bf0); PRIO0;
    asm volatile("s_waitcnt vmcnt(4)" ::: "memory");
    BAR;
  }

#pragma unroll
  for (int i = 0; i < 8; ++i)
#pragma unroll
    for (int j = 0; j < 4; ++j)
#pragma unroll
      for (int rr = 0; rr < 4; ++rr)
        C[(size_t)(row0 + wm * 128 + i * 16 + hi * 4 + rr) * N +
          col0 + wn * 64 + j * 16 + lm] = f2bf(acc[i][j][rr]);
#undef STAGE
#undef DS_A
#undef DS_B
#undef QUAD
#undef BARLG
#undef PRIO1
#undef PRIO0
#undef BAR
}

// ------------------------------------------------------------------
// bf16 MFMA GEMM, 8-wave m97 variant (out proj): C = A * Bt^T.
// XCD chunks shaped 4x8 (rows x cols) so each XCD's working set
// (4 A-panels + 8 B-panels ~ 6 MB) is mostly L2-resident, instead of
// all-16 A-panels with the row-fast ordering.
// ------------------------------------------------------------------
__device__ __forceinline__ void store_c(float* p, float v) { *p = v; }
__device__ __forceinline__ void store_c(short* p, float v) { *p = f2bf(v); }

template <typename OT>
__global__ __launch_bounds__(512, 1) void gemm_bf16_bt(const short* __restrict__ A,
                                                       const short* __restrict__ Bt,
                                                       OT* __restrict__ C,
                                                       int M, int N, int K) {
  __shared__ short As[128 * 32];
  __shared__ short Bs[128 * 32];
  const int t = threadIdx.x;          // 0..511
  const int l = t & 63, w = t >> 6;   // 8 waves
  const int wr = w >> 2, wc = w & 3;  // 2 x 4
  const int lm = l & 15, lk = (l >> 4) * 8;
  const int L = blockIdx.x;           // 256 blocks (16x16 tile grid)
  const int xcd = L & 7, j = L >> 3;  // j in 0..31
  const int rowt = (xcd & 3) * 4 + (j & 3);
  const int colt = (xcd >> 2) * 8 + (j >> 2);
  const int row0 = rowt * 128, col0 = colt * 128;
  facc acc[4][2] = {};

  const int sr = t >> 2;              // 0..127
  const int sk = (t & 3) * 8;
  const short* Ag = A + (size_t)(row0 + sr) * K + sk;
  const short* Bg = Bt + (size_t)(col0 + sr) * K + sk;
  short* la = As + t * 8;
  short* lb = Bs + t * 8;

  for (int k0 = 0; k0 < K; k0 += 32) {
    ASYNC16(Ag + k0, la);
    ASYNC16(Bg + k0, lb);
    __syncthreads();
    bfrag af[4], bf[2];
#pragma unroll
    for (int i = 0; i < 4; ++i)
      af[i] = *(const bfrag*)&As[(wr * 64 + i * 16 + lm) * 32 + lk];
#pragma unroll
    for (int j2 = 0; j2 < 2; ++j2)
      bf[j2] = *(const bfrag*)&Bs[(wc * 32 + j2 * 16 + lm) * 32 + lk];
#pragma unroll
    for (int i = 0; i < 4; ++i)
#pragma unroll
      for (int j2 = 0; j2 < 2; ++j2)
        acc[i][j2] = MFMA16(af[i], bf[j2], acc[i][j2]);
    __syncthreads();
  }

  const int orow = row0 + wr * 64 + (l >> 4) * 4;
  const int ocol = col0 + wc * 32 + lm;
#pragma unroll
  for (int i = 0; i < 4; ++i)
#pragma unroll
    for (int j2 = 0; j2 < 2; ++j2)
#pragma unroll
      for (int rr = 0; rr < 4; ++rr)
        store_c(&C[(size_t)(orow + i * 16 + rr) * N + ocol + j2 * 16], acc[i][j2][rr]);
}

// ------------------------------------------------------------------
// postqkv: fused rope(q,k) + K block-mean + V transpose + V block-mean.
// ------------------------------------------------------------------
__global__ __launch_bounds__(256) void postqkv(short* __restrict__ qkv,
                                               const float2* __restrict__ tbl,
                                               float* __restrict__ kc,
                                               short* __restrict__ vt,
                                               short* __restrict__ vct) {
  const int nb = blockIdx.x, h = blockIdx.y, b = blockIdx.z;
  const int t = threadIdx.x;
  const int n0 = nb * 64;
  __shared__ short tile[64][136];

  const int row = t >> 2;        // 0..63
  const int c16 = (t & 3) * 16;  // lower-half dim base: 0,16,32,48
  const float2* tp = tbl + (size_t)(n0 + row) * 64 + c16;

#pragma unroll
  for (int qk = 0; qk < 2; ++qk) {
    short* base = qkv + (size_t)(b * NSEQ + n0 + row) * QKV_STR + qk * KOFS + h * HDIM + c16;
    bfrag lo0 = *(const bfrag*)base;
    bfrag lo1 = *(const bfrag*)(base + 8);
    bfrag hi0 = *(const bfrag*)(base + 64);
    bfrag hi1 = *(const bfrag*)(base + 72);
    bfrag olo0, olo1, ohi0, ohi1;
#pragma unroll
    for (int j = 0; j < 8; ++j) {
      float2 cs0 = tp[j], cs1 = tp[j + 8];
      float a0 = bf2f(lo0[j]), b0 = bf2f(hi0[j]);
      float a1 = bf2f(lo1[j]), b1 = bf2f(hi1[j]);
      olo0[j] = f2bf(a0 * cs0.x - b0 * cs0.y);
      ohi0[j] = f2bf(a0 * cs0.y + b0 * cs0.x);
      olo1[j] = f2bf(a1 * cs1.x - b1 * cs1.y);
      ohi1[j] = f2bf(a1 * cs1.y + b1 * cs1.x);
    }
    *(bfrag*)base = olo0;
    *(bfrag*)(base + 8) = olo1;
    *(bfrag*)(base + 64) = ohi0;
    *(bfrag*)(base + 72) = ohi1;
    if (qk == 1) {  // stash roped K tile for the block mean
      *(bfrag*)&tile[row][c16] = olo0;
      *(bfrag*)&tile[row][c16 + 8] = olo1;
      *(bfrag*)&tile[row][c16 + 64] = ohi0;
      *(bfrag*)&tile[row][c16 + 72] = ohi1;
    }
  }
  __syncthreads();

  // K block mean (roped): kc[b][nb][h][d]
  if (t < 128) {
    float s = 0.f;
#pragma unroll 8
    for (int r = 0; r < 64; ++r) s += bf2f(tile[r][t]);
    kc[(((size_t)(b * NBLK + nb) * HN) + h) * 128 + t] = s * (1.0f / 64.0f);
  }
  __syncthreads();

  // V tile into LDS
#pragma unroll
  for (int it = 0; it < 4; ++it) {
    int idx = t + 256 * it;
    int r2 = idx >> 4, ch = idx & 15;
    *(bfrag*)&tile[r2][ch * 8] =
        *(const bfrag*)&qkv[(size_t)(b * NSEQ + n0 + r2) * QKV_STR + VOFS + h * HDIM + ch * 8];
  }
  __syncthreads();

  // transpose out + V block mean
#pragma unroll
  for (int it = 0; it < 4; ++it) {
    int idx = t + 256 * it;
    int d = idx >> 3, ch = idx & 7;
    bfrag tv;
    float s = 0.f;
#pragma unroll
    for (int j = 0; j < 8; ++j) {
      tv[j] = tile[ch * 8 + j][d];
      s += bf2f(tv[j]);
    }
    *(bfrag*)&vt[(((size_t)(b * HN + h) * 128) + d) * 1024 + n0 + ch * 8] = tv;
    s += __shfl_down(s, 4);
    s += __shfl_down(s, 2);
    s += __shfl_down(s, 1);
    if ((t & 7) == 0)
      vct[(((size_t)(b * HN + h) * 128) + d) * 16 + nb] = f2bf(s * (1.0f / 64.0f));
  }
}

// ------------------------------------------------------------------
// Compressed probs (bf16 pc [b][h][n][16]) + top-8 selection bitmask.
// ------------------------------------------------------------------
__global__ __launch_bounds__(64) void cmp_sel(const short* __restrict__ qkv,
                                              const float* __restrict__ kc,
                                              short* __restrict__ pc,
                                              int* __restrict__ sel) {
  int i = blockIdx.x * 64 + threadIdx.x;  // B*H*N = 32768
  int n = i & 1023;
  int h = (i >> 10) & 15;
  int b = i >> 14;
  const short* qp = qkv + (size_t)(b * NSEQ + n) * QKV_STR + h * HDIM;
  const int nv = (n + 1) >> 6;
  float s[NBLK];
#pragma unroll
  for (int m = 0; m < NBLK; ++m) s[m] = 0.f;
  for (int d0 = 0; d0 < HDIM; d0 += 8) {
    bfrag qv = *(const bfrag*)&qp[d0];
    float qf[8];
#pragma unroll
    for (int dd = 0; dd < 8; ++dd) qf[dd] = bf2f(qv[dd]);
    for (int m = 0; m < nv; ++m) {
      const float4* kp = (const float4*)(kc + ((size_t)((b * NBLK + m) * HN + h) << 7) + d0);
      const float4 k0 = kp[0], k1 = kp[1];
      s[m] += qf[0] * k0.x + qf[1] * k0.y + qf[2] * k0.z + qf[3] * k0.w +
              qf[4] * k1.x + qf[5] * k1.y + qf[6] * k1.z + qf[7] * k1.w;
    }
  }
  float mx = -1e30f;
  for (int m = 0; m < nv; ++m) { s[m] *= SCALE; mx = fmaxf(mx, s[m]); }
  float den = 0.f;
  for (int m = 0; m < nv; ++m) { s[m] = __expf(s[m] - mx); den += s[m]; }
  const float rden = (nv > 0) ? 1.0f / den : 0.f;
  float p[NBLK];
#pragma unroll
  for (int m = 0; m < NBLK; ++m) p[m] = (m < nv) ? s[m] * rden : 0.f;
  bfrag o0, o1;
#pragma unroll
  for (int m = 0; m < 8; ++m) { o0[m] = f2bf(p[m]); o1[m] = f2bf(p[m + 8]); }
  bfrag* pout = (bfrag*)(pc + (size_t)i * 16);
  pout[0] = o0; pout[1] = o1;
  p[n >> 6] += 2.0f;
  int mask = 0;
#pragma unroll
  for (int ss = 0; ss < 8; ++ss) {
    int best = 0;
    float bv = -1e30f;
#pragma unroll
    for (int m = 0; m < NBLK; ++m)
      if (p[m] > bv) { bv = p[m]; best = m; }
    mask |= 1 << best;
    p[best] = -1e30f;
  }
  sel[i] = mask;
}

// ------------------------------------------------------------------
// MFMA attention, LDS-staged with 2-tile-deep counted prefetch:
// 3 K/V buffers; per iter {stage(ct+2) -> compute(ct) -> vmcnt(4)
// [ct+1 done, ct+2 in flight] -> barrier}. Removes the per-tile
// vmcnt(0) drain of R14. Buffer safety: (ct+2)%3 != ct%3 != (ct+1)%3;
// the target's previous contents (ct-1) were fully read before the
// barrier that ended iter ct-1.
// ------------------------------------------------------------------
__global__ __launch_bounds__(512, 1) void attn_mfma(
    const short* __restrict__ qkv, const short* __restrict__ vt,
    const short* __restrict__ vct, const short* __restrict__ pc,
    const int* __restrict__ sel, short* __restrict__ o) {
  const int fid = blockIdx.x;            // 0..255
  const int xcd = fid & 7;
  const int idx = fid >> 3;              // 0..31
  const int pair = (xcd << 2) | (idx & 3);
  const int rblk = idx >> 2;             // 0..7
  const int h = pair & 15, b = pair >> 4;

  const int tid = threadIdx.x;
  const int wid = tid >> 6;              // 0..7
  const int l = tid & 63;
  const int lm = l & 15, hi = l >> 4;
  const int rt = wid * 8 + rblk;         // striped row-tile ownership
  const int nbase = rt * 16;
  const int CTMAX = ((56 + rblk) * 16) >> 6;  // thi of the largest rt in block

  __shared__ short kbuf[3][8192];        // [buf][64 n][128 d] swizzled
  __shared__ short vbuf[3][8192];        // [buf][128 d][64 n] swizzled
  __shared__ short pbuf[8][2][1024];     // per-wave P (slc/swa)
  short* p_slc = &pbuf[wid][0][0];
  short* p_swa = &pbuf[wid][1][0];

  // Q A-fragments
  const short* qrow = qkv + (size_t)(b * NSEQ + nbase + lm) * QKV_STR + h * HDIM;
  bfrag qf[4];
#pragma unroll
  for (int ks = 0; ks < 4; ++ks) qf[ks] = *(const bfrag*)&qrow[32 * ks + 8 * hi];

  // selection bits
  int selrow = sel[(size_t)(b * HN + h) * NSEQ + nbase + lm];
  int uni = selrow;
#pragma unroll
  for (int m = 1; m < 16; m <<= 1) uni |= __shfl_xor(uni, m);
  int sel4[4];
#pragma unroll
  for (int rg = 0; rg < 4; ++rg) sel4[rg] = __shfl(selrow, 4 * hi + rg);

  const int thi = nbase >> 6;
  const int tlo = (nbase >= 64) ? ((nbase - 64) >> 6) : 0;
  const int wmask = (int)((2u << thi) - (1u << tlo));
  const unsigned am = (unsigned)(uni | wmask) & (unsigned)((2u << thi) - 1);

  facc acc_slc[8] = {}, acc_swa[8] = {};
  float ps_s[4] = {0.f, 0.f, 0.f, 0.f}, ps_w[4] = {0.f, 0.f, 0.f, 0.f};

#define STAGEKV(ct_, buf_)                                                   \
  {                                                                          \
    _Pragma("unroll") for (int rr = 0; rr < 2; ++rr) {                       \
      const int i2 = tid + 512 * rr;                                         \
      const int rw = i2 >> 4, cc = i2 & 15;                                  \
      const short* g_ = qkv + (size_t)(b * NSEQ + (ct_) * 64 + rw) * QKV_STR \
                        + KOFS + h * HDIM + 8 * (cc ^ (rw & 7));             \
      ASYNC16(g_, &kbuf[buf_][i2 * 8]);                                      \
    }                                                                        \
    _Pragma("unroll") for (int rr = 0; rr < 2; ++rr) {                       \
      const int i2 = tid + 512 * rr;                                         \
      const int dd = i2 >> 3, cc = i2 & 7;                                   \
      const short* g_ = vt + ((size_t)(b * HN + h) * 128 + dd) * 1024        \
                        + (ct_) * 64 + 8 * (cc ^ (dd & 7));                  \
      ASYNC16(g_, &vbuf[buf_][i2 * 8]);                                      \
    }                                                                        \
  }

#define EXPF(f_)                                                            \
  _Pragma("unroll") for (int rg = 0; rg < 4; ++rg) {                        \
    const int col_ = ct * 64 + 16 * (f_) + lm;                              \
    const int row_ = nbase + 4 * hi + rg;                                   \
    float e_ = __expf(sacc[f_][rg] * SCALE);                                \
    e_ = (col_ <= row_) ? e_ : 0.f;                                         \
    float es_ = ((sel4[rg] >> ct) & 1) ? e_ : 0.f;                          \
    float ew_ = (row_ - col_ <= 64) ? e_ : 0.f;                             \
    ps_s[rg] += es_;                                                        \
    ps_w[rg] += ew_;                                                        \
    const int srow_ = 4 * hi + rg;                                          \
    const int sidx_ = (64 * srow_ + 16 * (f_) + lm) ^ ((srow_ & 7) << 3);   \
    if (do_s) p_slc[sidx_] = f2bf(es_);                                     \
    if (do_w) p_swa[sidx_] = f2bf(ew_);                                     \
  }

  // prologue: stage tiles 0 and 1 (CTMAX >= 14 always)
  STAGEKV(0, 0);
  STAGEKV(1, 1);
  asm volatile("s_waitcnt vmcnt(4)" ::: "memory");  // tile 0 ready
  __syncthreads();

  int cur = 0;
  for (int ct = 0; ct <= CTMAX; ++ct) {
    const bool have_next2 = (ct + 2 <= CTMAX);
    if (have_next2) {
      const int nb2 = (cur + 2 >= 3) ? cur - 1 : cur + 2;
      const int ct2 = ct + 2;
      STAGEKV(ct2, nb2);
    }

    if ((am >> ct) & 1) {
      const bool do_s = (uni >> ct) & 1;
      const bool do_w = (wmask >> ct) & 1;

      // QK^T from LDS K tile
      facc sacc[4] = {};
#pragma unroll
      for (int f = 0; f < 4; ++f) {
        const int row_ = 16 * f + lm;
        const int rx = row_ & 7;
        bfrag k0 = *(const bfrag*)&kbuf[cur][row_ * 128 + 8 * ((0 + hi) ^ rx)];
        bfrag k1 = *(const bfrag*)&kbuf[cur][row_ * 128 + 8 * ((4 + hi) ^ rx)];
        bfrag k2 = *(const bfrag*)&kbuf[cur][row_ * 128 + 8 * ((8 + hi) ^ rx)];
        bfrag k3 = *(const bfrag*)&kbuf[cur][row_ * 128 + 8 * ((12 + hi) ^ rx)];
        sacc[f] = MFMA16(qf[0], k0, sacc[f]);
        sacc[f] = MFMA16(qf[1], k1, sacc[f]);
        sacc[f] = MFMA16(qf[2], k2, sacc[f]);
        sacc[f] = MFMA16(qf[3], k3, sacc[f]);
      }

      EXPF(0); EXPF(1); EXPF(2); EXPF(3);

      // PV from LDS V tile
#pragma unroll
      for (int ks = 0; ks < 2; ++ks) {
        const int ridx = (64 * lm + 8 * hi + 32 * ks) ^ ((lm & 7) << 3);
        bfrag pas = {}, paw = {};
        if (do_s) pas = *(const bfrag*)&p_slc[ridx];
        if (do_w) paw = *(const bfrag*)&p_swa[ridx];
#pragma unroll
        for (int df = 0; df < 8; ++df) {
          const int d_ = 16 * df + lm;
          bfrag vb = *(const bfrag*)&vbuf[cur][d_ * 64 + 8 * ((4 * ks + hi) ^ (d_ & 7))];
          if (do_s) acc_slc[df] = MFMA16(pas, vb, acc_slc[df]);
          if (do_w) acc_swa[df] = MFMA16(paw, vb, acc_swa[df]);
        }
      }
    }

    // wait for next tile (ct+1); ct+2 (if staged) stays in flight
    if (ct < CTMAX) {
      if (have_next2)
        asm volatile("s_waitcnt vmcnt(4)" ::: "memory");
      else
        asm volatile("s_waitcnt vmcnt(0)" ::: "memory");
      __syncthreads();
    }
    cur = (cur + 1 >= 3) ? 0 : cur + 1;
  }
#undef STAGEKV
#undef EXPF

  // ---- compressed branch: O_cmp = Pc[16x16] * Vc[16x128], K padded to 32
  facc acc_cmp[8] = {};
  {
    bfrag pa = {};
    if (hi < 2)
      pa = *(const bfrag*)&pc[((size_t)(b * HN + h) * NSEQ + nbase + lm) * 16 + 8 * hi];
#pragma unroll
    for (int df = 0; df < 8; ++df) {
      bfrag vb = {};
      if (hi < 2)
        vb = *(const bfrag*)&vct[(((size_t)(b * HN + h) * 128) + 16 * df + lm) * 16 + 8 * hi];
      acc_cmp[df] = MFMA16(pa, vb, acc_cmp[df]);
    }
  }

  // ---- denominators: reduce across the 16 col-lanes
#pragma unroll
  for (int m = 1; m < 16; m <<= 1) {
#pragma unroll
    for (int rg = 0; rg < 4; ++rg) {
      ps_s[rg] += __shfl_xor(ps_s[rg], m);
      ps_w[rg] += __shfl_xor(ps_w[rg], m);
    }
  }

  float inv_s[4], inv_w[4], gcv[4], gsv[4], gwv[4];
#pragma unroll
  for (int rg = 0; rg < 4; ++rg) {
    inv_s[rg] = 1.0f / ps_s[rg];
    inv_w[rg] = 1.0f / ps_w[rg];
    const short* gp = qkv + (size_t)(b * NSEQ + nbase + 4 * hi + rg) * QKV_STR + GOFS;
    gcv[rg] = 1.0f / (1.0f + __expf(-bf2f(gp[h])));
    gsv[rg] = 1.0f / (1.0f + __expf(-bf2f(gp[16 + h])));
    gwv[rg] = 1.0f / (1.0f + __expf(-bf2f(gp[32 + h])));
  }

  short* obase = o + (size_t)(b * NSEQ + nbase) * 2048 + h * HDIM;
#pragma unroll
  for (int df = 0; df < 8; ++df)
#pragma unroll
    for (int rg = 0; rg < 4; ++rg) {
      float val = gcv[rg] * acc_cmp[df][rg] +
                  gsv[rg] * acc_slc[df][rg] * inv_s[rg] +
                  gwv[rg] * acc_swa[df][rg] * inv_w[rg];
      obase[(size_t)(4 * hi + rg) * 2048 + 16 * df + lm] = f2bf(val);
    }
}

// ------------------------------------------------------------------
extern "C" void kernel_launch(void* const* d_in, const int* in_sizes, int n_in,
                              void* d_out, int out_size, void* d_ws, size_t ws_size,
                              hipStream_t stream) {
  const float* x  = (const float*)d_in[0];
  const float* Wq = (const float*)d_in[1];
  const float* Wk = (const float*)d_in[2];
  const float* Wv = (const float*)d_in[3];
  const float* Wg = (const float*)d_in[4];
  const float* Wo = (const float*)d_in[5];
  float* out = (float*)d_out;

  char* w = (char*)d_ws;
  short* x_bf = (short*)w;            // 8.4 MB (reused as o_bf)
  short* o_bf = x_bf;
  w += (size_t)2048 * 2048 * 2;
  short* w_t  = (short*)w;            // 26.2 MB (rows 6272..6399 unused pad)
  w += (size_t)6400 * 2048 * 2;
  short* qkv  = (short*)w;            // 26.2 MB (stride 6400; gate at 6144)
  w += (size_t)2048 * 6400 * 2;
  float* kc   = (float*)w; w += (size_t)65536 * 4;
  short* vct  = (short*)w; w += (size_t)65536 * 2;
  short* pcb  = (short*)w; w += (size_t)524288 * 2;
  int*   sel  = (int*)w;   w += (size_t)32768 * 4;
  short* vt   = (short*)w; w += (size_t)4194304 * 2;  // 8.4 MB
  float2* tbl = (float2*)w; w += (size_t)65536 * 8;   // 0.5 MB
  short* wo_t = (short*)w; w += (size_t)2048 * 2048 * 2;  // 8.4 MB

  const dim3 blk(256);
  prep<<<dim3(64, 64, 7), blk, 0, stream>>>(Wq, Wk, Wv, Wg, Wo, x, w_t, wo_t, x_bf, tbl);
  gemm256<<<200, dim3(512), 0, stream>>>(x_bf, w_t, qkv, 2048, 6400, 2048);
  postqkv<<<dim3(16, 16, 2), blk, 0, stream>>>(qkv, tbl, kc, vt, vct);
  cmp_sel<<<512, dim3(64), 0, stream>>>(qkv, kc, pcb, sel);
  attn_mfma<<<256, dim3(512), 0, stream>>>(qkv, vt, vct, pcb, sel, o_bf);
  gemm_bf16_bt<float><<<256, dim3(512), 0, stream>>>(o_bf, wo_t, out, 2048, 2048, 2048);
}